// Round 13
// baseline (302.321 us; speedup 1.0000x reference)
//
#include <hip/hip_runtime.h>

// PointSetDifferenceModule: B=4, N=8192, C=64, K=16
// Round 13: stats_sim VALU diet — single fused k-loop (no max pass; |logit|<~44
// so raw expf is safe in fp32), self-term-factored diff stats (accumulate
// Sum(gdo), Sum(gdo^2); fold 16*gds terms in epilogue), 2 points/wave @ 8192
// blocks. XCD-affinity mapping retained (blockIdx&7 -> dir,batch).
// FT row (512B): [ f fp32 x64 | G_d bf16 x64 | G_s bf16 x64 ]

#define Bn 4
#define Nn 8192
#define NPTS (Bn * Nn)        // 32768
#define NSAMP (NPTS * 16)     // 524288
#define EPSf 1e-5f
#define FT_STRIDE 512
#define GSZ (NPTS * 64)

typedef __attribute__((ext_vector_type(8))) short v8bf;
typedef __attribute__((ext_vector_type(4))) float v4f;

__device__ inline unsigned pack_bf16x2(float a, float b) {
  unsigned ua = __float_as_uint(a), ub = __float_as_uint(b);
  ua = (ua + 0x7FFFu + ((ua >> 16) & 1u)) >> 16;
  ub = (ub + 0x7FFFu + ((ub >> 16) & 1u)) >> 16;
  return (ub << 16) | ua;
}
__device__ inline float bf16_lo(unsigned u) { return __uint_as_float(u << 16); }
__device__ inline float bf16_hi(unsigned u) { return __uint_as_float(u & 0xFFFF0000u); }

// ---------------- build fused tables: f fp32 + G_d, G_s bf16 ----------------
__global__ __launch_bounds__(256) void gemmG(const float* __restrict__ f0,
                                             const float* __restrict__ f1,
                                             const float* __restrict__ wd,
                                             const float* __restrict__ wsim,
                                             char* __restrict__ FT0,
                                             char* __restrict__ FT1) {
  int z = blockIdx.z;
  const float* F = z ? f1 : f0;
  char* FT = z ? FT1 : FT0;
  __shared__ float Fl[64][65];
  __shared__ float Wd[64][65];
  __shared__ float Ws[64][65];
  int t = threadIdx.x;
#pragma unroll
  for (int i = 0; i < 16; i++) {
    int ix = t + i * 256;
    Wd[ix >> 6][ix & 63] = wd[ix];
    Ws[ix >> 6][ix & 63] = wsim[ix];
  }
  int ptb = blockIdx.x * 64;
#pragma unroll
  for (int i = 0; i < 16; i++) {
    int ix = t + i * 256;
    float v = F[(size_t)ptb * 64 + ix];
    Fl[ix >> 6][ix & 63] = v;
    *(float*)(FT + (size_t)(ptb + (ix >> 6)) * FT_STRIDE + (ix & 63) * 4) = v;
  }
  __syncthreads();
  int ty = t >> 4, tx = t & 15, r0 = ty * 4, c0 = tx * 4;
  float ad[4][4] = {}, as_[4][4] = {};
#pragma unroll 4
  for (int j = 0; j < 64; ++j) {
    float a[4], w1[4], w2[4];
#pragma unroll
    for (int i = 0; i < 4; i++) a[i] = Fl[r0 + i][j];
#pragma unroll
    for (int m = 0; m < 4; m++) {
      w1[m] = Wd[c0 + m][j];
      w2[m] = Ws[c0 + m][j];
    }
#pragma unroll
    for (int i = 0; i < 4; i++)
#pragma unroll
      for (int m = 0; m < 4; m++) {
        ad[i][m] += a[i] * w1[m];
        as_[i][m] += a[i] * w2[m];
      }
  }
#pragma unroll
  for (int i = 0; i < 4; i++) {
    char* row = FT + (size_t)(ptb + r0 + i) * FT_STRIDE;
    uint2 gd2 = make_uint2(pack_bf16x2(ad[i][0], ad[i][1]),
                           pack_bf16x2(ad[i][2], ad[i][3]));
    *(uint2*)(row + 256 + c0 * 2) = gd2;
    uint2 gs2 = make_uint2(pack_bf16x2(as_[i][0], as_[i][1]),
                           pack_bf16x2(as_[i][2], as_[i][3]));
    *(uint2*)(row + 384 + c0 * 2) = gs2;
  }
}

// ---------------- diff stats + sim softmax + y_sim (one wave per point pair) -----
// lane 0-31: f pairs | lane 32-47: gd x4 | lane 48-63: gs x4
// XCD affinity: unit = blockIdx.x & 7 -> (dir, batch).
__global__ __launch_bounds__(256) void stats_sim(
    const char* __restrict__ FT0, const char* __restrict__ FT1,
    const int* __restrict__ i01, const int* __restrict__ i10,
    float* __restrict__ YS0, float* __restrict__ YS1, float* __restrict__ acc) {
  int u = blockIdx.x & 7;
  int dir = u & 1, batch = u >> 1;
  const char* FS = dir ? FT1 : FT0;
  const char* FO = dir ? FT0 : FT1;
  const int* idx = dir ? i10 : i01;
  float* ys = dir ? YS1 : YS0;
  float* accDiff = acc + dir * 128;
  float* accSim = acc + 256 + dir * 128;
  int lane = threadIdx.x & 63, wave = threadIdx.x >> 6;
  int w = blockIdx.x >> 3;              // 0..1023
  int gw = w * 4 + wave;                // 0..4095
  int ptbase = batch * Nn + gw * 2;     // 2 points per wave
  int bbase = batch * Nn;
  bool isD = (lane >= 32) && (lane < 48);
  bool isS = lane >= 48;
  int lq = lane & 15;
  float sdl[4] = {0, 0, 0, 0}, qdl[4] = {0, 0, 0, 0};
  float ssl[4] = {0, 0, 0, 0}, qsl[4] = {0, 0, 0, 0};
#pragma unroll 1
  for (int pi = 0; pi < 2; pi++) {
    int ptu = ptbase + pi;  // wave-uniform
    const char* srow = FS + (size_t)ptu * FT_STRIDE;
    uint2 selfr = *(const uint2*)(srow + lane * 8);
    const int* ip = idx + ptu * 16;
    int jx[16];
#pragma unroll
    for (int k = 0; k < 16; k++) jx[k] = ip[k];
    const char* ob = FO + (size_t)bbase * FT_STRIDE;
    uint2 nb[16];
#pragma unroll
    for (int k = 0; k < 16; k++)
      nb[k] = *(const uint2*)(ob + (size_t)jx[k] * FT_STRIDE + lane * 8);
    float fsx = __uint_as_float(selfr.x), fsy = __uint_as_float(selfr.y);
    // single fused k-loop: dot -> exp (no max shift; |logit| << 88) ->
    // softmax-num accum + neighbor-sum stats (self terms folded later)
    float den = 0.f, ya0 = 0.f, ya1 = 0.f, ya2 = 0.f, ya3 = 0.f;
    float S10 = 0.f, S11 = 0.f, S12 = 0.f, S13 = 0.f;
    float S20 = 0.f, S21 = 0.f, S22 = 0.f, S23 = 0.f;
#pragma unroll
    for (int k = 0; k < 16; k++) {
      float p = fsx * __uint_as_float(nb[k].x) + fsy * __uint_as_float(nb[k].y);
      p += __shfl_xor(p, 16);
      p += __shfl_xor(p, 8);
      p += __shfl_xor(p, 4);
      p += __shfl_xor(p, 2);
      p += __shfl_xor(p, 1);
      float s = __uint_as_float(__builtin_amdgcn_readfirstlane(__float_as_uint(p)));
      float e = __expf(s);
      den += e;
      float g0 = bf16_lo(nb[k].x), g1 = bf16_hi(nb[k].x);
      float g2 = bf16_lo(nb[k].y), g3 = bf16_hi(nb[k].y);
      S10 += g0; S11 += g1; S12 += g2; S13 += g3;
      S20 += g0 * g0; S21 += g1 * g1; S22 += g2 * g2; S23 += g3 * g3;
      ya0 += e * g0; ya1 += e * g1; ya2 += e * g2; ya3 += e * g3;
    }
    float inv = 1.f / den;
    ya0 *= inv; ya1 *= inv; ya2 *= inv; ya3 *= inv;
    if (isS)
      *(float4*)(ys + (size_t)ptu * 64 + lq * 4) = make_float4(ya0, ya1, ya2, ya3);
    ssl[0] += ya0; qsl[0] += ya0 * ya0;
    ssl[1] += ya1; qsl[1] += ya1 * ya1;
    ssl[2] += ya2; qsl[2] += ya2 * ya2;
    ssl[3] += ya3; qsl[3] += ya3 * ya3;
    // diff-stat epilogue (valid in isD lanes): Sum(gds-gdo) = 16*gds - S1,
    // Sum((gds-gdo)^2) = 16*gds^2 - 2*gds*S1 + S2
    float gds0 = bf16_lo(selfr.x), gds1 = bf16_hi(selfr.x);
    float gds2 = bf16_lo(selfr.y), gds3 = bf16_hi(selfr.y);
    sdl[0] += 16.f * gds0 - S10;
    sdl[1] += 16.f * gds1 - S11;
    sdl[2] += 16.f * gds2 - S12;
    sdl[3] += 16.f * gds3 - S13;
    qdl[0] += 16.f * gds0 * gds0 - 2.f * gds0 * S10 + S20;
    qdl[1] += 16.f * gds1 * gds1 - 2.f * gds1 * S11 + S21;
    qdl[2] += 16.f * gds2 * gds2 - 2.f * gds2 * S12 + S22;
    qdl[3] += 16.f * gds3 * gds3 - 2.f * gds3 * S13 + S23;
  }
  __shared__ float rA[4][64], rB[4][64], rC[4][64], rD2[4][64];
  int cd = lq * 4;
  if (isD) {
#pragma unroll
    for (int i = 0; i < 4; i++) {
      rA[wave][cd + i] = sdl[i];
      rB[wave][cd + i] = qdl[i];
    }
  }
  if (isS) {
#pragma unroll
    for (int i = 0; i < 4; i++) {
      rC[wave][cd + i] = ssl[i];
      rD2[wave][cd + i] = qsl[i];
    }
  }
  __syncthreads();
  if (wave == 0) {
    float v = rA[0][lane] + rA[1][lane] + rA[2][lane] + rA[3][lane];
    atomicAdd(accDiff + lane, v);
    v = rB[0][lane] + rB[1][lane] + rB[2][lane] + rB[3][lane];
    atomicAdd(accDiff + 64 + lane, v);
    v = rC[0][lane] + rC[1][lane] + rC[2][lane] + rC[3][lane];
    atomicAdd(accSim + lane, v);
    v = rD2[0][lane] + rD2[1][lane] + rD2[2][lane] + rD2[3][lane];
    atomicAdd(accSim + 64 + lane, v);
  }
}

// ---------------- finalize diff0,diff1,sim0,sim1 ----------------
__global__ void finalize1(const float* __restrict__ acc, const float* __restrict__ dg,
                          const float* __restrict__ dbeta, const float* __restrict__ sg,
                          const float* __restrict__ sbeta, float* __restrict__ ss) {
  int t = threadIdx.x;
  int seg = t >> 6, c = t & 63;
  const float* a = acc + seg * 128;
  float cnt = (seg < 2) ? (float)NSAMP : (float)NPTS;
  float mu = a[c] / cnt;
  float var = a[64 + c] / cnt - mu * mu;
  const float* g = (seg < 2) ? dg : sg;
  const float* be = (seg < 2) ? dbeta : sbeta;
  float scale = g[c] * rsqrtf(var + EPSf);
  ss[seg * 128 + c] = scale;
  ss[seg * 128 + 64 + c] = be[c] - mu * scale;
}

// ---------------- diff output: gather bf16 + BN/relu + MFMA GEMM + max over K --------
// Same XCD-affinity mapping: unit = blockIdx.x & 7 -> (dir,batch); 4 tiles/block.
__global__ __launch_bounds__(256) void diff_out_k(
    const char* __restrict__ FT0, const char* __restrict__ FT1,
    const int* __restrict__ i01, const int* __restrict__ i10,
    const float* __restrict__ w2d, const float* __restrict__ b2d,
    const float* __restrict__ ss, float* __restrict__ DF0, float* __restrict__ DF1) {
  int u = blockIdx.x & 7;
  int dir = u & 1, batch = u >> 1;
  const char* FS = dir ? FT1 : FT0;
  const char* FO = dir ? FT0 : FT1;
  const int* idx = dir ? i10 : i01;
  const float* ssd = ss + dir * 128;
  float* dout = dir ? DF1 : DF0;
  __shared__ __align__(16) unsigned WlU[64 * 36];
  __shared__ __align__(16) unsigned HtU[64 * 36];
  __shared__ unsigned Gs[4][32];
  __shared__ int idxt[64];
  __shared__ float sc[64], sh[64], bb[64];
  int t = threadIdx.x;
  int r = t >> 2, q = t & 3;
  {
    const float4* w4 = (const float4*)(w2d + r * 64 + q * 16);
#pragma unroll
    for (int uu = 0; uu < 4; uu++) {
      float4 v = w4[uu];
      WlU[r * 36 + q * 8 + uu * 2] = pack_bf16x2(v.x, v.y);
      WlU[r * 36 + q * 8 + uu * 2 + 1] = pack_bf16x2(v.z, v.w);
    }
  }
  if (t < 64) {
    sc[t] = ssd[t];
    sh[t] = ssd[64 + t];
    bb[t] = b2d[t];
  }
  int wave = t >> 6, lane = t & 63;
  int lr = lane & 15, lg = lane >> 4;
  int p = r >> 4;
  int wblk = blockIdx.x >> 3;  // 0..511
  int bbase = batch * Nn;
#pragma unroll 1
  for (int tt = 0; tt < 4; tt++) {
    int tile = wblk * 4 + tt;          // 0..2047 within batch
    int ptb = batch * Nn + tile * 4;
    __syncthreads();
    if (t < 64) idxt[t] = idx[ptb * 16 + t];
    if (t < 128)
      Gs[t >> 5][t & 31] =
          *(const unsigned*)(FS + (size_t)(ptb + (t >> 5)) * FT_STRIDE + 256 + (t & 31) * 4);
    __syncthreads();
    const char* orow = FO + (size_t)(bbase + idxt[r]) * FT_STRIDE + 256;
    uint4 g0 = *(const uint4*)(orow + q * 32);
    uint4 g1 = *(const uint4*)(orow + q * 32 + 16);
#pragma unroll
    for (int uu = 0; uu < 8; uu++) {
      unsigned gdo2 = (uu < 4) ? ((const unsigned*)&g0)[uu] : ((const unsigned*)&g1)[uu - 4];
      unsigned gds2 = Gs[p][q * 8 + uu];
      int c = q * 16 + uu * 2;
      float h0 = fmaxf(sc[c] * (bf16_lo(gds2) - bf16_lo(gdo2)) + sh[c], 0.f);
      float h1 = fmaxf(sc[c + 1] * (bf16_hi(gds2) - bf16_hi(gdo2)) + sh[c + 1], 0.f);
      HtU[r * 36 + q * 8 + uu] = pack_bf16x2(h0, h1);
    }
    __syncthreads();
    v4f acc[4] = {{0, 0, 0, 0}, {0, 0, 0, 0}, {0, 0, 0, 0}, {0, 0, 0, 0}};
    v8bf a0 = *(const v8bf*)&HtU[(wave * 16 + lr) * 36 + lg * 4];
    v8bf a1 = *(const v8bf*)&HtU[(wave * 16 + lr) * 36 + 16 + lg * 4];
#pragma unroll
    for (int c = 0; c < 4; c++) {
      v8bf b0 = *(const v8bf*)&WlU[(c * 16 + lr) * 36 + lg * 4];
      v8bf b1 = *(const v8bf*)&WlU[(c * 16 + lr) * 36 + 16 + lg * 4];
      acc[c] = __builtin_amdgcn_mfma_f32_16x16x32_bf16(a0, b0, acc[c], 0, 0, 0);
      acc[c] = __builtin_amdgcn_mfma_f32_16x16x32_bf16(a1, b1, acc[c], 0, 0, 0);
    }
#pragma unroll
    for (int c = 0; c < 4; c++) {
      float mm = fmaxf(fmaxf(acc[c][0], acc[c][1]), fmaxf(acc[c][2], acc[c][3]));
      mm = fmaxf(mm, __shfl_xor(mm, 16));
      mm = fmaxf(mm, __shfl_xor(mm, 32));
      if (lane < 16) dout[(size_t)(ptb + wave) * 64 + c * 16 + lane] = mm + bb[c * 16 + lane];
    }
  }
}

// ---------------- SF = relu(bn(YS)) @ sw2^T + sb2 ----------------
__global__ __launch_bounds__(256) void simfeat_gemm(
    const float* __restrict__ YS0, const float* __restrict__ YS1,
    const float* __restrict__ ss, const float* __restrict__ sw2,
    const float* __restrict__ sb2, float* __restrict__ SF0, float* __restrict__ SF1) {
  int dir = blockIdx.y;
  const float* ysim = dir ? YS1 : YS0;
  const float* ssS = ss + 256 + dir * 128;
  float* sf = dir ? SF1 : SF0;
  __shared__ float Wl[64][65];
  __shared__ float Hl[64][65];
  __shared__ float sc[64], sh[64], bb[64];
  int t = threadIdx.x;
  if (t < 64) {
    sc[t] = ssS[t];
    sh[t] = ssS[64 + t];
    bb[t] = sb2[t];
  }
#pragma unroll
  for (int i = 0; i < 16; i++) {
    int ix = t + i * 256;
    Wl[ix >> 6][ix & 63] = sw2[ix];
  }
  __syncthreads();
  int ptb = blockIdx.x * 64;
#pragma unroll
  for (int i = 0; i < 16; i++) {
    int ix = t + i * 256;
    int row = ix >> 6, col = ix & 63;
    float v = ysim[(size_t)ptb * 64 + ix];
    Hl[row][col] = fmaxf(sc[col] * v + sh[col], 0.f);
  }
  __syncthreads();
  int ty = t >> 4, tx = t & 15, r0 = ty * 4, c0 = tx * 4;
  float acc[4][4] = {};
#pragma unroll 4
  for (int j = 0; j < 64; ++j) {
    float a[4], w[4];
#pragma unroll
    for (int i = 0; i < 4; i++) a[i] = Hl[r0 + i][j];
#pragma unroll
    for (int m = 0; m < 4; m++) w[m] = Wl[c0 + m][j];
#pragma unroll
    for (int i = 0; i < 4; i++)
#pragma unroll
      for (int m = 0; m < 4; m++) acc[i][m] += a[i] * w[m];
  }
#pragma unroll
  for (int i = 0; i < 4; i++) {
    float4 v = make_float4(acc[i][0] + bb[c0], acc[i][1] + bb[c0 + 1],
                           acc[i][2] + bb[c0 + 2], acc[i][3] + bb[c0 + 3]);
    *reinterpret_cast<float4*>(sf + (size_t)(ptb + r0 + i) * 64 + c0) = v;
  }
}

// ---------------- YF = [DF|SF] @ fw1^T + fin BN stats ----------------
__global__ __launch_bounds__(256) void yfin_gemm(
    const float* __restrict__ DF0, const float* __restrict__ DF1,
    const float* __restrict__ SF0, const float* __restrict__ SF1,
    const float* __restrict__ fw1, float* __restrict__ YF0, float* __restrict__ YF1,
    float* __restrict__ acc) {
  int dir = blockIdx.z;
  const float* df = dir ? DF1 : DF0;
  const float* sf = dir ? SF1 : SF0;
  float* yf = dir ? YF1 : YF0;
  float* accF = acc + 512 + dir * 256;
  __shared__ float Wl[64][129];
  __shared__ float Cl[64][65];
  __shared__ float redS[64], redQ[64];
  int t = threadIdx.x;
  int y = blockIdx.y;
  if (t < 64) {
    redS[t] = 0.f;
    redQ[t] = 0.f;
  }
#pragma unroll
  for (int i = 0; i < 32; i++) {
    int ix = t + i * 256;
    Wl[ix >> 7][ix & 127] = fw1[(size_t)(y * 64 + (ix >> 7)) * 128 + (ix & 127)];
  }
  int ptb = blockIdx.x * 64;
#pragma unroll
  for (int i = 0; i < 16; i++) {
    int ix = t + i * 256;
    Cl[ix >> 6][ix & 63] = df[(size_t)ptb * 64 + ix];
  }
  __syncthreads();
  int ty = t >> 4, tx = t & 15, r0 = ty * 4, c0 = tx * 4;
  float acc4[4][4] = {};
#pragma unroll 4
  for (int j = 0; j < 64; ++j) {
    float a[4], w[4];
#pragma unroll
    for (int i = 0; i < 4; i++) a[i] = Cl[r0 + i][j];
#pragma unroll
    for (int m = 0; m < 4; m++) w[m] = Wl[c0 + m][j];
#pragma unroll
    for (int i = 0; i < 4; i++)
#pragma unroll
      for (int m = 0; m < 4; m++) acc4[i][m] += a[i] * w[m];
  }
  __syncthreads();
#pragma unroll
  for (int i = 0; i < 16; i++) {
    int ix = t + i * 256;
    Cl[ix >> 6][ix & 63] = sf[(size_t)ptb * 64 + ix];
  }
  __syncthreads();
#pragma unroll 4
  for (int j = 0; j < 64; ++j) {
    float a[4], w[4];
#pragma unroll
    for (int i = 0; i < 4; i++) a[i] = Cl[r0 + i][j];
#pragma unroll
    for (int m = 0; m < 4; m++) w[m] = Wl[c0 + m][64 + j];
#pragma unroll
    for (int i = 0; i < 4; i++)
#pragma unroll
      for (int m = 0; m < 4; m++) acc4[i][m] += a[i] * w[m];
  }
#pragma unroll
  for (int i = 0; i < 4; i++) {
    float4 v = make_float4(acc4[i][0], acc4[i][1], acc4[i][2], acc4[i][3]);
    *reinterpret_cast<float4*>(yf + (size_t)(ptb + r0 + i) * 128 + y * 64 + c0) = v;
  }
#pragma unroll
  for (int m = 0; m < 4; m++) {
    float s = acc4[0][m] + acc4[1][m] + acc4[2][m] + acc4[3][m];
    float qq = acc4[0][m] * acc4[0][m] + acc4[1][m] * acc4[1][m] +
               acc4[2][m] * acc4[2][m] + acc4[3][m] * acc4[3][m];
    atomicAdd(&redS[c0 + m], s);
    atomicAdd(&redQ[c0 + m], qq);
  }
  __syncthreads();
  if (t < 64) {
    atomicAdd(accF + y * 64 + t, redS[t]);
    atomicAdd(accF + 128 + y * 64 + t, redQ[t]);
  }
}

// ---------------- finalize fin0, fin1 ----------------
__global__ void finalize2(const float* __restrict__ accF, const float* __restrict__ fg,
                          const float* __restrict__ fbeta, float* __restrict__ ssF) {
  int t = threadIdx.x;
  int seg = t >> 7, c = t & 127;
  const float* a = accF + seg * 256;
  float mu = a[c] / (float)NPTS;
  float var = a[128 + c] / (float)NPTS - mu * mu;
  float scale = fg[c] * rsqrtf(var + EPSf);
  ssF[seg * 256 + c] = scale;
  ssF[seg * 256 + 128 + c] = fbeta[c] - mu * scale;
}

// ---------------- out = relu(bn(YF)) @ fw2^T + fb2 ----------------
__global__ __launch_bounds__(256) void finout_gemm(
    const float* __restrict__ YF0, const float* __restrict__ YF1,
    const float* __restrict__ ss, const float* __restrict__ fw2,
    const float* __restrict__ fb2, float* __restrict__ out) {
  int dir = blockIdx.y;
  const float* yf = dir ? YF1 : YF0;
  const float* ssF = ss + 512 + dir * 256;
  float* outp = out + (size_t)dir * NPTS * 64;
  __shared__ float Wl[64][129];
  __shared__ float Hl[64][65];
  __shared__ float scl[128], shf[128], bb[64];
  int t = threadIdx.x;
  if (t < 128) {
    scl[t] = ssF[t];
    shf[t] = ssF[128 + t];
  }
  if (t < 64) bb[t] = fb2[t];
#pragma unroll
  for (int i = 0; i < 32; i++) {
    int ix = t + i * 256;
    Wl[ix >> 7][ix & 127] = fw2[ix];
  }
  __syncthreads();
  int ptb = blockIdx.x * 64;
  int ty = t >> 4, tx = t & 15, r0 = ty * 4, c0 = tx * 4;
  float acc[4][4] = {};
#pragma unroll
  for (int i = 0; i < 16; i++) {
    int ix = t + i * 256;
    int row = ix >> 6, jj = ix & 63;
    float v = yf[(size_t)(ptb + row) * 128 + jj];
    Hl[row][jj] = fmaxf(scl[jj] * v + shf[jj], 0.f);
  }
  __syncthreads();
#pragma unroll 4
  for (int j = 0; j < 64; ++j) {
    float a[4], w[4];
#pragma unroll
    for (int i = 0; i < 4; i++) a[i] = Hl[r0 + i][j];
#pragma unroll
    for (int m = 0; m < 4; m++) w[m] = Wl[c0 + m][j];
#pragma unroll
    for (int i = 0; i < 4; i++)
#pragma unroll
      for (int m = 0; m < 4; m++) acc[i][m] += a[i] * w[m];
  }
  __syncthreads();
#pragma unroll
  for (int i = 0; i < 16; i++) {
    int ix = t + i * 256;
    int row = ix >> 6, jj = ix & 63;
    float v = yf[(size_t)(ptb + row) * 128 + 64 + jj];
    Hl[row][jj] = fmaxf(scl[64 + jj] * v + shf[64 + jj], 0.f);
  }
  __syncthreads();
#pragma unroll 4
  for (int j = 0; j < 64; ++j) {
    float a[4], w[4];
#pragma unroll
    for (int i = 0; i < 4; i++) a[i] = Hl[r0 + i][j];
#pragma unroll
    for (int m = 0; m < 4; m++) w[m] = Wl[c0 + m][64 + j];
#pragma unroll
    for (int i = 0; i < 4; i++)
#pragma unroll
      for (int m = 0; m < 4; m++) acc[i][m] += a[i] * w[m];
  }
#pragma unroll
  for (int i = 0; i < 4; i++) {
    float4 v = make_float4(acc[i][0] + bb[c0], acc[i][1] + bb[c0 + 1],
                           acc[i][2] + bb[c0 + 2], acc[i][3] + bb[c0 + 3]);
    *reinterpret_cast<float4*>(outp + (size_t)(ptb + r0 + i) * 64 + c0) = v;
  }
}

extern "C" void kernel_launch(void* const* d_in, const int* in_sizes, int n_in,
                              void* d_out, int out_size, void* d_ws, size_t ws_size,
                              hipStream_t stream) {
  const float* f0 = (const float*)d_in[0];
  const float* f1 = (const float*)d_in[1];
  const int* i01 = (const int*)d_in[2];
  const int* i10 = (const int*)d_in[3];
  const float* dw1 = (const float*)d_in[4];
  const float* dg = (const float*)d_in[6];
  const float* dbe = (const float*)d_in[7];
  const float* dw2 = (const float*)d_in[8];
  const float* db2 = (const float*)d_in[9];
  const float* sw1 = (const float*)d_in[10];
  const float* sg = (const float*)d_in[12];
  const float* sbe = (const float*)d_in[13];
  const float* sw2 = (const float*)d_in[14];
  const float* sb2 = (const float*)d_in[15];
  const float* fw1 = (const float*)d_in[16];
  const float* fg = (const float*)d_in[18];
  const float* fbe = (const float*)d_in[19];
  const float* fw2 = (const float*)d_in[20];
  const float* fb2 = (const float*)d_in[21];

  char* wsb = (char*)d_ws;
  float* out = (float*)d_out;

  char* FT0 = wsb;                            // 16 MB (32768*512)
  char* FT1 = wsb + (size_t)NPTS * FT_STRIDE; // 16 MB
  float* acc = (float*)(wsb + 2 * (size_t)NPTS * FT_STRIDE);  // @32MB
  float* ss = acc + 2048;
  float* YS0 = (float*)(wsb + 2 * (size_t)NPTS * FT_STRIDE + 65536);
  float* YS1 = YS0 + GSZ;
  float* DF0 = YS1 + GSZ;
  float* DF1 = DF0 + GSZ;
  float* SF0 = DF1 + GSZ;
  float* SF1 = SF0 + GSZ;
  float* YF0 = YS0;         // 16MB over YS0+YS1 (dead after simfeat_gemm)
  float* YF1 = (float*)FT0; // 16MB over FT0 (dead after diff_out_k)

  hipMemsetAsync(acc, 0, 1024 * sizeof(float), stream);
  gemmG<<<dim3(512, 1, 2), 256, 0, stream>>>(f0, f1, dw1, sw1, FT0, FT1);

  stats_sim<<<8192, 256, 0, stream>>>(FT0, FT1, i01, i10, YS0, YS1, acc);

  finalize1<<<1, 256, 0, stream>>>(acc, dg, dbe, sg, sbe, ss);

  diff_out_k<<<4096, 256, 0, stream>>>(FT0, FT1, i01, i10, dw2, db2, ss, DF0, DF1);

  simfeat_gemm<<<dim3(512, 2), 256, 0, stream>>>(YS0, YS1, ss, sw2, sb2, SF0, SF1);

  yfin_gemm<<<dim3(512, 2, 2), 256, 0, stream>>>(DF0, DF1, SF0, SF1, fw1, YF0, YF1, acc);

  finalize2<<<1, 256, 0, stream>>>(acc + 512, fg, fbe, ss + 512);

  finout_gemm<<<dim3(512, 2), 256, 0, stream>>>(YF0, YF1, ss, fw2, fb2, out);
}

// Round 14
// 260.258 us; speedup vs baseline: 1.1616x; 1.1616x over previous
//
#include <hip/hip_runtime.h>

// PointSetDifferenceModule: B=4, N=8192, C=64, K=16
// Round 14: stats_sim = r12 two-loop structure (4pts/wave, 4096 blocks) +
// factored diff stats + no-max exp. finalize1/2 folded into consumers
// (7 dispatches). XCD-affinity mapping retained.
// FT row (512B): [ f fp32 x64 | G_d bf16 x64 | G_s bf16 x64 ]

#define Bn 4
#define Nn 8192
#define NPTS (Bn * Nn)        // 32768
#define NSAMP (NPTS * 16)     // 524288
#define EPSf 1e-5f
#define FT_STRIDE 512
#define GSZ (NPTS * 64)

typedef __attribute__((ext_vector_type(8))) short v8bf;
typedef __attribute__((ext_vector_type(4))) float v4f;

__device__ inline unsigned pack_bf16x2(float a, float b) {
  unsigned ua = __float_as_uint(a), ub = __float_as_uint(b);
  ua = (ua + 0x7FFFu + ((ua >> 16) & 1u)) >> 16;
  ub = (ub + 0x7FFFu + ((ub >> 16) & 1u)) >> 16;
  return (ub << 16) | ua;
}
__device__ inline float bf16_lo(unsigned u) { return __uint_as_float(u << 16); }
__device__ inline float bf16_hi(unsigned u) { return __uint_as_float(u & 0xFFFF0000u); }

// ---------------- build fused tables: f fp32 + G_d, G_s bf16 ----------------
__global__ __launch_bounds__(256) void gemmG(const float* __restrict__ f0,
                                             const float* __restrict__ f1,
                                             const float* __restrict__ wd,
                                             const float* __restrict__ wsim,
                                             char* __restrict__ FT0,
                                             char* __restrict__ FT1) {
  int z = blockIdx.z;
  const float* F = z ? f1 : f0;
  char* FT = z ? FT1 : FT0;
  __shared__ float Fl[64][65];
  __shared__ float Wd[64][65];
  __shared__ float Ws[64][65];
  int t = threadIdx.x;
#pragma unroll
  for (int i = 0; i < 16; i++) {
    int ix = t + i * 256;
    Wd[ix >> 6][ix & 63] = wd[ix];
    Ws[ix >> 6][ix & 63] = wsim[ix];
  }
  int ptb = blockIdx.x * 64;
#pragma unroll
  for (int i = 0; i < 16; i++) {
    int ix = t + i * 256;
    float v = F[(size_t)ptb * 64 + ix];
    Fl[ix >> 6][ix & 63] = v;
    *(float*)(FT + (size_t)(ptb + (ix >> 6)) * FT_STRIDE + (ix & 63) * 4) = v;
  }
  __syncthreads();
  int ty = t >> 4, tx = t & 15, r0 = ty * 4, c0 = tx * 4;
  float ad[4][4] = {}, as_[4][4] = {};
#pragma unroll 4
  for (int j = 0; j < 64; ++j) {
    float a[4], w1[4], w2[4];
#pragma unroll
    for (int i = 0; i < 4; i++) a[i] = Fl[r0 + i][j];
#pragma unroll
    for (int m = 0; m < 4; m++) {
      w1[m] = Wd[c0 + m][j];
      w2[m] = Ws[c0 + m][j];
    }
#pragma unroll
    for (int i = 0; i < 4; i++)
#pragma unroll
      for (int m = 0; m < 4; m++) {
        ad[i][m] += a[i] * w1[m];
        as_[i][m] += a[i] * w2[m];
      }
  }
#pragma unroll
  for (int i = 0; i < 4; i++) {
    char* row = FT + (size_t)(ptb + r0 + i) * FT_STRIDE;
    uint2 gd2 = make_uint2(pack_bf16x2(ad[i][0], ad[i][1]),
                           pack_bf16x2(ad[i][2], ad[i][3]));
    *(uint2*)(row + 256 + c0 * 2) = gd2;
    uint2 gs2 = make_uint2(pack_bf16x2(as_[i][0], as_[i][1]),
                           pack_bf16x2(as_[i][2], as_[i][3]));
    *(uint2*)(row + 384 + c0 * 2) = gs2;
  }
}

// ---------------- diff stats + sim softmax + y_sim (one wave per point) ----------
// lane 0-31: f pairs | lane 32-47: gd x4 | lane 48-63: gs x4
// XCD affinity: unit = blockIdx.x & 7 -> (dir, batch).
__global__ __launch_bounds__(256) void stats_sim(
    const char* __restrict__ FT0, const char* __restrict__ FT1,
    const int* __restrict__ i01, const int* __restrict__ i10,
    float* __restrict__ YS0, float* __restrict__ YS1, float* __restrict__ acc) {
  int u = blockIdx.x & 7;
  int dir = u & 1, batch = u >> 1;
  const char* FS = dir ? FT1 : FT0;
  const char* FO = dir ? FT0 : FT1;
  const int* idx = dir ? i10 : i01;
  float* ys = dir ? YS1 : YS0;
  float* accDiff = acc + dir * 128;
  float* accSim = acc + 256 + dir * 128;
  int lane = threadIdx.x & 63, wave = threadIdx.x >> 6;
  int w = blockIdx.x >> 3;              // 0..511
  int gw = w * 4 + wave;                // 0..2047
  int ptbase = batch * Nn + gw * 4;     // 4 consecutive points per wave
  int bbase = batch * Nn;
  bool isD = (lane >= 32) && (lane < 48);
  bool isS = lane >= 48;
  int lq = lane & 15;
  float sdl[4] = {0, 0, 0, 0}, qdl[4] = {0, 0, 0, 0};
  float ssl[4] = {0, 0, 0, 0}, qsl[4] = {0, 0, 0, 0};
#pragma unroll 1
  for (int pi = 0; pi < 4; pi++) {
    int ptu = ptbase + pi;  // wave-uniform
    const char* srow = FS + (size_t)ptu * FT_STRIDE;
    uint2 selfr = *(const uint2*)(srow + lane * 8);
    const int* ip = idx + ptu * 16;
    int jx[16];
#pragma unroll
    for (int k = 0; k < 16; k++) jx[k] = ip[k];
    const char* ob = FO + (size_t)bbase * FT_STRIDE;
    uint2 nb[16];
#pragma unroll
    for (int k = 0; k < 16; k++)
      nb[k] = *(const uint2*)(ob + (size_t)jx[k] * FT_STRIDE + lane * 8);
    float fsx = __uint_as_float(selfr.x), fsy = __uint_as_float(selfr.y);
    // loop 1: 16 independent shfl trees (DS-pipe ILP) + neighbor-sum stats
    float sims[16];
    float S10 = 0.f, S11 = 0.f, S12 = 0.f, S13 = 0.f;
    float S20 = 0.f, S21 = 0.f, S22 = 0.f, S23 = 0.f;
#pragma unroll
    for (int k = 0; k < 16; k++) {
      float p = fsx * __uint_as_float(nb[k].x) + fsy * __uint_as_float(nb[k].y);
      p += __shfl_xor(p, 16);
      p += __shfl_xor(p, 8);
      p += __shfl_xor(p, 4);
      p += __shfl_xor(p, 2);
      p += __shfl_xor(p, 1);
      sims[k] = __uint_as_float(__builtin_amdgcn_readfirstlane(__float_as_uint(p)));
      float g0 = bf16_lo(nb[k].x), g1 = bf16_hi(nb[k].x);
      float g2 = bf16_lo(nb[k].y), g3 = bf16_hi(nb[k].y);
      S10 += g0; S11 += g1; S12 += g2; S13 += g3;
      S20 += g0 * g0; S21 += g1 * g1; S22 += g2 * g2; S23 += g3 * g3;
    }
    // loop 2: exp (no max shift; |logit| << 88) + softmax numerators
    float den = 0.f, ya0 = 0.f, ya1 = 0.f, ya2 = 0.f, ya3 = 0.f;
#pragma unroll
    for (int k = 0; k < 16; k++) {
      float e = __expf(sims[k]);
      den += e;
      ya0 += e * bf16_lo(nb[k].x);
      ya1 += e * bf16_hi(nb[k].x);
      ya2 += e * bf16_lo(nb[k].y);
      ya3 += e * bf16_hi(nb[k].y);
    }
    float inv = 1.f / den;
    ya0 *= inv; ya1 *= inv; ya2 *= inv; ya3 *= inv;
    if (isS)
      *(float4*)(ys + (size_t)ptu * 64 + lq * 4) = make_float4(ya0, ya1, ya2, ya3);
    ssl[0] += ya0; qsl[0] += ya0 * ya0;
    ssl[1] += ya1; qsl[1] += ya1 * ya1;
    ssl[2] += ya2; qsl[2] += ya2 * ya2;
    ssl[3] += ya3; qsl[3] += ya3 * ya3;
    // diff-stat epilogue: Sum(gds-gdo) = 16*gds - S1;
    // Sum((gds-gdo)^2) = 16*gds^2 - 2*gds*S1 + S2
    float gds0 = bf16_lo(selfr.x), gds1 = bf16_hi(selfr.x);
    float gds2 = bf16_lo(selfr.y), gds3 = bf16_hi(selfr.y);
    sdl[0] += 16.f * gds0 - S10;
    sdl[1] += 16.f * gds1 - S11;
    sdl[2] += 16.f * gds2 - S12;
    sdl[3] += 16.f * gds3 - S13;
    qdl[0] += 16.f * gds0 * gds0 - 2.f * gds0 * S10 + S20;
    qdl[1] += 16.f * gds1 * gds1 - 2.f * gds1 * S11 + S21;
    qdl[2] += 16.f * gds2 * gds2 - 2.f * gds2 * S12 + S22;
    qdl[3] += 16.f * gds3 * gds3 - 2.f * gds3 * S13 + S23;
  }
  __shared__ float rA[4][64], rB[4][64], rC[4][64], rD2[4][64];
  int cd = lq * 4;
  if (isD) {
#pragma unroll
    for (int i = 0; i < 4; i++) {
      rA[wave][cd + i] = sdl[i];
      rB[wave][cd + i] = qdl[i];
    }
  }
  if (isS) {
#pragma unroll
    for (int i = 0; i < 4; i++) {
      rC[wave][cd + i] = ssl[i];
      rD2[wave][cd + i] = qsl[i];
    }
  }
  __syncthreads();
  if (wave == 0) {
    float v = rA[0][lane] + rA[1][lane] + rA[2][lane] + rA[3][lane];
    atomicAdd(accDiff + lane, v);
    v = rB[0][lane] + rB[1][lane] + rB[2][lane] + rB[3][lane];
    atomicAdd(accDiff + 64 + lane, v);
    v = rC[0][lane] + rC[1][lane] + rC[2][lane] + rC[3][lane];
    atomicAdd(accSim + lane, v);
    v = rD2[0][lane] + rD2[1][lane] + rD2[2][lane] + rD2[3][lane];
    atomicAdd(accSim + 64 + lane, v);
  }
}

// ---------------- diff output: gather bf16 + BN/relu + MFMA GEMM + max over K --------
// finalize1(diff) folded in: each block computes scale/shift from raw acc.
__global__ __launch_bounds__(256) void diff_out_k(
    const char* __restrict__ FT0, const char* __restrict__ FT1,
    const int* __restrict__ i01, const int* __restrict__ i10,
    const float* __restrict__ w2d, const float* __restrict__ b2d,
    const float* __restrict__ acc, const float* __restrict__ dg,
    const float* __restrict__ dbe, float* __restrict__ DF0, float* __restrict__ DF1) {
  int u = blockIdx.x & 7;
  int dir = u & 1, batch = u >> 1;
  const char* FS = dir ? FT1 : FT0;
  const char* FO = dir ? FT0 : FT1;
  const int* idx = dir ? i10 : i01;
  const float* aD = acc + dir * 128;
  float* dout = dir ? DF1 : DF0;
  __shared__ __align__(16) unsigned WlU[64 * 36];
  __shared__ __align__(16) unsigned HtU[64 * 36];
  __shared__ unsigned Gs[4][32];
  __shared__ int idxt[64];
  __shared__ float sc[64], sh[64], bb[64];
  int t = threadIdx.x;
  int r = t >> 2, q = t & 3;
  {
    const float4* w4 = (const float4*)(w2d + r * 64 + q * 16);
#pragma unroll
    for (int uu = 0; uu < 4; uu++) {
      float4 v = w4[uu];
      WlU[r * 36 + q * 8 + uu * 2] = pack_bf16x2(v.x, v.y);
      WlU[r * 36 + q * 8 + uu * 2 + 1] = pack_bf16x2(v.z, v.w);
    }
  }
  if (t < 64) {
    float mu = aD[t] / (float)NSAMP;
    float var = aD[64 + t] / (float)NSAMP - mu * mu;
    float scale = dg[t] * rsqrtf(var + EPSf);
    sc[t] = scale;
    sh[t] = dbe[t] - mu * scale;
    bb[t] = b2d[t];
  }
  int wave = t >> 6, lane = t & 63;
  int lr = lane & 15, lg = lane >> 4;
  int p = r >> 4;
  int wblk = blockIdx.x >> 3;  // 0..511
  int bbase = batch * Nn;
#pragma unroll 1
  for (int tt = 0; tt < 4; tt++) {
    int tile = wblk * 4 + tt;          // 0..2047 within batch
    int ptb = batch * Nn + tile * 4;
    __syncthreads();
    if (t < 64) idxt[t] = idx[ptb * 16 + t];
    if (t < 128)
      Gs[t >> 5][t & 31] =
          *(const unsigned*)(FS + (size_t)(ptb + (t >> 5)) * FT_STRIDE + 256 + (t & 31) * 4);
    __syncthreads();
    const char* orow = FO + (size_t)(bbase + idxt[r]) * FT_STRIDE + 256;
    uint4 g0 = *(const uint4*)(orow + q * 32);
    uint4 g1 = *(const uint4*)(orow + q * 32 + 16);
#pragma unroll
    for (int uu = 0; uu < 8; uu++) {
      unsigned gdo2 = (uu < 4) ? ((const unsigned*)&g0)[uu] : ((const unsigned*)&g1)[uu - 4];
      unsigned gds2 = Gs[p][q * 8 + uu];
      int c = q * 16 + uu * 2;
      float h0 = fmaxf(sc[c] * (bf16_lo(gds2) - bf16_lo(gdo2)) + sh[c], 0.f);
      float h1 = fmaxf(sc[c + 1] * (bf16_hi(gds2) - bf16_hi(gdo2)) + sh[c + 1], 0.f);
      HtU[r * 36 + q * 8 + uu] = pack_bf16x2(h0, h1);
    }
    __syncthreads();
    v4f acc4[4] = {{0, 0, 0, 0}, {0, 0, 0, 0}, {0, 0, 0, 0}, {0, 0, 0, 0}};
    v8bf a0 = *(const v8bf*)&HtU[(wave * 16 + lr) * 36 + lg * 4];
    v8bf a1 = *(const v8bf*)&HtU[(wave * 16 + lr) * 36 + 16 + lg * 4];
#pragma unroll
    for (int c = 0; c < 4; c++) {
      v8bf b0 = *(const v8bf*)&WlU[(c * 16 + lr) * 36 + lg * 4];
      v8bf b1 = *(const v8bf*)&WlU[(c * 16 + lr) * 36 + 16 + lg * 4];
      acc4[c] = __builtin_amdgcn_mfma_f32_16x16x32_bf16(a0, b0, acc4[c], 0, 0, 0);
      acc4[c] = __builtin_amdgcn_mfma_f32_16x16x32_bf16(a1, b1, acc4[c], 0, 0, 0);
    }
#pragma unroll
    for (int c = 0; c < 4; c++) {
      float mm = fmaxf(fmaxf(acc4[c][0], acc4[c][1]), fmaxf(acc4[c][2], acc4[c][3]));
      mm = fmaxf(mm, __shfl_xor(mm, 16));
      mm = fmaxf(mm, __shfl_xor(mm, 32));
      if (lane < 16) dout[(size_t)(ptb + wave) * 64 + c * 16 + lane] = mm + bb[c * 16 + lane];
    }
  }
}

// ---------------- SF = relu(bn(YS)) @ sw2^T + sb2 (finalize1-sim folded in) -------
__global__ __launch_bounds__(256) void simfeat_gemm(
    const float* __restrict__ YS0, const float* __restrict__ YS1,
    const float* __restrict__ acc, const float* __restrict__ sg,
    const float* __restrict__ sbe, const float* __restrict__ sw2,
    const float* __restrict__ sb2, float* __restrict__ SF0, float* __restrict__ SF1) {
  int dir = blockIdx.y;
  const float* ysim = dir ? YS1 : YS0;
  const float* aS = acc + 256 + dir * 128;
  float* sf = dir ? SF1 : SF0;
  __shared__ float Wl[64][65];
  __shared__ float Hl[64][65];
  __shared__ float sc[64], sh[64], bb[64];
  int t = threadIdx.x;
  if (t < 64) {
    float mu = aS[t] / (float)NPTS;
    float var = aS[64 + t] / (float)NPTS - mu * mu;
    float scale = sg[t] * rsqrtf(var + EPSf);
    sc[t] = scale;
    sh[t] = sbe[t] - mu * scale;
    bb[t] = sb2[t];
  }
#pragma unroll
  for (int i = 0; i < 16; i++) {
    int ix = t + i * 256;
    Wl[ix >> 6][ix & 63] = sw2[ix];
  }
  __syncthreads();
  int ptb = blockIdx.x * 64;
#pragma unroll
  for (int i = 0; i < 16; i++) {
    int ix = t + i * 256;
    int row = ix >> 6, col = ix & 63;
    float v = ysim[(size_t)ptb * 64 + ix];
    Hl[row][col] = fmaxf(sc[col] * v + sh[col], 0.f);
  }
  __syncthreads();
  int ty = t >> 4, tx = t & 15, r0 = ty * 4, c0 = tx * 4;
  float acc4[4][4] = {};
#pragma unroll 4
  for (int j = 0; j < 64; ++j) {
    float a[4], w[4];
#pragma unroll
    for (int i = 0; i < 4; i++) a[i] = Hl[r0 + i][j];
#pragma unroll
    for (int m = 0; m < 4; m++) w[m] = Wl[c0 + m][j];
#pragma unroll
    for (int i = 0; i < 4; i++)
#pragma unroll
      for (int m = 0; m < 4; m++) acc4[i][m] += a[i] * w[m];
  }
#pragma unroll
  for (int i = 0; i < 4; i++) {
    float4 v = make_float4(acc4[i][0] + bb[c0], acc4[i][1] + bb[c0 + 1],
                           acc4[i][2] + bb[c0 + 2], acc4[i][3] + bb[c0 + 3]);
    *reinterpret_cast<float4*>(sf + (size_t)(ptb + r0 + i) * 64 + c0) = v;
  }
}

// ---------------- YF = [DF|SF] @ fw1^T + fin BN stats ----------------
__global__ __launch_bounds__(256) void yfin_gemm(
    const float* __restrict__ DF0, const float* __restrict__ DF1,
    const float* __restrict__ SF0, const float* __restrict__ SF1,
    const float* __restrict__ fw1, float* __restrict__ YF0, float* __restrict__ YF1,
    float* __restrict__ acc) {
  int dir = blockIdx.z;
  const float* df = dir ? DF1 : DF0;
  const float* sf = dir ? SF1 : SF0;
  float* yf = dir ? YF1 : YF0;
  float* accF = acc + 512 + dir * 256;
  __shared__ float Wl[64][129];
  __shared__ float Cl[64][65];
  __shared__ float redS[64], redQ[64];
  int t = threadIdx.x;
  int y = blockIdx.y;
  if (t < 64) {
    redS[t] = 0.f;
    redQ[t] = 0.f;
  }
#pragma unroll
  for (int i = 0; i < 32; i++) {
    int ix = t + i * 256;
    Wl[ix >> 7][ix & 127] = fw1[(size_t)(y * 64 + (ix >> 7)) * 128 + (ix & 127)];
  }
  int ptb = blockIdx.x * 64;
#pragma unroll
  for (int i = 0; i < 16; i++) {
    int ix = t + i * 256;
    Cl[ix >> 6][ix & 63] = df[(size_t)ptb * 64 + ix];
  }
  __syncthreads();
  int ty = t >> 4, tx = t & 15, r0 = ty * 4, c0 = tx * 4;
  float acc4[4][4] = {};
#pragma unroll 4
  for (int j = 0; j < 64; ++j) {
    float a[4], w[4];
#pragma unroll
    for (int i = 0; i < 4; i++) a[i] = Cl[r0 + i][j];
#pragma unroll
    for (int m = 0; m < 4; m++) w[m] = Wl[c0 + m][j];
#pragma unroll
    for (int i = 0; i < 4; i++)
#pragma unroll
      for (int m = 0; m < 4; m++) acc4[i][m] += a[i] * w[m];
  }
  __syncthreads();
#pragma unroll
  for (int i = 0; i < 16; i++) {
    int ix = t + i * 256;
    Cl[ix >> 6][ix & 63] = sf[(size_t)ptb * 64 + ix];
  }
  __syncthreads();
#pragma unroll 4
  for (int j = 0; j < 64; ++j) {
    float a[4], w[4];
#pragma unroll
    for (int i = 0; i < 4; i++) a[i] = Cl[r0 + i][j];
#pragma unroll
    for (int m = 0; m < 4; m++) w[m] = Wl[c0 + m][64 + j];
#pragma unroll
    for (int i = 0; i < 4; i++)
#pragma unroll
      for (int m = 0; m < 4; m++) acc4[i][m] += a[i] * w[m];
  }
#pragma unroll
  for (int i = 0; i < 4; i++) {
    float4 v = make_float4(acc4[i][0], acc4[i][1], acc4[i][2], acc4[i][3]);
    *reinterpret_cast<float4*>(yf + (size_t)(ptb + r0 + i) * 128 + y * 64 + c0) = v;
  }
#pragma unroll
  for (int m = 0; m < 4; m++) {
    float s = acc4[0][m] + acc4[1][m] + acc4[2][m] + acc4[3][m];
    float qq = acc4[0][m] * acc4[0][m] + acc4[1][m] * acc4[1][m] +
               acc4[2][m] * acc4[2][m] + acc4[3][m] * acc4[3][m];
    atomicAdd(&redS[c0 + m], s);
    atomicAdd(&redQ[c0 + m], qq);
  }
  __syncthreads();
  if (t < 64) {
    atomicAdd(accF + y * 64 + t, redS[t]);
    atomicAdd(accF + 128 + y * 64 + t, redQ[t]);
  }
}

// ---------------- out = relu(bn(YF)) @ fw2^T + fb2 (finalize2 folded in) ----------
__global__ __launch_bounds__(256) void finout_gemm(
    const float* __restrict__ YF0, const float* __restrict__ YF1,
    const float* __restrict__ acc, const float* __restrict__ fg,
    const float* __restrict__ fbe, const float* __restrict__ fw2,
    const float* __restrict__ fb2, float* __restrict__ out) {
  int dir = blockIdx.y;
  const float* yf = dir ? YF1 : YF0;
  const float* aF = acc + 512 + dir * 256;
  float* outp = out + (size_t)dir * NPTS * 64;
  __shared__ float Wl[64][129];
  __shared__ float Hl[64][65];
  __shared__ float scl[128], shf[128], bb[64];
  int t = threadIdx.x;
  if (t < 128) {
    float mu = aF[t] / (float)NPTS;
    float var = aF[128 + t] / (float)NPTS - mu * mu;
    float scale = fg[t] * rsqrtf(var + EPSf);
    scl[t] = scale;
    shf[t] = fbe[t] - mu * scale;
  }
  if (t < 64) bb[t] = fb2[t];
#pragma unroll
  for (int i = 0; i < 32; i++) {
    int ix = t + i * 256;
    Wl[ix >> 7][ix & 127] = fw2[ix];
  }
  __syncthreads();
  int ptb = blockIdx.x * 64;
  int ty = t >> 4, tx = t & 15, r0 = ty * 4, c0 = tx * 4;
  float acc4[4][4] = {};
#pragma unroll
  for (int i = 0; i < 16; i++) {
    int ix = t + i * 256;
    int row = ix >> 6, jj = ix & 63;
    float v = yf[(size_t)(ptb + row) * 128 + jj];
    Hl[row][jj] = fmaxf(scl[jj] * v + shf[jj], 0.f);
  }
  __syncthreads();
#pragma unroll 4
  for (int j = 0; j < 64; ++j) {
    float a[4], w[4];
#pragma unroll
    for (int i = 0; i < 4; i++) a[i] = Hl[r0 + i][j];
#pragma unroll
    for (int m = 0; m < 4; m++) w[m] = Wl[c0 + m][j];
#pragma unroll
    for (int i = 0; i < 4; i++)
#pragma unroll
      for (int m = 0; m < 4; m++) acc4[i][m] += a[i] * w[m];
  }
  __syncthreads();
#pragma unroll
  for (int i = 0; i < 16; i++) {
    int ix = t + i * 256;
    int row = ix >> 6, jj = ix & 63;
    float v = yf[(size_t)(ptb + row) * 128 + 64 + jj];
    Hl[row][jj] = fmaxf(scl[64 + jj] * v + shf[64 + jj], 0.f);
  }
  __syncthreads();
#pragma unroll 4
  for (int j = 0; j < 64; ++j) {
    float a[4], w[4];
#pragma unroll
    for (int i = 0; i < 4; i++) a[i] = Hl[r0 + i][j];
#pragma unroll
    for (int m = 0; m < 4; m++) w[m] = Wl[c0 + m][64 + j];
#pragma unroll
    for (int i = 0; i < 4; i++)
#pragma unroll
      for (int m = 0; m < 4; m++) acc4[i][m] += a[i] * w[m];
  }
#pragma unroll
  for (int i = 0; i < 4; i++) {
    float4 v = make_float4(acc4[i][0] + bb[c0], acc4[i][1] + bb[c0 + 1],
                           acc4[i][2] + bb[c0 + 2], acc4[i][3] + bb[c0 + 3]);
    *reinterpret_cast<float4*>(outp + (size_t)(ptb + r0 + i) * 64 + c0) = v;
  }
}

extern "C" void kernel_launch(void* const* d_in, const int* in_sizes, int n_in,
                              void* d_out, int out_size, void* d_ws, size_t ws_size,
                              hipStream_t stream) {
  const float* f0 = (const float*)d_in[0];
  const float* f1 = (const float*)d_in[1];
  const int* i01 = (const int*)d_in[2];
  const int* i10 = (const int*)d_in[3];
  const float* dw1 = (const float*)d_in[4];
  const float* dg = (const float*)d_in[6];
  const float* dbe = (const float*)d_in[7];
  const float* dw2 = (const float*)d_in[8];
  const float* db2 = (const float*)d_in[9];
  const float* sw1 = (const float*)d_in[10];
  const float* sg = (const float*)d_in[12];
  const float* sbe = (const float*)d_in[13];
  const float* sw2 = (const float*)d_in[14];
  const float* sb2 = (const float*)d_in[15];
  const float* fw1 = (const float*)d_in[16];
  const float* fg = (const float*)d_in[18];
  const float* fbe = (const float*)d_in[19];
  const float* fw2 = (const float*)d_in[20];
  const float* fb2 = (const float*)d_in[21];

  char* wsb = (char*)d_ws;
  float* out = (float*)d_out;

  char* FT0 = wsb;                            // 16 MB (32768*512)
  char* FT1 = wsb + (size_t)NPTS * FT_STRIDE; // 16 MB
  float* acc = (float*)(wsb + 2 * (size_t)NPTS * FT_STRIDE);  // @32MB
  float* YS0 = (float*)(wsb + 2 * (size_t)NPTS * FT_STRIDE + 65536);
  float* YS1 = YS0 + GSZ;
  float* DF0 = YS1 + GSZ;
  float* DF1 = DF0 + GSZ;
  float* SF0 = DF1 + GSZ;
  float* SF1 = SF0 + GSZ;
  float* YF0 = YS0;         // 16MB over YS0+YS1 (dead after simfeat_gemm)
  float* YF1 = (float*)FT0; // 16MB over FT0 (dead after diff_out_k)

  hipMemsetAsync(acc, 0, 1024 * sizeof(float), stream);
  gemmG<<<dim3(512, 1, 2), 256, 0, stream>>>(f0, f1, dw1, sw1, FT0, FT1);

  stats_sim<<<4096, 256, 0, stream>>>(FT0, FT1, i01, i10, YS0, YS1, acc);

  diff_out_k<<<4096, 256, 0, stream>>>(FT0, FT1, i01, i10, dw2, db2, acc, dg, dbe, DF0, DF1);

  simfeat_gemm<<<dim3(512, 2), 256, 0, stream>>>(YS0, YS1, acc, sg, sbe, sw2, sb2, SF0, SF1);

  yfin_gemm<<<dim3(512, 2, 2), 256, 0, stream>>>(DF0, DF1, SF0, SF1, fw1, YF0, YF1, acc);

  finout_gemm<<<dim3(512, 2), 256, 0, stream>>>(YF0, YF1, acc, fg, fbe, fw2, fb2, out);
}

// Round 15
// 251.606 us; speedup vs baseline: 1.2016x; 1.0344x over previous
//
#include <hip/hip_runtime.h>
#include <hip/hip_fp16.h>

// PointSetDifferenceModule: B=4, N=8192, C=64, K=16
// Round 15: 384B fused rows [f fp16 | gd bf16 | gs bf16]. fp16 f keeps logit
// error ~8x below bf16 (r7's failure); products exact in fp32. Dot via
// v_dot2_f32_f16 over 16 lanes (4-shfl tree). Lanes: 0-15 f, 16-31 gd,
// 32-47 gs, 48-63 pad-read. XCD affinity + folded finalizes retained.

#define Bn 4
#define Nn 8192
#define NPTS (Bn * Nn)        // 32768
#define NSAMP (NPTS * 16)     // 524288
#define EPSf 1e-5f
#define FT_STRIDE 384
#define FTSZ ((size_t)NPTS * FT_STRIDE + 1024)  // +pad for lane48-63 overread
#define GSZ (NPTS * 64)

typedef __attribute__((ext_vector_type(8))) short v8bf;
typedef __attribute__((ext_vector_type(4))) float v4f;
typedef __attribute__((ext_vector_type(2))) _Float16 v2h;

union U2H {
  unsigned u;
  v2h h;
};

__device__ inline unsigned pack_bf16x2(float a, float b) {
  unsigned ua = __float_as_uint(a), ub = __float_as_uint(b);
  ua = (ua + 0x7FFFu + ((ua >> 16) & 1u)) >> 16;
  ub = (ub + 0x7FFFu + ((ub >> 16) & 1u)) >> 16;
  return (ub << 16) | ua;
}
__device__ inline float bf16_lo(unsigned u) { return __uint_as_float(u << 16); }
__device__ inline float bf16_hi(unsigned u) { return __uint_as_float(u & 0xFFFF0000u); }

__device__ inline float dot2acc(unsigned a, unsigned b, float c) {
  U2H ua, ub;
  ua.u = a;
  ub.u = b;
#if __has_builtin(__builtin_amdgcn_fdot2)
  return __builtin_amdgcn_fdot2(ua.h, ub.h, c, false);
#else
  return c + (float)ua.h.x * (float)ub.h.x + (float)ua.h.y * (float)ub.h.y;
#endif
}

// ---------------- build fused tables: f fp16 + G_d, G_s bf16 ----------------
__global__ __launch_bounds__(256) void gemmG(const float* __restrict__ f0,
                                             const float* __restrict__ f1,
                                             const float* __restrict__ wd,
                                             const float* __restrict__ wsim,
                                             char* __restrict__ FT0,
                                             char* __restrict__ FT1) {
  int z = blockIdx.z;
  const float* F = z ? f1 : f0;
  char* FT = z ? FT1 : FT0;
  __shared__ float Fl[64][65];
  __shared__ float Wd[64][65];
  __shared__ float Ws[64][65];
  int t = threadIdx.x;
#pragma unroll
  for (int i = 0; i < 16; i++) {
    int ix = t + i * 256;
    Wd[ix >> 6][ix & 63] = wd[ix];
    Ws[ix >> 6][ix & 63] = wsim[ix];
  }
  int ptb = blockIdx.x * 64;
#pragma unroll
  for (int i = 0; i < 8; i++) {
    int pr = t + i * 256;  // pair index 0..2047
    int row = pr >> 5, c2 = pr & 31;
    float2 v = *(const float2*)(F + (size_t)(ptb + row) * 64 + c2 * 2);
    Fl[row][c2 * 2] = v.x;
    Fl[row][c2 * 2 + 1] = v.y;
    __half2 h2 = __floats2half2_rn(v.x, v.y);
    *(unsigned*)(FT + (size_t)(ptb + row) * FT_STRIDE + c2 * 4) =
        *reinterpret_cast<unsigned*>(&h2);
  }
  __syncthreads();
  int ty = t >> 4, tx = t & 15, r0 = ty * 4, c0 = tx * 4;
  float ad[4][4] = {}, as_[4][4] = {};
#pragma unroll 4
  for (int j = 0; j < 64; ++j) {
    float a[4], w1[4], w2[4];
#pragma unroll
    for (int i = 0; i < 4; i++) a[i] = Fl[r0 + i][j];
#pragma unroll
    for (int m = 0; m < 4; m++) {
      w1[m] = Wd[c0 + m][j];
      w2[m] = Ws[c0 + m][j];
    }
#pragma unroll
    for (int i = 0; i < 4; i++)
#pragma unroll
      for (int m = 0; m < 4; m++) {
        ad[i][m] += a[i] * w1[m];
        as_[i][m] += a[i] * w2[m];
      }
  }
#pragma unroll
  for (int i = 0; i < 4; i++) {
    char* row = FT + (size_t)(ptb + r0 + i) * FT_STRIDE;
    uint2 gd2 = make_uint2(pack_bf16x2(ad[i][0], ad[i][1]),
                           pack_bf16x2(ad[i][2], ad[i][3]));
    *(uint2*)(row + 128 + c0 * 2) = gd2;
    uint2 gs2 = make_uint2(pack_bf16x2(as_[i][0], as_[i][1]),
                           pack_bf16x2(as_[i][2], as_[i][3]));
    *(uint2*)(row + 256 + c0 * 2) = gs2;
  }
}

// ---------------- diff stats + sim softmax + y_sim (one wave per point) ----------
// lanes 0-15: f fp16 x4 | 16-31: gd bf16 x4 | 32-47: gs bf16 x4 | 48-63: pad
__global__ __launch_bounds__(256) void stats_sim(
    const char* __restrict__ FT0, const char* __restrict__ FT1,
    const int* __restrict__ i01, const int* __restrict__ i10,
    float* __restrict__ YS0, float* __restrict__ YS1, float* __restrict__ acc) {
  int u = blockIdx.x & 7;
  int dir = u & 1, batch = u >> 1;
  const char* FS = dir ? FT1 : FT0;
  const char* FO = dir ? FT0 : FT1;
  const int* idx = dir ? i10 : i01;
  float* ys = dir ? YS1 : YS0;
  float* accDiff = acc + dir * 128;
  float* accSim = acc + 256 + dir * 128;
  int lane = threadIdx.x & 63, wave = threadIdx.x >> 6;
  int w = blockIdx.x >> 3;              // 0..511
  int gw = w * 4 + wave;                // 0..2047
  int ptbase = batch * Nn + gw * 4;     // 4 consecutive points per wave
  int bbase = batch * Nn;
  bool isD = (lane >= 16) && (lane < 32);
  bool isS = (lane >= 32) && (lane < 48);
  int lq = lane & 15;
  float sdl[4] = {0, 0, 0, 0}, qdl[4] = {0, 0, 0, 0};
  float ssl[4] = {0, 0, 0, 0}, qsl[4] = {0, 0, 0, 0};
#pragma unroll 1
  for (int pi = 0; pi < 4; pi++) {
    int ptu = ptbase + pi;  // wave-uniform
    const char* srow = FS + (size_t)ptu * FT_STRIDE;
    uint2 selfr = *(const uint2*)(srow + lane * 8);
    const int* ip = idx + ptu * 16;
    int jx[16];
#pragma unroll
    for (int k = 0; k < 16; k++) jx[k] = ip[k];
    const char* ob = FO + (size_t)bbase * FT_STRIDE;
    uint2 nb[16];
#pragma unroll
    for (int k = 0; k < 16; k++)
      nb[k] = *(const uint2*)(ob + (size_t)jx[k] * FT_STRIDE + lane * 8);
    // loop 1: 16 independent dot trees (fp16 dot2, 16-lane reduce) + S1/S2 stats
    float sims[16];
    float S10 = 0.f, S11 = 0.f, S12 = 0.f, S13 = 0.f;
    float S20 = 0.f, S21 = 0.f, S22 = 0.f, S23 = 0.f;
#pragma unroll
    for (int k = 0; k < 16; k++) {
      float p = dot2acc(selfr.y, nb[k].y, dot2acc(selfr.x, nb[k].x, 0.f));
      p += __shfl_xor(p, 8);
      p += __shfl_xor(p, 4);
      p += __shfl_xor(p, 2);
      p += __shfl_xor(p, 1);
      sims[k] = __uint_as_float(__builtin_amdgcn_readfirstlane(__float_as_uint(p)));
      float g0 = bf16_lo(nb[k].x), g1 = bf16_hi(nb[k].x);
      float g2 = bf16_lo(nb[k].y), g3 = bf16_hi(nb[k].y);
      S10 += g0; S11 += g1; S12 += g2; S13 += g3;
      S20 += g0 * g0; S21 += g1 * g1; S22 += g2 * g2; S23 += g3 * g3;
    }
    // loop 2: exp (no max shift; |logit| << 88) + softmax numerators
    float den = 0.f, ya0 = 0.f, ya1 = 0.f, ya2 = 0.f, ya3 = 0.f;
#pragma unroll
    for (int k = 0; k < 16; k++) {
      float e = __expf(sims[k]);
      den += e;
      ya0 += e * bf16_lo(nb[k].x);
      ya1 += e * bf16_hi(nb[k].x);
      ya2 += e * bf16_lo(nb[k].y);
      ya3 += e * bf16_hi(nb[k].y);
    }
    float inv = 1.f / den;
    ya0 *= inv; ya1 *= inv; ya2 *= inv; ya3 *= inv;
    if (isS)
      *(float4*)(ys + (size_t)ptu * 64 + lq * 4) = make_float4(ya0, ya1, ya2, ya3);
    ssl[0] += ya0; qsl[0] += ya0 * ya0;
    ssl[1] += ya1; qsl[1] += ya1 * ya1;
    ssl[2] += ya2; qsl[2] += ya2 * ya2;
    ssl[3] += ya3; qsl[3] += ya3 * ya3;
    // diff-stat epilogue (valid in isD lanes): Sum(gds-gdo) = 16*gds - S1;
    // Sum((gds-gdo)^2) = 16*gds^2 - 2*gds*S1 + S2
    float gds0 = bf16_lo(selfr.x), gds1 = bf16_hi(selfr.x);
    float gds2 = bf16_lo(selfr.y), gds3 = bf16_hi(selfr.y);
    sdl[0] += 16.f * gds0 - S10;
    sdl[1] += 16.f * gds1 - S11;
    sdl[2] += 16.f * gds2 - S12;
    sdl[3] += 16.f * gds3 - S13;
    qdl[0] += 16.f * gds0 * gds0 - 2.f * gds0 * S10 + S20;
    qdl[1] += 16.f * gds1 * gds1 - 2.f * gds1 * S11 + S21;
    qdl[2] += 16.f * gds2 * gds2 - 2.f * gds2 * S12 + S22;
    qdl[3] += 16.f * gds3 * gds3 - 2.f * gds3 * S13 + S23;
  }
  __shared__ float rA[4][64], rB[4][64], rC[4][64], rD2[4][64];
  int cd = lq * 4;
  if (isD) {
#pragma unroll
    for (int i = 0; i < 4; i++) {
      rA[wave][cd + i] = sdl[i];
      rB[wave][cd + i] = qdl[i];
    }
  }
  if (isS) {
#pragma unroll
    for (int i = 0; i < 4; i++) {
      rC[wave][cd + i] = ssl[i];
      rD2[wave][cd + i] = qsl[i];
    }
  }
  __syncthreads();
  if (wave == 0) {
    float v = rA[0][lane] + rA[1][lane] + rA[2][lane] + rA[3][lane];
    atomicAdd(accDiff + lane, v);
    v = rB[0][lane] + rB[1][lane] + rB[2][lane] + rB[3][lane];
    atomicAdd(accDiff + 64 + lane, v);
    v = rC[0][lane] + rC[1][lane] + rC[2][lane] + rC[3][lane];
    atomicAdd(accSim + lane, v);
    v = rD2[0][lane] + rD2[1][lane] + rD2[2][lane] + rD2[3][lane];
    atomicAdd(accSim + 64 + lane, v);
  }
}

// ---------------- diff output: gather bf16 + BN/relu + MFMA GEMM + max over K --------
// finalize1(diff) folded in: each block computes scale/shift from raw acc.
__global__ __launch_bounds__(256) void diff_out_k(
    const char* __restrict__ FT0, const char* __restrict__ FT1,
    const int* __restrict__ i01, const int* __restrict__ i10,
    const float* __restrict__ w2d, const float* __restrict__ b2d,
    const float* __restrict__ acc, const float* __restrict__ dg,
    const float* __restrict__ dbe, float* __restrict__ DF0, float* __restrict__ DF1) {
  int u = blockIdx.x & 7;
  int dir = u & 1, batch = u >> 1;
  const char* FS = dir ? FT1 : FT0;
  const char* FO = dir ? FT0 : FT1;
  const int* idx = dir ? i10 : i01;
  const float* aD = acc + dir * 128;
  float* dout = dir ? DF1 : DF0;
  __shared__ __align__(16) unsigned WlU[64 * 36];
  __shared__ __align__(16) unsigned HtU[64 * 36];
  __shared__ unsigned Gs[4][32];
  __shared__ int idxt[64];
  __shared__ float sc[64], sh[64], bb[64];
  int t = threadIdx.x;
  int r = t >> 2, q = t & 3;
  {
    const float4* w4 = (const float4*)(w2d + r * 64 + q * 16);
#pragma unroll
    for (int uu = 0; uu < 4; uu++) {
      float4 v = w4[uu];
      WlU[r * 36 + q * 8 + uu * 2] = pack_bf16x2(v.x, v.y);
      WlU[r * 36 + q * 8 + uu * 2 + 1] = pack_bf16x2(v.z, v.w);
    }
  }
  if (t < 64) {
    float mu = aD[t] / (float)NSAMP;
    float var = aD[64 + t] / (float)NSAMP - mu * mu;
    float scale = dg[t] * rsqrtf(var + EPSf);
    sc[t] = scale;
    sh[t] = dbe[t] - mu * scale;
    bb[t] = b2d[t];
  }
  int wave = t >> 6, lane = t & 63;
  int lr = lane & 15, lg = lane >> 4;
  int p = r >> 4;
  int wblk = blockIdx.x >> 3;  // 0..511
  int bbase = batch * Nn;
#pragma unroll 1
  for (int tt = 0; tt < 4; tt++) {
    int tile = wblk * 4 + tt;          // 0..2047 within batch
    int ptb = batch * Nn + tile * 4;
    __syncthreads();
    if (t < 64) idxt[t] = idx[ptb * 16 + t];
    if (t < 128)
      Gs[t >> 5][t & 31] =
          *(const unsigned*)(FS + (size_t)(ptb + (t >> 5)) * FT_STRIDE + 128 + (t & 31) * 4);
    __syncthreads();
    const char* orow = FO + (size_t)(bbase + idxt[r]) * FT_STRIDE + 128;
    uint4 g0 = *(const uint4*)(orow + q * 32);
    uint4 g1 = *(const uint4*)(orow + q * 32 + 16);
#pragma unroll
    for (int uu = 0; uu < 8; uu++) {
      unsigned gdo2 = (uu < 4) ? ((const unsigned*)&g0)[uu] : ((const unsigned*)&g1)[uu - 4];
      unsigned gds2 = Gs[p][q * 8 + uu];
      int c = q * 16 + uu * 2;
      float h0 = fmaxf(sc[c] * (bf16_lo(gds2) - bf16_lo(gdo2)) + sh[c], 0.f);
      float h1 = fmaxf(sc[c + 1] * (bf16_hi(gds2) - bf16_hi(gdo2)) + sh[c + 1], 0.f);
      HtU[r * 36 + q * 8 + uu] = pack_bf16x2(h0, h1);
    }
    __syncthreads();
    v4f acc4[4] = {{0, 0, 0, 0}, {0, 0, 0, 0}, {0, 0, 0, 0}, {0, 0, 0, 0}};
    v8bf a0 = *(const v8bf*)&HtU[(wave * 16 + lr) * 36 + lg * 4];
    v8bf a1 = *(const v8bf*)&HtU[(wave * 16 + lr) * 36 + 16 + lg * 4];
#pragma unroll
    for (int c = 0; c < 4; c++) {
      v8bf b0 = *(const v8bf*)&WlU[(c * 16 + lr) * 36 + lg * 4];
      v8bf b1 = *(const v8bf*)&WlU[(c * 16 + lr) * 36 + 16 + lg * 4];
      acc4[c] = __builtin_amdgcn_mfma_f32_16x16x32_bf16(a0, b0, acc4[c], 0, 0, 0);
      acc4[c] = __builtin_amdgcn_mfma_f32_16x16x32_bf16(a1, b1, acc4[c], 0, 0, 0);
    }
#pragma unroll
    for (int c = 0; c < 4; c++) {
      float mm = fmaxf(fmaxf(acc4[c][0], acc4[c][1]), fmaxf(acc4[c][2], acc4[c][3]));
      mm = fmaxf(mm, __shfl_xor(mm, 16));
      mm = fmaxf(mm, __shfl_xor(mm, 32));
      if (lane < 16) dout[(size_t)(ptb + wave) * 64 + c * 16 + lane] = mm + bb[c * 16 + lane];
    }
  }
}

// ---------------- SF = relu(bn(YS)) @ sw2^T + sb2 (finalize1-sim folded in) -------
__global__ __launch_bounds__(256) void simfeat_gemm(
    const float* __restrict__ YS0, const float* __restrict__ YS1,
    const float* __restrict__ acc, const float* __restrict__ sg,
    const float* __restrict__ sbe, const float* __restrict__ sw2,
    const float* __restrict__ sb2, float* __restrict__ SF0, float* __restrict__ SF1) {
  int dir = blockIdx.y;
  const float* ysim = dir ? YS1 : YS0;
  const float* aS = acc + 256 + dir * 128;
  float* sf = dir ? SF1 : SF0;
  __shared__ float Wl[64][65];
  __shared__ float Hl[64][65];
  __shared__ float sc[64], sh[64], bb[64];
  int t = threadIdx.x;
  if (t < 64) {
    float mu = aS[t] / (float)NPTS;
    float var = aS[64 + t] / (float)NPTS - mu * mu;
    float scale = sg[t] * rsqrtf(var + EPSf);
    sc[t] = scale;
    sh[t] = sbe[t] - mu * scale;
    bb[t] = sb2[t];
  }
#pragma unroll
  for (int i = 0; i < 16; i++) {
    int ix = t + i * 256;
    Wl[ix >> 6][ix & 63] = sw2[ix];
  }
  __syncthreads();
  int ptb = blockIdx.x * 64;
#pragma unroll
  for (int i = 0; i < 16; i++) {
    int ix = t + i * 256;
    int row = ix >> 6, col = ix & 63;
    float v = ysim[(size_t)ptb * 64 + ix];
    Hl[row][col] = fmaxf(sc[col] * v + sh[col], 0.f);
  }
  __syncthreads();
  int ty = t >> 4, tx = t & 15, r0 = ty * 4, c0 = tx * 4;
  float acc4[4][4] = {};
#pragma unroll 4
  for (int j = 0; j < 64; ++j) {
    float a[4], w[4];
#pragma unroll
    for (int i = 0; i < 4; i++) a[i] = Hl[r0 + i][j];
#pragma unroll
    for (int m = 0; m < 4; m++) w[m] = Wl[c0 + m][j];
#pragma unroll
    for (int i = 0; i < 4; i++)
#pragma unroll
      for (int m = 0; m < 4; m++) acc4[i][m] += a[i] * w[m];
  }
#pragma unroll
  for (int i = 0; i < 4; i++) {
    float4 v = make_float4(acc4[i][0] + bb[c0], acc4[i][1] + bb[c0 + 1],
                           acc4[i][2] + bb[c0 + 2], acc4[i][3] + bb[c0 + 3]);
    *reinterpret_cast<float4*>(sf + (size_t)(ptb + r0 + i) * 64 + c0) = v;
  }
}

// ---------------- YF = [DF|SF] @ fw1^T + fin BN stats ----------------
__global__ __launch_bounds__(256) void yfin_gemm(
    const float* __restrict__ DF0, const float* __restrict__ DF1,
    const float* __restrict__ SF0, const float* __restrict__ SF1,
    const float* __restrict__ fw1, float* __restrict__ YF0, float* __restrict__ YF1,
    float* __restrict__ acc) {
  int dir = blockIdx.z;
  const float* df = dir ? DF1 : DF0;
  const float* sf = dir ? SF1 : SF0;
  float* yf = dir ? YF1 : YF0;
  float* accF = acc + 512 + dir * 256;
  __shared__ float Wl[64][129];
  __shared__ float Cl[64][65];
  __shared__ float redS[64], redQ[64];
  int t = threadIdx.x;
  int y = blockIdx.y;
  if (t < 64) {
    redS[t] = 0.f;
    redQ[t] = 0.f;
  }
#pragma unroll
  for (int i = 0; i < 32; i++) {
    int ix = t + i * 256;
    Wl[ix >> 7][ix & 127] = fw1[(size_t)(y * 64 + (ix >> 7)) * 128 + (ix & 127)];
  }
  int ptb = blockIdx.x * 64;
#pragma unroll
  for (int i = 0; i < 16; i++) {
    int ix = t + i * 256;
    Cl[ix >> 6][ix & 63] = df[(size_t)ptb * 64 + ix];
  }
  __syncthreads();
  int ty = t >> 4, tx = t & 15, r0 = ty * 4, c0 = tx * 4;
  float acc4[4][4] = {};
#pragma unroll 4
  for (int j = 0; j < 64; ++j) {
    float a[4], w[4];
#pragma unroll
    for (int i = 0; i < 4; i++) a[i] = Cl[r0 + i][j];
#pragma unroll
    for (int m = 0; m < 4; m++) w[m] = Wl[c0 + m][j];
#pragma unroll
    for (int i = 0; i < 4; i++)
#pragma unroll
      for (int m = 0; m < 4; m++) acc4[i][m] += a[i] * w[m];
  }
  __syncthreads();
#pragma unroll
  for (int i = 0; i < 16; i++) {
    int ix = t + i * 256;
    Cl[ix >> 6][ix & 63] = sf[(size_t)ptb * 64 + ix];
  }
  __syncthreads();
#pragma unroll 4
  for (int j = 0; j < 64; ++j) {
    float a[4], w[4];
#pragma unroll
    for (int i = 0; i < 4; i++) a[i] = Cl[r0 + i][j];
#pragma unroll
    for (int m = 0; m < 4; m++) w[m] = Wl[c0 + m][64 + j];
#pragma unroll
    for (int i = 0; i < 4; i++)
#pragma unroll
      for (int m = 0; m < 4; m++) acc4[i][m] += a[i] * w[m];
  }
#pragma unroll
  for (int i = 0; i < 4; i++) {
    float4 v = make_float4(acc4[i][0], acc4[i][1], acc4[i][2], acc4[i][3]);
    *reinterpret_cast<float4*>(yf + (size_t)(ptb + r0 + i) * 128 + y * 64 + c0) = v;
  }
#pragma unroll
  for (int m = 0; m < 4; m++) {
    float s = acc4[0][m] + acc4[1][m] + acc4[2][m] + acc4[3][m];
    float qq = acc4[0][m] * acc4[0][m] + acc4[1][m] * acc4[1][m] +
               acc4[2][m] * acc4[2][m] + acc4[3][m] * acc4[3][m];
    atomicAdd(&redS[c0 + m], s);
    atomicAdd(&redQ[c0 + m], qq);
  }
  __syncthreads();
  if (t < 64) {
    atomicAdd(accF + y * 64 + t, redS[t]);
    atomicAdd(accF + 128 + y * 64 + t, redQ[t]);
  }
}

// ---------------- out = relu(bn(YF)) @ fw2^T + fb2 (finalize2 folded in) ----------
__global__ __launch_bounds__(256) void finout_gemm(
    const float* __restrict__ YF0, const float* __restrict__ YF1,
    const float* __restrict__ acc, const float* __restrict__ fg,
    const float* __restrict__ fbe, const float* __restrict__ fw2,
    const float* __restrict__ fb2, float* __restrict__ out) {
  int dir = blockIdx.y;
  const float* yf = dir ? YF1 : YF0;
  const float* aF = acc + 512 + dir * 256;
  float* outp = out + (size_t)dir * NPTS * 64;
  __shared__ float Wl[64][129];
  __shared__ float Hl[64][65];
  __shared__ float scl[128], shf[128], bb[64];
  int t = threadIdx.x;
  if (t < 128) {
    float mu = aF[t] / (float)NPTS;
    float var = aF[128 + t] / (float)NPTS - mu * mu;
    float scale = fg[t] * rsqrtf(var + EPSf);
    scl[t] = scale;
    shf[t] = fbe[t] - mu * scale;
  }
  if (t < 64) bb[t] = fb2[t];
#pragma unroll
  for (int i = 0; i < 32; i++) {
    int ix = t + i * 256;
    Wl[ix >> 7][ix & 127] = fw2[ix];
  }
  __syncthreads();
  int ptb = blockIdx.x * 64;
  int ty = t >> 4, tx = t & 15, r0 = ty * 4, c0 = tx * 4;
  float acc4[4][4] = {};
#pragma unroll
  for (int i = 0; i < 16; i++) {
    int ix = t + i * 256;
    int row = ix >> 6, jj = ix & 63;
    float v = yf[(size_t)(ptb + row) * 128 + jj];
    Hl[row][jj] = fmaxf(scl[jj] * v + shf[jj], 0.f);
  }
  __syncthreads();
#pragma unroll 4
  for (int j = 0; j < 64; ++j) {
    float a[4], w[4];
#pragma unroll
    for (int i = 0; i < 4; i++) a[i] = Hl[r0 + i][j];
#pragma unroll
    for (int m = 0; m < 4; m++) w[m] = Wl[c0 + m][j];
#pragma unroll
    for (int i = 0; i < 4; i++)
#pragma unroll
      for (int m = 0; m < 4; m++) acc4[i][m] += a[i] * w[m];
  }
  __syncthreads();
#pragma unroll
  for (int i = 0; i < 16; i++) {
    int ix = t + i * 256;
    int row = ix >> 6, jj = ix & 63;
    float v = yf[(size_t)(ptb + row) * 128 + 64 + jj];
    Hl[row][jj] = fmaxf(scl[64 + jj] * v + shf[64 + jj], 0.f);
  }
  __syncthreads();
#pragma unroll 4
  for (int j = 0; j < 64; ++j) {
    float a[4], w[4];
#pragma unroll
    for (int i = 0; i < 4; i++) a[i] = Hl[r0 + i][j];
#pragma unroll
    for (int m = 0; m < 4; m++) w[m] = Wl[c0 + m][64 + j];
#pragma unroll
    for (int i = 0; i < 4; i++)
#pragma unroll
      for (int m = 0; m < 4; m++) acc4[i][m] += a[i] * w[m];
  }
#pragma unroll
  for (int i = 0; i < 4; i++) {
    float4 v = make_float4(acc4[i][0] + bb[c0], acc4[i][1] + bb[c0 + 1],
                           acc4[i][2] + bb[c0 + 2], acc4[i][3] + bb[c0 + 3]);
    *reinterpret_cast<float4*>(outp + (size_t)(ptb + r0 + i) * 64 + c0) = v;
  }
}

extern "C" void kernel_launch(void* const* d_in, const int* in_sizes, int n_in,
                              void* d_out, int out_size, void* d_ws, size_t ws_size,
                              hipStream_t stream) {
  const float* f0 = (const float*)d_in[0];
  const float* f1 = (const float*)d_in[1];
  const int* i01 = (const int*)d_in[2];
  const int* i10 = (const int*)d_in[3];
  const float* dw1 = (const float*)d_in[4];
  const float* dg = (const float*)d_in[6];
  const float* dbe = (const float*)d_in[7];
  const float* dw2 = (const float*)d_in[8];
  const float* db2 = (const float*)d_in[9];
  const float* sw1 = (const float*)d_in[10];
  const float* sg = (const float*)d_in[12];
  const float* sbe = (const float*)d_in[13];
  const float* sw2 = (const float*)d_in[14];
  const float* sb2 = (const float*)d_in[15];
  const float* fw1 = (const float*)d_in[16];
  const float* fg = (const float*)d_in[18];
  const float* fbe = (const float*)d_in[19];
  const float* fw2 = (const float*)d_in[20];
  const float* fb2 = (const float*)d_in[21];

  char* wsb = (char*)d_ws;
  float* out = (float*)d_out;

  char* FT0 = wsb;                 // 12 MB + pad
  char* FT1 = wsb + FTSZ;          // 12 MB + pad
  float* acc = (float*)(wsb + 2 * FTSZ);
  float* YS0 = (float*)(wsb + 2 * FTSZ + 65536);
  float* YS1 = YS0 + GSZ;
  float* DF0 = YS1 + GSZ;
  float* DF1 = DF0 + GSZ;
  float* SF0 = DF1 + GSZ;
  float* SF1 = SF0 + GSZ;
  float* YF0 = YS0;          // 16MB over YS0+YS1 (dead after simfeat_gemm)
  float* YF1 = (float*)wsb;  // 16MB over FT0+FT1 (dead after diff_out_k)

  hipMemsetAsync(acc, 0, 1024 * sizeof(float), stream);
  gemmG<<<dim3(512, 1, 2), 256, 0, stream>>>(f0, f1, dw1, sw1, FT0, FT1);

  stats_sim<<<4096, 256, 0, stream>>>(FT0, FT1, i01, i10, YS0, YS1, acc);

  diff_out_k<<<4096, 256, 0, stream>>>(FT0, FT1, i01, i10, dw2, db2, acc, dg, dbe, DF0, DF1);

  simfeat_gemm<<<dim3(512, 2), 256, 0, stream>>>(YS0, YS1, acc, sg, sbe, sw2, sb2, SF0, SF1);

  yfin_gemm<<<dim3(512, 2, 2), 256, 0, stream>>>(DF0, DF1, SF0, SF1, fw1, YF0, YF1, acc);

  finout_gemm<<<dim3(512, 2), 256, 0, stream>>>(YF0, YF1, acc, fg, fbe, fw2, fb2, out);
}

// Round 16
// 238.677 us; speedup vs baseline: 1.2667x; 1.0542x over previous
//
#include <hip/hip_runtime.h>
#include <hip/hip_fp16.h>

// PointSetDifferenceModule: B=4, N=8192, C=64, K=16
// Round 16: yfin_gemm restructured — shfl-based stat reduction (no LDS atomics,
// which were 6.3M bank-conflict cycles) + two-phase Wl[64][65] (LDS 50->35KB,
// occupancy 25->~50%). Everything else identical to round 15.
// FT row (384B): [ f fp16 x64 | G_d bf16 x64 | G_s bf16 x64 ]

#define Bn 4
#define Nn 8192
#define NPTS (Bn * Nn)        // 32768
#define NSAMP (NPTS * 16)     // 524288
#define EPSf 1e-5f
#define FT_STRIDE 384
#define FTSZ ((size_t)NPTS * FT_STRIDE + 1024)
#define GSZ (NPTS * 64)

typedef __attribute__((ext_vector_type(8))) short v8bf;
typedef __attribute__((ext_vector_type(4))) float v4f;
typedef __attribute__((ext_vector_type(2))) _Float16 v2h;

union U2H {
  unsigned u;
  v2h h;
};

__device__ inline unsigned pack_bf16x2(float a, float b) {
  unsigned ua = __float_as_uint(a), ub = __float_as_uint(b);
  ua = (ua + 0x7FFFu + ((ua >> 16) & 1u)) >> 16;
  ub = (ub + 0x7FFFu + ((ub >> 16) & 1u)) >> 16;
  return (ub << 16) | ua;
}
__device__ inline float bf16_lo(unsigned u) { return __uint_as_float(u << 16); }
__device__ inline float bf16_hi(unsigned u) { return __uint_as_float(u & 0xFFFF0000u); }

__device__ inline float dot2acc(unsigned a, unsigned b, float c) {
  U2H ua, ub;
  ua.u = a;
  ub.u = b;
#if __has_builtin(__builtin_amdgcn_fdot2)
  return __builtin_amdgcn_fdot2(ua.h, ub.h, c, false);
#else
  return c + (float)ua.h.x * (float)ub.h.x + (float)ua.h.y * (float)ub.h.y;
#endif
}

// ---------------- build fused tables: f fp16 + G_d, G_s bf16 ----------------
__global__ __launch_bounds__(256) void gemmG(const float* __restrict__ f0,
                                             const float* __restrict__ f1,
                                             const float* __restrict__ wd,
                                             const float* __restrict__ wsim,
                                             char* __restrict__ FT0,
                                             char* __restrict__ FT1) {
  int z = blockIdx.z;
  const float* F = z ? f1 : f0;
  char* FT = z ? FT1 : FT0;
  __shared__ float Fl[64][65];
  __shared__ float Wd[64][65];
  __shared__ float Ws[64][65];
  int t = threadIdx.x;
#pragma unroll
  for (int i = 0; i < 16; i++) {
    int ix = t + i * 256;
    Wd[ix >> 6][ix & 63] = wd[ix];
    Ws[ix >> 6][ix & 63] = wsim[ix];
  }
  int ptb = blockIdx.x * 64;
#pragma unroll
  for (int i = 0; i < 8; i++) {
    int pr = t + i * 256;  // pair index 0..2047
    int row = pr >> 5, c2 = pr & 31;
    float2 v = *(const float2*)(F + (size_t)(ptb + row) * 64 + c2 * 2);
    Fl[row][c2 * 2] = v.x;
    Fl[row][c2 * 2 + 1] = v.y;
    __half2 h2 = __floats2half2_rn(v.x, v.y);
    *(unsigned*)(FT + (size_t)(ptb + row) * FT_STRIDE + c2 * 4) =
        *reinterpret_cast<unsigned*>(&h2);
  }
  __syncthreads();
  int ty = t >> 4, tx = t & 15, r0 = ty * 4, c0 = tx * 4;
  float ad[4][4] = {}, as_[4][4] = {};
#pragma unroll 4
  for (int j = 0; j < 64; ++j) {
    float a[4], w1[4], w2[4];
#pragma unroll
    for (int i = 0; i < 4; i++) a[i] = Fl[r0 + i][j];
#pragma unroll
    for (int m = 0; m < 4; m++) {
      w1[m] = Wd[c0 + m][j];
      w2[m] = Ws[c0 + m][j];
    }
#pragma unroll
    for (int i = 0; i < 4; i++)
#pragma unroll
      for (int m = 0; m < 4; m++) {
        ad[i][m] += a[i] * w1[m];
        as_[i][m] += a[i] * w2[m];
      }
  }
#pragma unroll
  for (int i = 0; i < 4; i++) {
    char* row = FT + (size_t)(ptb + r0 + i) * FT_STRIDE;
    uint2 gd2 = make_uint2(pack_bf16x2(ad[i][0], ad[i][1]),
                           pack_bf16x2(ad[i][2], ad[i][3]));
    *(uint2*)(row + 128 + c0 * 2) = gd2;
    uint2 gs2 = make_uint2(pack_bf16x2(as_[i][0], as_[i][1]),
                           pack_bf16x2(as_[i][2], as_[i][3]));
    *(uint2*)(row + 256 + c0 * 2) = gs2;
  }
}

// ---------------- diff stats + sim softmax + y_sim (one wave per point) ----------
// lanes 0-15: f fp16 x4 | 16-31: gd bf16 x4 | 32-47: gs bf16 x4 | 48-63: pad
__global__ __launch_bounds__(256) void stats_sim(
    const char* __restrict__ FT0, const char* __restrict__ FT1,
    const int* __restrict__ i01, const int* __restrict__ i10,
    float* __restrict__ YS0, float* __restrict__ YS1, float* __restrict__ acc) {
  int u = blockIdx.x & 7;
  int dir = u & 1, batch = u >> 1;
  const char* FS = dir ? FT1 : FT0;
  const char* FO = dir ? FT0 : FT1;
  const int* idx = dir ? i10 : i01;
  float* ys = dir ? YS1 : YS0;
  float* accDiff = acc + dir * 128;
  float* accSim = acc + 256 + dir * 128;
  int lane = threadIdx.x & 63, wave = threadIdx.x >> 6;
  int w = blockIdx.x >> 3;              // 0..511
  int gw = w * 4 + wave;                // 0..2047
  int ptbase = batch * Nn + gw * 4;     // 4 consecutive points per wave
  int bbase = batch * Nn;
  bool isD = (lane >= 16) && (lane < 32);
  bool isS = (lane >= 32) && (lane < 48);
  int lq = lane & 15;
  float sdl[4] = {0, 0, 0, 0}, qdl[4] = {0, 0, 0, 0};
  float ssl[4] = {0, 0, 0, 0}, qsl[4] = {0, 0, 0, 0};
#pragma unroll 1
  for (int pi = 0; pi < 4; pi++) {
    int ptu = ptbase + pi;  // wave-uniform
    const char* srow = FS + (size_t)ptu * FT_STRIDE;
    uint2 selfr = *(const uint2*)(srow + lane * 8);
    const int* ip = idx + ptu * 16;
    int jx[16];
#pragma unroll
    for (int k = 0; k < 16; k++) jx[k] = ip[k];
    const char* ob = FO + (size_t)bbase * FT_STRIDE;
    uint2 nb[16];
#pragma unroll
    for (int k = 0; k < 16; k++)
      nb[k] = *(const uint2*)(ob + (size_t)jx[k] * FT_STRIDE + lane * 8);
    // loop 1: 16 independent dot trees (fp16 dot2, 16-lane reduce) + S1/S2 stats
    float sims[16];
    float S10 = 0.f, S11 = 0.f, S12 = 0.f, S13 = 0.f;
    float S20 = 0.f, S21 = 0.f, S22 = 0.f, S23 = 0.f;
#pragma unroll
    for (int k = 0; k < 16; k++) {
      float p = dot2acc(selfr.y, nb[k].y, dot2acc(selfr.x, nb[k].x, 0.f));
      p += __shfl_xor(p, 8);
      p += __shfl_xor(p, 4);
      p += __shfl_xor(p, 2);
      p += __shfl_xor(p, 1);
      sims[k] = __uint_as_float(__builtin_amdgcn_readfirstlane(__float_as_uint(p)));
      float g0 = bf16_lo(nb[k].x), g1 = bf16_hi(nb[k].x);
      float g2 = bf16_lo(nb[k].y), g3 = bf16_hi(nb[k].y);
      S10 += g0; S11 += g1; S12 += g2; S13 += g3;
      S20 += g0 * g0; S21 += g1 * g1; S22 += g2 * g2; S23 += g3 * g3;
    }
    // loop 2: exp (no max shift; |logit| << 88) + softmax numerators
    float den = 0.f, ya0 = 0.f, ya1 = 0.f, ya2 = 0.f, ya3 = 0.f;
#pragma unroll
    for (int k = 0; k < 16; k++) {
      float e = __expf(sims[k]);
      den += e;
      ya0 += e * bf16_lo(nb[k].x);
      ya1 += e * bf16_hi(nb[k].x);
      ya2 += e * bf16_lo(nb[k].y);
      ya3 += e * bf16_hi(nb[k].y);
    }
    float inv = 1.f / den;
    ya0 *= inv; ya1 *= inv; ya2 *= inv; ya3 *= inv;
    if (isS)
      *(float4*)(ys + (size_t)ptu * 64 + lq * 4) = make_float4(ya0, ya1, ya2, ya3);
    ssl[0] += ya0; qsl[0] += ya0 * ya0;
    ssl[1] += ya1; qsl[1] += ya1 * ya1;
    ssl[2] += ya2; qsl[2] += ya2 * ya2;
    ssl[3] += ya3; qsl[3] += ya3 * ya3;
    float gds0 = bf16_lo(selfr.x), gds1 = bf16_hi(selfr.x);
    float gds2 = bf16_lo(selfr.y), gds3 = bf16_hi(selfr.y);
    sdl[0] += 16.f * gds0 - S10;
    sdl[1] += 16.f * gds1 - S11;
    sdl[2] += 16.f * gds2 - S12;
    sdl[3] += 16.f * gds3 - S13;
    qdl[0] += 16.f * gds0 * gds0 - 2.f * gds0 * S10 + S20;
    qdl[1] += 16.f * gds1 * gds1 - 2.f * gds1 * S11 + S21;
    qdl[2] += 16.f * gds2 * gds2 - 2.f * gds2 * S12 + S22;
    qdl[3] += 16.f * gds3 * gds3 - 2.f * gds3 * S13 + S23;
  }
  __shared__ float rA[4][64], rB[4][64], rC[4][64], rD2[4][64];
  int cd = lq * 4;
  if (isD) {
#pragma unroll
    for (int i = 0; i < 4; i++) {
      rA[wave][cd + i] = sdl[i];
      rB[wave][cd + i] = qdl[i];
    }
  }
  if (isS) {
#pragma unroll
    for (int i = 0; i < 4; i++) {
      rC[wave][cd + i] = ssl[i];
      rD2[wave][cd + i] = qsl[i];
    }
  }
  __syncthreads();
  if (wave == 0) {
    float v = rA[0][lane] + rA[1][lane] + rA[2][lane] + rA[3][lane];
    atomicAdd(accDiff + lane, v);
    v = rB[0][lane] + rB[1][lane] + rB[2][lane] + rB[3][lane];
    atomicAdd(accDiff + 64 + lane, v);
    v = rC[0][lane] + rC[1][lane] + rC[2][lane] + rC[3][lane];
    atomicAdd(accSim + lane, v);
    v = rD2[0][lane] + rD2[1][lane] + rD2[2][lane] + rD2[3][lane];
    atomicAdd(accSim + 64 + lane, v);
  }
}

// ---------------- diff output: gather bf16 + BN/relu + MFMA GEMM + max over K --------
__global__ __launch_bounds__(256) void diff_out_k(
    const char* __restrict__ FT0, const char* __restrict__ FT1,
    const int* __restrict__ i01, const int* __restrict__ i10,
    const float* __restrict__ w2d, const float* __restrict__ b2d,
    const float* __restrict__ acc, const float* __restrict__ dg,
    const float* __restrict__ dbe, float* __restrict__ DF0, float* __restrict__ DF1) {
  int u = blockIdx.x & 7;
  int dir = u & 1, batch = u >> 1;
  const char* FS = dir ? FT1 : FT0;
  const char* FO = dir ? FT0 : FT1;
  const int* idx = dir ? i10 : i01;
  const float* aD = acc + dir * 128;
  float* dout = dir ? DF1 : DF0;
  __shared__ __align__(16) unsigned WlU[64 * 36];
  __shared__ __align__(16) unsigned HtU[64 * 36];
  __shared__ unsigned Gs[4][32];
  __shared__ int idxt[64];
  __shared__ float sc[64], sh[64], bb[64];
  int t = threadIdx.x;
  int r = t >> 2, q = t & 3;
  {
    const float4* w4 = (const float4*)(w2d + r * 64 + q * 16);
#pragma unroll
    for (int uu = 0; uu < 4; uu++) {
      float4 v = w4[uu];
      WlU[r * 36 + q * 8 + uu * 2] = pack_bf16x2(v.x, v.y);
      WlU[r * 36 + q * 8 + uu * 2 + 1] = pack_bf16x2(v.z, v.w);
    }
  }
  if (t < 64) {
    float mu = aD[t] / (float)NSAMP;
    float var = aD[64 + t] / (float)NSAMP - mu * mu;
    float scale = dg[t] * rsqrtf(var + EPSf);
    sc[t] = scale;
    sh[t] = dbe[t] - mu * scale;
    bb[t] = b2d[t];
  }
  int wave = t >> 6, lane = t & 63;
  int lr = lane & 15, lg = lane >> 4;
  int p = r >> 4;
  int wblk = blockIdx.x >> 3;  // 0..511
  int bbase = batch * Nn;
#pragma unroll 1
  for (int tt = 0; tt < 4; tt++) {
    int tile = wblk * 4 + tt;
    int ptb = batch * Nn + tile * 4;
    __syncthreads();
    if (t < 64) idxt[t] = idx[ptb * 16 + t];
    if (t < 128)
      Gs[t >> 5][t & 31] =
          *(const unsigned*)(FS + (size_t)(ptb + (t >> 5)) * FT_STRIDE + 128 + (t & 31) * 4);
    __syncthreads();
    const char* orow = FO + (size_t)(bbase + idxt[r]) * FT_STRIDE + 128;
    uint4 g0 = *(const uint4*)(orow + q * 32);
    uint4 g1 = *(const uint4*)(orow + q * 32 + 16);
#pragma unroll
    for (int uu = 0; uu < 8; uu++) {
      unsigned gdo2 = (uu < 4) ? ((const unsigned*)&g0)[uu] : ((const unsigned*)&g1)[uu - 4];
      unsigned gds2 = Gs[p][q * 8 + uu];
      int c = q * 16 + uu * 2;
      float h0 = fmaxf(sc[c] * (bf16_lo(gds2) - bf16_lo(gdo2)) + sh[c], 0.f);
      float h1 = fmaxf(sc[c + 1] * (bf16_hi(gds2) - bf16_hi(gdo2)) + sh[c + 1], 0.f);
      HtU[r * 36 + q * 8 + uu] = pack_bf16x2(h0, h1);
    }
    __syncthreads();
    v4f acc4[4] = {{0, 0, 0, 0}, {0, 0, 0, 0}, {0, 0, 0, 0}, {0, 0, 0, 0}};
    v8bf a0 = *(const v8bf*)&HtU[(wave * 16 + lr) * 36 + lg * 4];
    v8bf a1 = *(const v8bf*)&HtU[(wave * 16 + lr) * 36 + 16 + lg * 4];
#pragma unroll
    for (int c = 0; c < 4; c++) {
      v8bf b0 = *(const v8bf*)&WlU[(c * 16 + lr) * 36 + lg * 4];
      v8bf b1 = *(const v8bf*)&WlU[(c * 16 + lr) * 36 + 16 + lg * 4];
      acc4[c] = __builtin_amdgcn_mfma_f32_16x16x32_bf16(a0, b0, acc4[c], 0, 0, 0);
      acc4[c] = __builtin_amdgcn_mfma_f32_16x16x32_bf16(a1, b1, acc4[c], 0, 0, 0);
    }
#pragma unroll
    for (int c = 0; c < 4; c++) {
      float mm = fmaxf(fmaxf(acc4[c][0], acc4[c][1]), fmaxf(acc4[c][2], acc4[c][3]));
      mm = fmaxf(mm, __shfl_xor(mm, 16));
      mm = fmaxf(mm, __shfl_xor(mm, 32));
      if (lane < 16) dout[(size_t)(ptb + wave) * 64 + c * 16 + lane] = mm + bb[c * 16 + lane];
    }
  }
}

// ---------------- SF = relu(bn(YS)) @ sw2^T + sb2 (finalize1-sim folded in) -------
__global__ __launch_bounds__(256) void simfeat_gemm(
    const float* __restrict__ YS0, const float* __restrict__ YS1,
    const float* __restrict__ acc, const float* __restrict__ sg,
    const float* __restrict__ sbe, const float* __restrict__ sw2,
    const float* __restrict__ sb2, float* __restrict__ SF0, float* __restrict__ SF1) {
  int dir = blockIdx.y;
  const float* ysim = dir ? YS1 : YS0;
  const float* aS = acc + 256 + dir * 128;
  float* sf = dir ? SF1 : SF0;
  __shared__ float Wl[64][65];
  __shared__ float Hl[64][65];
  __shared__ float sc[64], sh[64], bb[64];
  int t = threadIdx.x;
  if (t < 64) {
    float mu = aS[t] / (float)NPTS;
    float var = aS[64 + t] / (float)NPTS - mu * mu;
    float scale = sg[t] * rsqrtf(var + EPSf);
    sc[t] = scale;
    sh[t] = sbe[t] - mu * scale;
    bb[t] = sb2[t];
  }
#pragma unroll
  for (int i = 0; i < 16; i++) {
    int ix = t + i * 256;
    Wl[ix >> 6][ix & 63] = sw2[ix];
  }
  __syncthreads();
  int ptb = blockIdx.x * 64;
#pragma unroll
  for (int i = 0; i < 16; i++) {
    int ix = t + i * 256;
    int row = ix >> 6, col = ix & 63;
    float v = ysim[(size_t)ptb * 64 + ix];
    Hl[row][col] = fmaxf(sc[col] * v + sh[col], 0.f);
  }
  __syncthreads();
  int ty = t >> 4, tx = t & 15, r0 = ty * 4, c0 = tx * 4;
  float acc4[4][4] = {};
#pragma unroll 4
  for (int j = 0; j < 64; ++j) {
    float a[4], w[4];
#pragma unroll
    for (int i = 0; i < 4; i++) a[i] = Hl[r0 + i][j];
#pragma unroll
    for (int m = 0; m < 4; m++) w[m] = Wl[c0 + m][j];
#pragma unroll
    for (int i = 0; i < 4; i++)
#pragma unroll
      for (int m = 0; m < 4; m++) acc4[i][m] += a[i] * w[m];
  }
#pragma unroll
  for (int i = 0; i < 4; i++) {
    float4 v = make_float4(acc4[i][0] + bb[c0], acc4[i][1] + bb[c0 + 1],
                           acc4[i][2] + bb[c0 + 2], acc4[i][3] + bb[c0 + 3]);
    *reinterpret_cast<float4*>(sf + (size_t)(ptb + r0 + i) * 64 + c0) = v;
  }
}

// ---------------- YF = [DF|SF] @ fw1^T + fin BN stats ----------------
// v2: two-phase Wl[64][65] (LDS 35KB), shfl-reduced stats (no LDS atomics).
__global__ __launch_bounds__(256) void yfin_gemm(
    const float* __restrict__ DF0, const float* __restrict__ DF1,
    const float* __restrict__ SF0, const float* __restrict__ SF1,
    const float* __restrict__ fw1, float* __restrict__ YF0, float* __restrict__ YF1,
    float* __restrict__ acc) {
  int dir = blockIdx.z;
  const float* df = dir ? DF1 : DF0;
  const float* sf = dir ? SF1 : SF0;
  float* yf = dir ? YF1 : YF0;
  float* accF = acc + 512 + dir * 256;
  __shared__ float Wl[64][65];
  __shared__ float Cl[64][65];
  __shared__ float redS[4][64], redQ[4][64];
  int t = threadIdx.x;
  int y = blockIdx.y;
  int ptb = blockIdx.x * 64;
  int ty = t >> 4, tx = t & 15, r0 = ty * 4, c0 = tx * 4;
  float acc4[4][4] = {};
  // phase 1: K = 0..63 (DF), Wl = fw1[y*64+r][0..63]
#pragma unroll
  for (int i = 0; i < 16; i++) {
    int ix = t + i * 256;
    Wl[ix >> 6][ix & 63] = fw1[(size_t)(y * 64 + (ix >> 6)) * 128 + (ix & 63)];
    Cl[ix >> 6][ix & 63] = df[(size_t)ptb * 64 + ix];
  }
  __syncthreads();
#pragma unroll 4
  for (int j = 0; j < 64; ++j) {
    float a[4], w[4];
#pragma unroll
    for (int i = 0; i < 4; i++) a[i] = Cl[r0 + i][j];
#pragma unroll
    for (int m = 0; m < 4; m++) w[m] = Wl[c0 + m][j];
#pragma unroll
    for (int i = 0; i < 4; i++)
#pragma unroll
      for (int m = 0; m < 4; m++) acc4[i][m] += a[i] * w[m];
  }
  __syncthreads();
  // phase 2: K = 64..127 (SF), Wl = fw1[y*64+r][64..127]
#pragma unroll
  for (int i = 0; i < 16; i++) {
    int ix = t + i * 256;
    Wl[ix >> 6][ix & 63] = fw1[(size_t)(y * 64 + (ix >> 6)) * 128 + 64 + (ix & 63)];
    Cl[ix >> 6][ix & 63] = sf[(size_t)ptb * 64 + ix];
  }
  __syncthreads();
#pragma unroll 4
  for (int j = 0; j < 64; ++j) {
    float a[4], w[4];
#pragma unroll
    for (int i = 0; i < 4; i++) a[i] = Cl[r0 + i][j];
#pragma unroll
    for (int m = 0; m < 4; m++) w[m] = Wl[c0 + m][j];
#pragma unroll
    for (int i = 0; i < 4; i++)
#pragma unroll
      for (int m = 0; m < 4; m++) acc4[i][m] += a[i] * w[m];
  }
#pragma unroll
  for (int i = 0; i < 4; i++) {
    float4 v = make_float4(acc4[i][0], acc4[i][1], acc4[i][2], acc4[i][3]);
    *reinterpret_cast<float4*>(yf + (size_t)(ptb + r0 + i) * 128 + y * 64 + c0) = v;
  }
  // stats: in-register row sum -> wave shfl over ty-groups -> per-wave LDS
  // partials -> 128 global atomics by first 64 threads. No LDS atomics.
  int wave = t >> 6, lane = t & 63;
  float sv[4], qv[4];
#pragma unroll
  for (int m = 0; m < 4; m++) {
    float s = acc4[0][m] + acc4[1][m] + acc4[2][m] + acc4[3][m];
    float qq = acc4[0][m] * acc4[0][m] + acc4[1][m] * acc4[1][m] +
               acc4[2][m] * acc4[2][m] + acc4[3][m] * acc4[3][m];
    s += __shfl_xor(s, 16);
    s += __shfl_xor(s, 32);
    qq += __shfl_xor(qq, 16);
    qq += __shfl_xor(qq, 32);
    sv[m] = s;
    qv[m] = qq;
  }
  if (lane < 16) {
#pragma unroll
    for (int m = 0; m < 4; m++) {
      redS[wave][lane * 4 + m] = sv[m];
      redQ[wave][lane * 4 + m] = qv[m];
    }
  }
  __syncthreads();
  if (t < 64) {
    atomicAdd(accF + y * 64 + t, redS[0][t] + redS[1][t] + redS[2][t] + redS[3][t]);
    atomicAdd(accF + 128 + y * 64 + t,
              redQ[0][t] + redQ[1][t] + redQ[2][t] + redQ[3][t]);
  }
}

// ---------------- out = relu(bn(YF)) @ fw2^T + fb2 (finalize2 folded in) ----------
__global__ __launch_bounds__(256) void finout_gemm(
    const float* __restrict__ YF0, const float* __restrict__ YF1,
    const float* __restrict__ acc, const float* __restrict__ fg,
    const float* __restrict__ fbe, const float* __restrict__ fw2,
    const float* __restrict__ fb2, float* __restrict__ out) {
  int dir = blockIdx.y;
  const float* yf = dir ? YF1 : YF0;
  const float* aF = acc + 512 + dir * 256;
  float* outp = out + (size_t)dir * NPTS * 64;
  __shared__ float Wl[64][129];
  __shared__ float Hl[64][65];
  __shared__ float scl[128], shf[128], bb[64];
  int t = threadIdx.x;
  if (t < 128) {
    float mu = aF[t] / (float)NPTS;
    float var = aF[128 + t] / (float)NPTS - mu * mu;
    float scale = fg[t] * rsqrtf(var + EPSf);
    scl[t] = scale;
    shf[t] = fbe[t] - mu * scale;
  }
  if (t < 64) bb[t] = fb2[t];
#pragma unroll
  for (int i = 0; i < 32; i++) {
    int ix = t + i * 256;
    Wl[ix >> 7][ix & 127] = fw2[ix];
  }
  __syncthreads();
  int ptb = blockIdx.x * 64;
  int ty = t >> 4, tx = t & 15, r0 = ty * 4, c0 = tx * 4;
  float acc4[4][4] = {};
#pragma unroll
  for (int i = 0; i < 16; i++) {
    int ix = t + i * 256;
    int row = ix >> 6, jj = ix & 63;
    float v = yf[(size_t)(ptb + row) * 128 + jj];
    Hl[row][jj] = fmaxf(scl[jj] * v + shf[jj], 0.f);
  }
  __syncthreads();
#pragma unroll 4
  for (int j = 0; j < 64; ++j) {
    float a[4], w[4];
#pragma unroll
    for (int i = 0; i < 4; i++) a[i] = Hl[r0 + i][j];
#pragma unroll
    for (int m = 0; m < 4; m++) w[m] = Wl[c0 + m][j];
#pragma unroll
    for (int i = 0; i < 4; i++)
#pragma unroll
      for (int m = 0; m < 4; m++) acc4[i][m] += a[i] * w[m];
  }
  __syncthreads();
#pragma unroll
  for (int i = 0; i < 16; i++) {
    int ix = t + i * 256;
    int row = ix >> 6, jj = ix & 63;
    float v = yf[(size_t)(ptb + row) * 128 + 64 + jj];
    Hl[row][jj] = fmaxf(scl[64 + jj] * v + shf[64 + jj], 0.f);
  }
  __syncthreads();
#pragma unroll 4
  for (int j = 0; j < 64; ++j) {
    float a[4], w[4];
#pragma unroll
    for (int i = 0; i < 4; i++) a[i] = Hl[r0 + i][j];
#pragma unroll
    for (int m = 0; m < 4; m++) w[m] = Wl[c0 + m][64 + j];
#pragma unroll
    for (int i = 0; i < 4; i++)
#pragma unroll
      for (int m = 0; m < 4; m++) acc4[i][m] += a[i] * w[m];
  }
#pragma unroll
  for (int i = 0; i < 4; i++) {
    float4 v = make_float4(acc4[i][0] + bb[c0], acc4[i][1] + bb[c0 + 1],
                           acc4[i][2] + bb[c0 + 2], acc4[i][3] + bb[c0 + 3]);
    *reinterpret_cast<float4*>(outp + (size_t)(ptb + r0 + i) * 64 + c0) = v;
  }
}

extern "C" void kernel_launch(void* const* d_in, const int* in_sizes, int n_in,
                              void* d_out, int out_size, void* d_ws, size_t ws_size,
                              hipStream_t stream) {
  const float* f0 = (const float*)d_in[0];
  const float* f1 = (const float*)d_in[1];
  const int* i01 = (const int*)d_in[2];
  const int* i10 = (const int*)d_in[3];
  const float* dw1 = (const float*)d_in[4];
  const float* dg = (const float*)d_in[6];
  const float* dbe = (const float*)d_in[7];
  const float* dw2 = (const float*)d_in[8];
  const float* db2 = (const float*)d_in[9];
  const float* sw1 = (const float*)d_in[10];
  const float* sg = (const float*)d_in[12];
  const float* sbe = (const float*)d_in[13];
  const float* sw2 = (const float*)d_in[14];
  const float* sb2 = (const float*)d_in[15];
  const float* fw1 = (const float*)d_in[16];
  const float* fg = (const float*)d_in[18];
  const float* fbe = (const float*)d_in[19];
  const float* fw2 = (const float*)d_in[20];
  const float* fb2 = (const float*)d_in[21];

  char* wsb = (char*)d_ws;
  float* out = (float*)d_out;

  char* FT0 = wsb;                 // 12 MB + pad
  char* FT1 = wsb + FTSZ;          // 12 MB + pad
  float* acc = (float*)(wsb + 2 * FTSZ);
  float* YS0 = (float*)(wsb + 2 * FTSZ + 65536);
  float* YS1 = YS0 + GSZ;
  float* DF0 = YS1 + GSZ;
  float* DF1 = DF0 + GSZ;
  float* SF0 = DF1 + GSZ;
  float* SF1 = SF0 + GSZ;
  float* YF0 = YS0;          // 16MB over YS0+YS1 (dead after simfeat_gemm)
  float* YF1 = (float*)wsb;  // 16MB over FT0+FT1 (dead after diff_out_k)

  hipMemsetAsync(acc, 0, 1024 * sizeof(float), stream);
  gemmG<<<dim3(512, 1, 2), 256, 0, stream>>>(f0, f1, dw1, sw1, FT0, FT1);

  stats_sim<<<4096, 256, 0, stream>>>(FT0, FT1, i01, i10, YS0, YS1, acc);

  diff_out_k<<<4096, 256, 0, stream>>>(FT0, FT1, i01, i10, dw2, db2, acc, dg, dbe, DF0, DF1);

  simfeat_gemm<<<dim3(512, 2), 256, 0, stream>>>(YS0, YS1, acc, sg, sbe, sw2, sb2, SF0, SF1);

  yfin_gemm<<<dim3(512, 2, 2), 256, 0, stream>>>(DF0, DF1, SF0, SF1, fw1, YF0, YF1, acc);

  finout_gemm<<<dim3(512, 2), 256, 0, stream>>>(YF0, YF1, acc, fg, fbe, fw2, fb2, out);
}

// Round 17
// 227.096 us; speedup vs baseline: 1.3312x; 1.0510x over previous
//
#include <hip/hip_runtime.h>
#include <hip/hip_fp16.h>

// PointSetDifferenceModule: B=4, N=8192, C=64, K=16
// Round 17: stats_sim restructured to 4 points/wave (one per 16-lane group):
// dot tree / exp / stat FMAs amortize over 4 points per wave-instruction
// (~2.8x fewer VALU ops), gathers become 3 pad-free loads per k, idx load
// fully coalesced. k staged in 2 chunks of 8. Everything else = round 16.
// FT row (384B): [ f fp16 x64 | G_d bf16 x64 | G_s bf16 x64 ]

#define Bn 4
#define Nn 8192
#define NPTS (Bn * Nn)        // 32768
#define NSAMP (NPTS * 16)     // 524288
#define EPSf 1e-5f
#define FT_STRIDE 384
#define FTSZ ((size_t)NPTS * FT_STRIDE + 1024)
#define GSZ (NPTS * 64)

typedef __attribute__((ext_vector_type(8))) short v8bf;
typedef __attribute__((ext_vector_type(4))) float v4f;
typedef __attribute__((ext_vector_type(2))) _Float16 v2h;

union U2H {
  unsigned u;
  v2h h;
};

__device__ inline unsigned pack_bf16x2(float a, float b) {
  unsigned ua = __float_as_uint(a), ub = __float_as_uint(b);
  ua = (ua + 0x7FFFu + ((ua >> 16) & 1u)) >> 16;
  ub = (ub + 0x7FFFu + ((ub >> 16) & 1u)) >> 16;
  return (ub << 16) | ua;
}
__device__ inline float bf16_lo(unsigned u) { return __uint_as_float(u << 16); }
__device__ inline float bf16_hi(unsigned u) { return __uint_as_float(u & 0xFFFF0000u); }

__device__ inline float dot2acc(unsigned a, unsigned b, float c) {
  U2H ua, ub;
  ua.u = a;
  ub.u = b;
#if __has_builtin(__builtin_amdgcn_fdot2)
  return __builtin_amdgcn_fdot2(ua.h, ub.h, c, false);
#else
  return c + (float)ua.h.x * (float)ub.h.x + (float)ua.h.y * (float)ub.h.y;
#endif
}

// ---------------- build fused tables: f fp16 + G_d, G_s bf16 ----------------
__global__ __launch_bounds__(256) void gemmG(const float* __restrict__ f0,
                                             const float* __restrict__ f1,
                                             const float* __restrict__ wd,
                                             const float* __restrict__ wsim,
                                             char* __restrict__ FT0,
                                             char* __restrict__ FT1) {
  int z = blockIdx.z;
  const float* F = z ? f1 : f0;
  char* FT = z ? FT1 : FT0;
  __shared__ float Fl[64][65];
  __shared__ float Wd[64][65];
  __shared__ float Ws[64][65];
  int t = threadIdx.x;
#pragma unroll
  for (int i = 0; i < 16; i++) {
    int ix = t + i * 256;
    Wd[ix >> 6][ix & 63] = wd[ix];
    Ws[ix >> 6][ix & 63] = wsim[ix];
  }
  int ptb = blockIdx.x * 64;
#pragma unroll
  for (int i = 0; i < 8; i++) {
    int pr = t + i * 256;  // pair index 0..2047
    int row = pr >> 5, c2 = pr & 31;
    float2 v = *(const float2*)(F + (size_t)(ptb + row) * 64 + c2 * 2);
    Fl[row][c2 * 2] = v.x;
    Fl[row][c2 * 2 + 1] = v.y;
    __half2 h2 = __floats2half2_rn(v.x, v.y);
    *(unsigned*)(FT + (size_t)(ptb + row) * FT_STRIDE + c2 * 4) =
        *reinterpret_cast<unsigned*>(&h2);
  }
  __syncthreads();
  int ty = t >> 4, tx = t & 15, r0 = ty * 4, c0 = tx * 4;
  float ad[4][4] = {}, as_[4][4] = {};
#pragma unroll 4
  for (int j = 0; j < 64; ++j) {
    float a[4], w1[4], w2[4];
#pragma unroll
    for (int i = 0; i < 4; i++) a[i] = Fl[r0 + i][j];
#pragma unroll
    for (int m = 0; m < 4; m++) {
      w1[m] = Wd[c0 + m][j];
      w2[m] = Ws[c0 + m][j];
    }
#pragma unroll
    for (int i = 0; i < 4; i++)
#pragma unroll
      for (int m = 0; m < 4; m++) {
        ad[i][m] += a[i] * w1[m];
        as_[i][m] += a[i] * w2[m];
      }
  }
#pragma unroll
  for (int i = 0; i < 4; i++) {
    char* row = FT + (size_t)(ptb + r0 + i) * FT_STRIDE;
    uint2 gd2 = make_uint2(pack_bf16x2(ad[i][0], ad[i][1]),
                           pack_bf16x2(ad[i][2], ad[i][3]));
    *(uint2*)(row + 128 + c0 * 2) = gd2;
    uint2 gs2 = make_uint2(pack_bf16x2(as_[i][0], as_[i][1]),
                           pack_bf16x2(as_[i][2], as_[i][3]));
    *(uint2*)(row + 256 + c0 * 2) = gs2;
  }
}

// ---------------- diff stats + sim softmax + y_sim (4 points per wave) ----------
// group g = lane>>4 owns point ptbase+g; slot s = lane&15 owns channels 4s..4s+3
__global__ __launch_bounds__(256) void stats_sim(
    const char* __restrict__ FT0, const char* __restrict__ FT1,
    const int* __restrict__ i01, const int* __restrict__ i10,
    float* __restrict__ YS0, float* __restrict__ YS1, float* __restrict__ acc) {
  int u = blockIdx.x & 7;
  int dir = u & 1, batch = u >> 1;
  const char* FS = dir ? FT1 : FT0;
  const char* FO = dir ? FT0 : FT1;
  const int* idx = dir ? i10 : i01;
  float* ys = dir ? YS1 : YS0;
  float* accDiff = acc + dir * 128;
  float* accSim = acc + 256 + dir * 128;
  int lane = threadIdx.x & 63, wave = threadIdx.x >> 6;
  int s = lane & 15, g = lane >> 4, gsel = lane & 48;
  int ptbase = batch * Nn + (blockIdx.x >> 3) * 16 + wave * 4;
  int bbase = batch * Nn;
  // coalesced idx: lane holds k-slot s of point ptbase+g
  int myidx = idx[ptbase * 16 + lane];
  // self loads (group g reads its own point's row)
  const char* srow = FS + (size_t)(ptbase + g) * FT_STRIDE;
  uint2 fs = *(const uint2*)(srow + s * 8);
  uint2 gds_u = *(const uint2*)(srow + 128 + s * 8);
  float gds0 = bf16_lo(gds_u.x), gds1 = bf16_hi(gds_u.x);
  float gds2 = bf16_lo(gds_u.y), gds3 = bf16_hi(gds_u.y);
  const char* ob = FO + (size_t)bbase * FT_STRIDE;
  float S10 = 0.f, S11 = 0.f, S12 = 0.f, S13 = 0.f;
  float S20 = 0.f, S21 = 0.f, S22 = 0.f, S23 = 0.f;
  float den = 0.f, ya0 = 0.f, ya1 = 0.f, ya2 = 0.f, ya3 = 0.f;
#pragma unroll 1
  for (int kc = 0; kc < 16; kc += 8) {
    uint2 fo[8], gdo[8], gso[8];
#pragma unroll
    for (int k = 0; k < 8; k++) {
      int j = __shfl(myidx, gsel | (kc + k));
      const char* orow = ob + (size_t)j * FT_STRIDE;
      fo[k] = *(const uint2*)(orow + s * 8);
      gdo[k] = *(const uint2*)(orow + 128 + s * 8);
      gso[k] = *(const uint2*)(orow + 256 + s * 8);
    }
    float sims[8];
#pragma unroll
    for (int k = 0; k < 8; k++) {
      float p = dot2acc(fs.y, fo[k].y, dot2acc(fs.x, fo[k].x, 0.f));
      p += __shfl_xor(p, 8);
      p += __shfl_xor(p, 4);
      p += __shfl_xor(p, 2);
      p += __shfl_xor(p, 1);
      sims[k] = p;
      float g0 = bf16_lo(gdo[k].x), g1 = bf16_hi(gdo[k].x);
      float g2 = bf16_lo(gdo[k].y), g3 = bf16_hi(gdo[k].y);
      S10 += g0; S11 += g1; S12 += g2; S13 += g3;
      S20 += g0 * g0; S21 += g1 * g1; S22 += g2 * g2; S23 += g3 * g3;
    }
    // exp (no max shift; |logit| << 88) + softmax numerators
#pragma unroll
    for (int k = 0; k < 8; k++) {
      float e = __expf(sims[k]);
      den += e;
      ya0 += e * bf16_lo(gso[k].x);
      ya1 += e * bf16_hi(gso[k].x);
      ya2 += e * bf16_lo(gso[k].y);
      ya3 += e * bf16_hi(gso[k].y);
    }
  }
  float inv = 1.f / den;
  ya0 *= inv; ya1 *= inv; ya2 *= inv; ya3 *= inv;
  // ysim: group g writes point ptbase+g, channels 4s..4s+3 (full 64-lane store)
  *(float4*)(ys + (size_t)(ptbase + g) * 64 + s * 4) =
      make_float4(ya0, ya1, ya2, ya3);
  // per-lane stats for (point ptbase+g, channels 4s..4s+3)
  float sd0 = 16.f * gds0 - S10;
  float sd1 = 16.f * gds1 - S11;
  float sd2 = 16.f * gds2 - S12;
  float sd3 = 16.f * gds3 - S13;
  float qd0 = 16.f * gds0 * gds0 - 2.f * gds0 * S10 + S20;
  float qd1 = 16.f * gds1 * gds1 - 2.f * gds1 * S11 + S21;
  float qd2 = 16.f * gds2 * gds2 - 2.f * gds2 * S12 + S22;
  float qd3 = 16.f * gds3 * gds3 - 2.f * gds3 * S13 + S23;
  float ss0 = ya0, ss1 = ya1, ss2 = ya2, ss3 = ya3;
  float qs0 = ya0 * ya0, qs1 = ya1 * ya1, qs2 = ya2 * ya2, qs3 = ya3 * ya3;
  // sum the 4 groups (xor16 + xor32 keep slot s fixed, vary g)
#define GRED(x)            \
  x += __shfl_xor(x, 16);  \
  x += __shfl_xor(x, 32);
  GRED(sd0) GRED(sd1) GRED(sd2) GRED(sd3)
  GRED(qd0) GRED(qd1) GRED(qd2) GRED(qd3)
  GRED(ss0) GRED(ss1) GRED(ss2) GRED(ss3)
  GRED(qs0) GRED(qs1) GRED(qs2) GRED(qs3)
#undef GRED
  __shared__ float red[4][4][64];  // [wave][which][channel]
  if (lane < 16) {
    red[wave][0][s * 4 + 0] = sd0;
    red[wave][0][s * 4 + 1] = sd1;
    red[wave][0][s * 4 + 2] = sd2;
    red[wave][0][s * 4 + 3] = sd3;
    red[wave][1][s * 4 + 0] = qd0;
    red[wave][1][s * 4 + 1] = qd1;
    red[wave][1][s * 4 + 2] = qd2;
    red[wave][1][s * 4 + 3] = qd3;
    red[wave][2][s * 4 + 0] = ss0;
    red[wave][2][s * 4 + 1] = ss1;
    red[wave][2][s * 4 + 2] = ss2;
    red[wave][2][s * 4 + 3] = ss3;
    red[wave][3][s * 4 + 0] = qs0;
    red[wave][3][s * 4 + 1] = qs1;
    red[wave][3][s * 4 + 2] = qs2;
    red[wave][3][s * 4 + 3] = qs3;
  }
  __syncthreads();
  if (wave == 0) {
    float v = red[0][0][lane] + red[1][0][lane] + red[2][0][lane] + red[3][0][lane];
    atomicAdd(accDiff + lane, v);
    v = red[0][1][lane] + red[1][1][lane] + red[2][1][lane] + red[3][1][lane];
    atomicAdd(accDiff + 64 + lane, v);
    v = red[0][2][lane] + red[1][2][lane] + red[2][2][lane] + red[3][2][lane];
    atomicAdd(accSim + lane, v);
    v = red[0][3][lane] + red[1][3][lane] + red[2][3][lane] + red[3][3][lane];
    atomicAdd(accSim + 64 + lane, v);
  }
}

// ---------------- diff output: gather bf16 + BN/relu + MFMA GEMM + max over K --------
__global__ __launch_bounds__(256) void diff_out_k(
    const char* __restrict__ FT0, const char* __restrict__ FT1,
    const int* __restrict__ i01, const int* __restrict__ i10,
    const float* __restrict__ w2d, const float* __restrict__ b2d,
    const float* __restrict__ acc, const float* __restrict__ dg,
    const float* __restrict__ dbe, float* __restrict__ DF0, float* __restrict__ DF1) {
  int u = blockIdx.x & 7;
  int dir = u & 1, batch = u >> 1;
  const char* FS = dir ? FT1 : FT0;
  const char* FO = dir ? FT0 : FT1;
  const int* idx = dir ? i10 : i01;
  const float* aD = acc + dir * 128;
  float* dout = dir ? DF1 : DF0;
  __shared__ __align__(16) unsigned WlU[64 * 36];
  __shared__ __align__(16) unsigned HtU[64 * 36];
  __shared__ unsigned Gs[4][32];
  __shared__ int idxt[64];
  __shared__ float sc[64], sh[64], bb[64];
  int t = threadIdx.x;
  int r = t >> 2, q = t & 3;
  {
    const float4* w4 = (const float4*)(w2d + r * 64 + q * 16);
#pragma unroll
    for (int uu = 0; uu < 4; uu++) {
      float4 v = w4[uu];
      WlU[r * 36 + q * 8 + uu * 2] = pack_bf16x2(v.x, v.y);
      WlU[r * 36 + q * 8 + uu * 2 + 1] = pack_bf16x2(v.z, v.w);
    }
  }
  if (t < 64) {
    float mu = aD[t] / (float)NSAMP;
    float var = aD[64 + t] / (float)NSAMP - mu * mu;
    float scale = dg[t] * rsqrtf(var + EPSf);
    sc[t] = scale;
    sh[t] = dbe[t] - mu * scale;
    bb[t] = b2d[t];
  }
  int wave = t >> 6, lane = t & 63;
  int lr = lane & 15, lg = lane >> 4;
  int p = r >> 4;
  int wblk = blockIdx.x >> 3;  // 0..511
  int bbase = batch * Nn;
#pragma unroll 1
  for (int tt = 0; tt < 4; tt++) {
    int tile = wblk * 4 + tt;
    int ptb = batch * Nn + tile * 4;
    __syncthreads();
    if (t < 64) idxt[t] = idx[ptb * 16 + t];
    if (t < 128)
      Gs[t >> 5][t & 31] =
          *(const unsigned*)(FS + (size_t)(ptb + (t >> 5)) * FT_STRIDE + 128 + (t & 31) * 4);
    __syncthreads();
    const char* orow = FO + (size_t)(bbase + idxt[r]) * FT_STRIDE + 128;
    uint4 g0 = *(const uint4*)(orow + q * 32);
    uint4 g1 = *(const uint4*)(orow + q * 32 + 16);
#pragma unroll
    for (int uu = 0; uu < 8; uu++) {
      unsigned gdo2 = (uu < 4) ? ((const unsigned*)&g0)[uu] : ((const unsigned*)&g1)[uu - 4];
      unsigned gds2 = Gs[p][q * 8 + uu];
      int c = q * 16 + uu * 2;
      float h0 = fmaxf(sc[c] * (bf16_lo(gds2) - bf16_lo(gdo2)) + sh[c], 0.f);
      float h1 = fmaxf(sc[c + 1] * (bf16_hi(gds2) - bf16_hi(gdo2)) + sh[c + 1], 0.f);
      HtU[r * 36 + q * 8 + uu] = pack_bf16x2(h0, h1);
    }
    __syncthreads();
    v4f acc4[4] = {{0, 0, 0, 0}, {0, 0, 0, 0}, {0, 0, 0, 0}, {0, 0, 0, 0}};
    v8bf a0 = *(const v8bf*)&HtU[(wave * 16 + lr) * 36 + lg * 4];
    v8bf a1 = *(const v8bf*)&HtU[(wave * 16 + lr) * 36 + 16 + lg * 4];
#pragma unroll
    for (int c = 0; c < 4; c++) {
      v8bf b0 = *(const v8bf*)&WlU[(c * 16 + lr) * 36 + lg * 4];
      v8bf b1 = *(const v8bf*)&WlU[(c * 16 + lr) * 36 + 16 + lg * 4];
      acc4[c] = __builtin_amdgcn_mfma_f32_16x16x32_bf16(a0, b0, acc4[c], 0, 0, 0);
      acc4[c] = __builtin_amdgcn_mfma_f32_16x16x32_bf16(a1, b1, acc4[c], 0, 0, 0);
    }
#pragma unroll
    for (int c = 0; c < 4; c++) {
      float mm = fmaxf(fmaxf(acc4[c][0], acc4[c][1]), fmaxf(acc4[c][2], acc4[c][3]));
      mm = fmaxf(mm, __shfl_xor(mm, 16));
      mm = fmaxf(mm, __shfl_xor(mm, 32));
      if (lane < 16) dout[(size_t)(ptb + wave) * 64 + c * 16 + lane] = mm + bb[c * 16 + lane];
    }
  }
}

// ---------------- SF = relu(bn(YS)) @ sw2^T + sb2 (finalize1-sim folded in) -------
__global__ __launch_bounds__(256) void simfeat_gemm(
    const float* __restrict__ YS0, const float* __restrict__ YS1,
    const float* __restrict__ acc, const float* __restrict__ sg,
    const float* __restrict__ sbe, const float* __restrict__ sw2,
    const float* __restrict__ sb2, float* __restrict__ SF0, float* __restrict__ SF1) {
  int dir = blockIdx.y;
  const float* ysim = dir ? YS1 : YS0;
  const float* aS = acc + 256 + dir * 128;
  float* sf = dir ? SF1 : SF0;
  __shared__ float Wl[64][65];
  __shared__ float Hl[64][65];
  __shared__ float sc[64], sh[64], bb[64];
  int t = threadIdx.x;
  if (t < 64) {
    float mu = aS[t] / (float)NPTS;
    float var = aS[64 + t] / (float)NPTS - mu * mu;
    float scale = sg[t] * rsqrtf(var + EPSf);
    sc[t] = scale;
    sh[t] = sbe[t] - mu * scale;
    bb[t] = sb2[t];
  }
#pragma unroll
  for (int i = 0; i < 16; i++) {
    int ix = t + i * 256;
    Wl[ix >> 6][ix & 63] = sw2[ix];
  }
  __syncthreads();
  int ptb = blockIdx.x * 64;
#pragma unroll
  for (int i = 0; i < 16; i++) {
    int ix = t + i * 256;
    int row = ix >> 6, col = ix & 63;
    float v = ysim[(size_t)ptb * 64 + ix];
    Hl[row][col] = fmaxf(sc[col] * v + sh[col], 0.f);
  }
  __syncthreads();
  int ty = t >> 4, tx = t & 15, r0 = ty * 4, c0 = tx * 4;
  float acc4[4][4] = {};
#pragma unroll 4
  for (int j = 0; j < 64; ++j) {
    float a[4], w[4];
#pragma unroll
    for (int i = 0; i < 4; i++) a[i] = Hl[r0 + i][j];
#pragma unroll
    for (int m = 0; m < 4; m++) w[m] = Wl[c0 + m][j];
#pragma unroll
    for (int i = 0; i < 4; i++)
#pragma unroll
      for (int m = 0; m < 4; m++) acc4[i][m] += a[i] * w[m];
  }
#pragma unroll
  for (int i = 0; i < 4; i++) {
    float4 v = make_float4(acc4[i][0] + bb[c0], acc4[i][1] + bb[c0 + 1],
                           acc4[i][2] + bb[c0 + 2], acc4[i][3] + bb[c0 + 3]);
    *reinterpret_cast<float4*>(sf + (size_t)(ptb + r0 + i) * 64 + c0) = v;
  }
}

// ---------------- YF = [DF|SF] @ fw1^T + fin BN stats ----------------
__global__ __launch_bounds__(256) void yfin_gemm(
    const float* __restrict__ DF0, const float* __restrict__ DF1,
    const float* __restrict__ SF0, const float* __restrict__ SF1,
    const float* __restrict__ fw1, float* __restrict__ YF0, float* __restrict__ YF1,
    float* __restrict__ acc) {
  int dir = blockIdx.z;
  const float* df = dir ? DF1 : DF0;
  const float* sf = dir ? SF1 : SF0;
  float* yf = dir ? YF1 : YF0;
  float* accF = acc + 512 + dir * 256;
  __shared__ float Wl[64][65];
  __shared__ float Cl[64][65];
  __shared__ float redS[4][64], redQ[4][64];
  int t = threadIdx.x;
  int y = blockIdx.y;
  int ptb = blockIdx.x * 64;
  int ty = t >> 4, tx = t & 15, r0 = ty * 4, c0 = tx * 4;
  float acc4[4][4] = {};
#pragma unroll
  for (int i = 0; i < 16; i++) {
    int ix = t + i * 256;
    Wl[ix >> 6][ix & 63] = fw1[(size_t)(y * 64 + (ix >> 6)) * 128 + (ix & 63)];
    Cl[ix >> 6][ix & 63] = df[(size_t)ptb * 64 + ix];
  }
  __syncthreads();
#pragma unroll 4
  for (int j = 0; j < 64; ++j) {
    float a[4], w[4];
#pragma unroll
    for (int i = 0; i < 4; i++) a[i] = Cl[r0 + i][j];
#pragma unroll
    for (int m = 0; m < 4; m++) w[m] = Wl[c0 + m][j];
#pragma unroll
    for (int i = 0; i < 4; i++)
#pragma unroll
      for (int m = 0; m < 4; m++) acc4[i][m] += a[i] * w[m];
  }
  __syncthreads();
#pragma unroll
  for (int i = 0; i < 16; i++) {
    int ix = t + i * 256;
    Wl[ix >> 6][ix & 63] = fw1[(size_t)(y * 64 + (ix >> 6)) * 128 + 64 + (ix & 63)];
    Cl[ix >> 6][ix & 63] = sf[(size_t)ptb * 64 + ix];
  }
  __syncthreads();
#pragma unroll 4
  for (int j = 0; j < 64; ++j) {
    float a[4], w[4];
#pragma unroll
    for (int i = 0; i < 4; i++) a[i] = Cl[r0 + i][j];
#pragma unroll
    for (int m = 0; m < 4; m++) w[m] = Wl[c0 + m][j];
#pragma unroll
    for (int i = 0; i < 4; i++)
#pragma unroll
      for (int m = 0; m < 4; m++) acc4[i][m] += a[i] * w[m];
  }
#pragma unroll
  for (int i = 0; i < 4; i++) {
    float4 v = make_float4(acc4[i][0], acc4[i][1], acc4[i][2], acc4[i][3]);
    *reinterpret_cast<float4*>(yf + (size_t)(ptb + r0 + i) * 128 + y * 64 + c0) = v;
  }
  int wave = t >> 6, lane = t & 63;
  float sv[4], qv[4];
#pragma unroll
  for (int m = 0; m < 4; m++) {
    float s = acc4[0][m] + acc4[1][m] + acc4[2][m] + acc4[3][m];
    float qq = acc4[0][m] * acc4[0][m] + acc4[1][m] * acc4[1][m] +
               acc4[2][m] * acc4[2][m] + acc4[3][m] * acc4[3][m];
    s += __shfl_xor(s, 16);
    s += __shfl_xor(s, 32);
    qq += __shfl_xor(qq, 16);
    qq += __shfl_xor(qq, 32);
    sv[m] = s;
    qv[m] = qq;
  }
  if (lane < 16) {
#pragma unroll
    for (int m = 0; m < 4; m++) {
      redS[wave][lane * 4 + m] = sv[m];
      redQ[wave][lane * 4 + m] = qv[m];
    }
  }
  __syncthreads();
  if (t < 64) {
    atomicAdd(accF + y * 64 + t, redS[0][t] + redS[1][t] + redS[2][t] + redS[3][t]);
    atomicAdd(accF + 128 + y * 64 + t,
              redQ[0][t] + redQ[1][t] + redQ[2][t] + redQ[3][t]);
  }
}

// ---------------- out = relu(bn(YF)) @ fw2^T + fb2 (finalize2 folded in) ----------
__global__ __launch_bounds__(256) void finout_gemm(
    const float* __restrict__ YF0, const float* __restrict__ YF1,
    const float* __restrict__ acc, const float* __restrict__ fg,
    const float* __restrict__ fbe, const float* __restrict__ fw2,
    const float* __restrict__ fb2, float* __restrict__ out) {
  int dir = blockIdx.y;
  const float* yf = dir ? YF1 : YF0;
  const float* aF = acc + 512 + dir * 256;
  float* outp = out + (size_t)dir * NPTS * 64;
  __shared__ float Wl[64][129];
  __shared__ float Hl[64][65];
  __shared__ float scl[128], shf[128], bb[64];
  int t = threadIdx.x;
  if (t < 128) {
    float mu = aF[t] / (float)NPTS;
    float var = aF[128 + t] / (float)NPTS - mu * mu;
    float scale = fg[t] * rsqrtf(var + EPSf);
    scl[t] = scale;
    shf[t] = fbe[t] - mu * scale;
  }
  if (t < 64) bb[t] = fb2[t];
#pragma unroll
  for (int i = 0; i < 32; i++) {
    int ix = t + i * 256;
    Wl[ix >> 7][ix & 127] = fw2[ix];
  }
  __syncthreads();
  int ptb = blockIdx.x * 64;
  int ty = t >> 4, tx = t & 15, r0 = ty * 4, c0 = tx * 4;
  float acc4[4][4] = {};
#pragma unroll
  for (int i = 0; i < 16; i++) {
    int ix = t + i * 256;
    int row = ix >> 6, jj = ix & 63;
    float v = yf[(size_t)(ptb + row) * 128 + jj];
    Hl[row][jj] = fmaxf(scl[jj] * v + shf[jj], 0.f);
  }
  __syncthreads();
#pragma unroll 4
  for (int j = 0; j < 64; ++j) {
    float a[4], w[4];
#pragma unroll
    for (int i = 0; i < 4; i++) a[i] = Hl[r0 + i][j];
#pragma unroll
    for (int m = 0; m < 4; m++) w[m] = Wl[c0 + m][j];
#pragma unroll
    for (int i = 0; i < 4; i++)
#pragma unroll
      for (int m = 0; m < 4; m++) acc4[i][m] += a[i] * w[m];
  }
  __syncthreads();
#pragma unroll
  for (int i = 0; i < 16; i++) {
    int ix = t + i * 256;
    int row = ix >> 6, jj = ix & 63;
    float v = yf[(size_t)(ptb + row) * 128 + 64 + jj];
    Hl[row][jj] = fmaxf(scl[64 + jj] * v + shf[64 + jj], 0.f);
  }
  __syncthreads();
#pragma unroll 4
  for (int j = 0; j < 64; ++j) {
    float a[4], w[4];
#pragma unroll
    for (int i = 0; i < 4; i++) a[i] = Hl[r0 + i][j];
#pragma unroll
    for (int m = 0; m < 4; m++) w[m] = Wl[c0 + m][64 + j];
#pragma unroll
    for (int i = 0; i < 4; i++)
#pragma unroll
      for (int m = 0; m < 4; m++) acc4[i][m] += a[i] * w[m];
  }
#pragma unroll
  for (int i = 0; i < 4; i++) {
    float4 v = make_float4(acc4[i][0] + bb[c0], acc4[i][1] + bb[c0 + 1],
                           acc4[i][2] + bb[c0 + 2], acc4[i][3] + bb[c0 + 3]);
    *reinterpret_cast<float4*>(outp + (size_t)(ptb + r0 + i) * 64 + c0) = v;
  }
}

extern "C" void kernel_launch(void* const* d_in, const int* in_sizes, int n_in,
                              void* d_out, int out_size, void* d_ws, size_t ws_size,
                              hipStream_t stream) {
  const float* f0 = (const float*)d_in[0];
  const float* f1 = (const float*)d_in[1];
  const int* i01 = (const int*)d_in[2];
  const int* i10 = (const int*)d_in[3];
  const float* dw1 = (const float*)d_in[4];
  const float* dg = (const float*)d_in[6];
  const float* dbe = (const float*)d_in[7];
  const float* dw2 = (const float*)d_in[8];
  const float* db2 = (const float*)d_in[9];
  const float* sw1 = (const float*)d_in[10];
  const float* sg = (const float*)d_in[12];
  const float* sbe = (const float*)d_in[13];
  const float* sw2 = (const float*)d_in[14];
  const float* sb2 = (const float*)d_in[15];
  const float* fw1 = (const float*)d_in[16];
  const float* fg = (const float*)d_in[18];
  const float* fbe = (const float*)d_in[19];
  const float* fw2 = (const float*)d_in[20];
  const float* fb2 = (const float*)d_in[21];

  char* wsb = (char*)d_ws;
  float* out = (float*)d_out;

  char* FT0 = wsb;                 // 12 MB + pad
  char* FT1 = wsb + FTSZ;          // 12 MB + pad
  float* acc = (float*)(wsb + 2 * FTSZ);
  float* YS0 = (float*)(wsb + 2 * FTSZ + 65536);
  float* YS1 = YS0 + GSZ;
  float* DF0 = YS1 + GSZ;
  float* DF1 = DF0 + GSZ;
  float* SF0 = DF1 + GSZ;
  float* SF1 = SF0 + GSZ;
  float* YF0 = YS0;          // 16MB over YS0+YS1 (dead after simfeat_gemm)
  float* YF1 = (float*)wsb;  // 16MB over FT0+FT1 (dead after diff_out_k)

  hipMemsetAsync(acc, 0, 1024 * sizeof(float), stream);
  gemmG<<<dim3(512, 1, 2), 256, 0, stream>>>(f0, f1, dw1, sw1, FT0, FT1);

  stats_sim<<<4096, 256, 0, stream>>>(FT0, FT1, i01, i10, YS0, YS1, acc);

  diff_out_k<<<4096, 256, 0, stream>>>(FT0, FT1, i01, i10, dw2, db2, acc, dg, dbe, DF0, DF1);

  simfeat_gemm<<<dim3(512, 2), 256, 0, stream>>>(YS0, YS1, acc, sg, sbe, sw2, sb2, SF0, SF1);

  yfin_gemm<<<dim3(512, 2, 2), 256, 0, stream>>>(DF0, DF1, SF0, SF1, fw1, YF0, YF1, acc);

  finout_gemm<<<dim3(512, 2), 256, 0, stream>>>(YF0, YF1, acc, fg, fbe, fw2, fb2, out);
}

// Round 19
// 192.750 us; speedup vs baseline: 1.5685x; 1.1782x over previous
//
#include <hip/hip_runtime.h>
#include <hip/hip_fp16.h>

// PointSetDifferenceModule: B=4, N=8192, C=64, K=16
// Round 18: yfin_gemm + finout_gemm MFMA-ized (bf16 LDS tiles, XOR-swizzled
// ds_read_b128, 16 mfma/wave) — replaces 1024 scalar LDS reads/thread that
// made them DS-pipe-bound (6.3M bank-conflict cycles). Rest = round 17.
// FT row (384B): [ f fp16 x64 | G_d bf16 x64 | G_s bf16 x64 ]

#define Bn 4
#define Nn 8192
#define NPTS (Bn * Nn)        // 32768
#define NSAMP (NPTS * 16)     // 524288
#define EPSf 1e-5f
#define FT_STRIDE 384
#define FTSZ ((size_t)NPTS * FT_STRIDE + 1024)
#define GSZ (NPTS * 64)

typedef __attribute__((ext_vector_type(8))) short v8bf;
typedef __attribute__((ext_vector_type(4))) float v4f;
typedef __attribute__((ext_vector_type(2))) _Float16 v2h;

union U2H {
  unsigned u;
  v2h h;
};

__device__ inline unsigned pack_bf16x2(float a, float b) {
  unsigned ua = __float_as_uint(a), ub = __float_as_uint(b);
  ua = (ua + 0x7FFFu + ((ua >> 16) & 1u)) >> 16;
  ub = (ub + 0x7FFFu + ((ub >> 16) & 1u)) >> 16;
  return (ub << 16) | ua;
}
__device__ inline float bf16_lo(unsigned u) { return __uint_as_float(u << 16); }
__device__ inline float bf16_hi(unsigned u) { return __uint_as_float(u & 0xFFFF0000u); }

__device__ inline float dot2acc(unsigned a, unsigned b, float c) {
  U2H ua, ub;
  ua.u = a;
  ub.u = b;
#if __has_builtin(__builtin_amdgcn_fdot2)
  return __builtin_amdgcn_fdot2(ua.h, ub.h, c, false);
#else
  return c + (float)ua.h.x * (float)ub.h.x + (float)ua.h.y * (float)ub.h.y;
#endif
}

// ---------------- build fused tables: f fp16 + G_d, G_s bf16 ----------------
__global__ __launch_bounds__(256) void gemmG(const float* __restrict__ f0,
                                             const float* __restrict__ f1,
                                             const float* __restrict__ wd,
                                             const float* __restrict__ wsim,
                                             char* __restrict__ FT0,
                                             char* __restrict__ FT1) {
  int z = blockIdx.z;
  const float* F = z ? f1 : f0;
  char* FT = z ? FT1 : FT0;
  __shared__ float Fl[64][65];
  __shared__ float Wd[64][65];
  __shared__ float Ws[64][65];
  int t = threadIdx.x;
#pragma unroll
  for (int i = 0; i < 16; i++) {
    int ix = t + i * 256;
    Wd[ix >> 6][ix & 63] = wd[ix];
    Ws[ix >> 6][ix & 63] = wsim[ix];
  }
  int ptb = blockIdx.x * 64;
#pragma unroll
  for (int i = 0; i < 8; i++) {
    int pr = t + i * 256;  // pair index 0..2047
    int row = pr >> 5, c2 = pr & 31;
    float2 v = *(const float2*)(F + (size_t)(ptb + row) * 64 + c2 * 2);
    Fl[row][c2 * 2] = v.x;
    Fl[row][c2 * 2 + 1] = v.y;
    __half2 h2 = __floats2half2_rn(v.x, v.y);
    *(unsigned*)(FT + (size_t)(ptb + row) * FT_STRIDE + c2 * 4) =
        *reinterpret_cast<unsigned*>(&h2);
  }
  __syncthreads();
  int ty = t >> 4, tx = t & 15, r0 = ty * 4, c0 = tx * 4;
  float ad[4][4] = {}, as_[4][4] = {};
#pragma unroll 4
  for (int j = 0; j < 64; ++j) {
    float a[4], w1[4], w2[4];
#pragma unroll
    for (int i = 0; i < 4; i++) a[i] = Fl[r0 + i][j];
#pragma unroll
    for (int m = 0; m < 4; m++) {
      w1[m] = Wd[c0 + m][j];
      w2[m] = Ws[c0 + m][j];
    }
#pragma unroll
    for (int i = 0; i < 4; i++)
#pragma unroll
      for (int m = 0; m < 4; m++) {
        ad[i][m] += a[i] * w1[m];
        as_[i][m] += a[i] * w2[m];
      }
  }
#pragma unroll
  for (int i = 0; i < 4; i++) {
    char* row = FT + (size_t)(ptb + r0 + i) * FT_STRIDE;
    uint2 gd2 = make_uint2(pack_bf16x2(ad[i][0], ad[i][1]),
                           pack_bf16x2(ad[i][2], ad[i][3]));
    *(uint2*)(row + 128 + c0 * 2) = gd2;
    uint2 gs2 = make_uint2(pack_bf16x2(as_[i][0], as_[i][1]),
                           pack_bf16x2(as_[i][2], as_[i][3]));
    *(uint2*)(row + 256 + c0 * 2) = gs2;
  }
}

// ---------------- diff stats + sim softmax + y_sim (4 points per wave) ----------
__global__ __launch_bounds__(256) void stats_sim(
    const char* __restrict__ FT0, const char* __restrict__ FT1,
    const int* __restrict__ i01, const int* __restrict__ i10,
    float* __restrict__ YS0, float* __restrict__ YS1, float* __restrict__ acc) {
  int u = blockIdx.x & 7;
  int dir = u & 1, batch = u >> 1;
  const char* FS = dir ? FT1 : FT0;
  const char* FO = dir ? FT0 : FT1;
  const int* idx = dir ? i10 : i01;
  float* ys = dir ? YS1 : YS0;
  float* accDiff = acc + dir * 128;
  float* accSim = acc + 256 + dir * 128;
  int lane = threadIdx.x & 63, wave = threadIdx.x >> 6;
  int s = lane & 15, g = lane >> 4, gsel = lane & 48;
  int ptbase = batch * Nn + (blockIdx.x >> 3) * 16 + wave * 4;
  int bbase = batch * Nn;
  int myidx = idx[ptbase * 16 + lane];
  const char* srow = FS + (size_t)(ptbase + g) * FT_STRIDE;
  uint2 fs = *(const uint2*)(srow + s * 8);
  uint2 gds_u = *(const uint2*)(srow + 128 + s * 8);
  float gds0 = bf16_lo(gds_u.x), gds1 = bf16_hi(gds_u.x);
  float gds2 = bf16_lo(gds_u.y), gds3 = bf16_hi(gds_u.y);
  const char* ob = FO + (size_t)bbase * FT_STRIDE;
  float S10 = 0.f, S11 = 0.f, S12 = 0.f, S13 = 0.f;
  float S20 = 0.f, S21 = 0.f, S22 = 0.f, S23 = 0.f;
  float den = 0.f, ya0 = 0.f, ya1 = 0.f, ya2 = 0.f, ya3 = 0.f;
#pragma unroll 1
  for (int kc = 0; kc < 16; kc += 8) {
    uint2 fo[8], gdo[8], gso[8];
#pragma unroll
    for (int k = 0; k < 8; k++) {
      int j = __shfl(myidx, gsel | (kc + k));
      const char* orow = ob + (size_t)j * FT_STRIDE;
      fo[k] = *(const uint2*)(orow + s * 8);
      gdo[k] = *(const uint2*)(orow + 128 + s * 8);
      gso[k] = *(const uint2*)(orow + 256 + s * 8);
    }
    float sims[8];
#pragma unroll
    for (int k = 0; k < 8; k++) {
      float p = dot2acc(fs.y, fo[k].y, dot2acc(fs.x, fo[k].x, 0.f));
      p += __shfl_xor(p, 8);
      p += __shfl_xor(p, 4);
      p += __shfl_xor(p, 2);
      p += __shfl_xor(p, 1);
      sims[k] = p;
      float g0 = bf16_lo(gdo[k].x), g1 = bf16_hi(gdo[k].x);
      float g2 = bf16_lo(gdo[k].y), g3 = bf16_hi(gdo[k].y);
      S10 += g0; S11 += g1; S12 += g2; S13 += g3;
      S20 += g0 * g0; S21 += g1 * g1; S22 += g2 * g2; S23 += g3 * g3;
    }
#pragma unroll
    for (int k = 0; k < 8; k++) {
      float e = __expf(sims[k]);
      den += e;
      ya0 += e * bf16_lo(gso[k].x);
      ya1 += e * bf16_hi(gso[k].x);
      ya2 += e * bf16_lo(gso[k].y);
      ya3 += e * bf16_hi(gso[k].y);
    }
  }
  float inv = 1.f / den;
  ya0 *= inv; ya1 *= inv; ya2 *= inv; ya3 *= inv;
  *(float4*)(ys + (size_t)(ptbase + g) * 64 + s * 4) =
      make_float4(ya0, ya1, ya2, ya3);
  float sd0 = 16.f * gds0 - S10;
  float sd1 = 16.f * gds1 - S11;
  float sd2 = 16.f * gds2 - S12;
  float sd3 = 16.f * gds3 - S13;
  float qd0 = 16.f * gds0 * gds0 - 2.f * gds0 * S10 + S20;
  float qd1 = 16.f * gds1 * gds1 - 2.f * gds1 * S11 + S21;
  float qd2 = 16.f * gds2 * gds2 - 2.f * gds2 * S12 + S22;
  float qd3 = 16.f * gds3 * gds3 - 2.f * gds3 * S13 + S23;
  float ss0 = ya0, ss1 = ya1, ss2 = ya2, ss3 = ya3;
  float qs0 = ya0 * ya0, qs1 = ya1 * ya1, qs2 = ya2 * ya2, qs3 = ya3 * ya3;
#define GRED(x)            \
  x += __shfl_xor(x, 16);  \
  x += __shfl_xor(x, 32);
  GRED(sd0) GRED(sd1) GRED(sd2) GRED(sd3)
  GRED(qd0) GRED(qd1) GRED(qd2) GRED(qd3)
  GRED(ss0) GRED(ss1) GRED(ss2) GRED(ss3)
  GRED(qs0) GRED(qs1) GRED(qs2) GRED(qs3)
#undef GRED
  __shared__ float red[4][4][64];
  if (lane < 16) {
    red[wave][0][s * 4 + 0] = sd0;
    red[wave][0][s * 4 + 1] = sd1;
    red[wave][0][s * 4 + 2] = sd2;
    red[wave][0][s * 4 + 3] = sd3;
    red[wave][1][s * 4 + 0] = qd0;
    red[wave][1][s * 4 + 1] = qd1;
    red[wave][1][s * 4 + 2] = qd2;
    red[wave][1][s * 4 + 3] = qd3;
    red[wave][2][s * 4 + 0] = ss0;
    red[wave][2][s * 4 + 1] = ss1;
    red[wave][2][s * 4 + 2] = ss2;
    red[wave][2][s * 4 + 3] = ss3;
    red[wave][3][s * 4 + 0] = qs0;
    red[wave][3][s * 4 + 1] = qs1;
    red[wave][3][s * 4 + 2] = qs2;
    red[wave][3][s * 4 + 3] = qs3;
  }
  __syncthreads();
  if (wave == 0) {
    float v = red[0][0][lane] + red[1][0][lane] + red[2][0][lane] + red[3][0][lane];
    atomicAdd(accDiff + lane, v);
    v = red[0][1][lane] + red[1][1][lane] + red[2][1][lane] + red[3][1][lane];
    atomicAdd(accDiff + 64 + lane, v);
    v = red[0][2][lane] + red[1][2][lane] + red[2][2][lane] + red[3][2][lane];
    atomicAdd(accSim + lane, v);
    v = red[0][3][lane] + red[1][3][lane] + red[2][3][lane] + red[3][3][lane];
    atomicAdd(accSim + 64 + lane, v);
  }
}

// ---------------- diff output: gather bf16 + BN/relu + MFMA GEMM + max over K --------
__global__ __launch_bounds__(256) void diff_out_k(
    const char* __restrict__ FT0, const char* __restrict__ FT1,
    const int* __restrict__ i01, const int* __restrict__ i10,
    const float* __restrict__ w2d, const float* __restrict__ b2d,
    const float* __restrict__ acc, const float* __restrict__ dg,
    const float* __restrict__ dbe, float* __restrict__ DF0, float* __restrict__ DF1) {
  int u = blockIdx.x & 7;
  int dir = u & 1, batch = u >> 1;
  const char* FS = dir ? FT1 : FT0;
  const char* FO = dir ? FT0 : FT1;
  const int* idx = dir ? i10 : i01;
  const float* aD = acc + dir * 128;
  float* dout = dir ? DF1 : DF0;
  __shared__ __align__(16) unsigned WlU[64 * 36];
  __shared__ __align__(16) unsigned HtU[64 * 36];
  __shared__ unsigned Gs[4][32];
  __shared__ int idxt[64];
  __shared__ float sc[64], sh[64], bb[64];
  int t = threadIdx.x;
  int r = t >> 2, q = t & 3;
  {
    const float4* w4 = (const float4*)(w2d + r * 64 + q * 16);
#pragma unroll
    for (int uu = 0; uu < 4; uu++) {
      float4 v = w4[uu];
      WlU[r * 36 + q * 8 + uu * 2] = pack_bf16x2(v.x, v.y);
      WlU[r * 36 + q * 8 + uu * 2 + 1] = pack_bf16x2(v.z, v.w);
    }
  }
  if (t < 64) {
    float mu = aD[t] / (float)NSAMP;
    float var = aD[64 + t] / (float)NSAMP - mu * mu;
    float scale = dg[t] * rsqrtf(var + EPSf);
    sc[t] = scale;
    sh[t] = dbe[t] - mu * scale;
    bb[t] = b2d[t];
  }
  int wave = t >> 6, lane = t & 63;
  int lr = lane & 15, lg = lane >> 4;
  int p = r >> 4;
  int wblk = blockIdx.x >> 3;  // 0..511
  int bbase = batch * Nn;
#pragma unroll 1
  for (int tt = 0; tt < 4; tt++) {
    int tile = wblk * 4 + tt;
    int ptb = batch * Nn + tile * 4;
    __syncthreads();
    if (t < 64) idxt[t] = idx[ptb * 16 + t];
    if (t < 128)
      Gs[t >> 5][t & 31] =
          *(const unsigned*)(FS + (size_t)(ptb + (t >> 5)) * FT_STRIDE + 128 + (t & 31) * 4);
    __syncthreads();
    const char* orow = FO + (size_t)(bbase + idxt[r]) * FT_STRIDE + 128;
    uint4 g0 = *(const uint4*)(orow + q * 32);
    uint4 g1 = *(const uint4*)(orow + q * 32 + 16);
#pragma unroll
    for (int uu = 0; uu < 8; uu++) {
      unsigned gdo2 = (uu < 4) ? ((const unsigned*)&g0)[uu] : ((const unsigned*)&g1)[uu - 4];
      unsigned gds2 = Gs[p][q * 8 + uu];
      int c = q * 16 + uu * 2;
      float h0 = fmaxf(sc[c] * (bf16_lo(gds2) - bf16_lo(gdo2)) + sh[c], 0.f);
      float h1 = fmaxf(sc[c + 1] * (bf16_hi(gds2) - bf16_hi(gdo2)) + sh[c + 1], 0.f);
      HtU[r * 36 + q * 8 + uu] = pack_bf16x2(h0, h1);
    }
    __syncthreads();
    v4f acc4[4] = {{0, 0, 0, 0}, {0, 0, 0, 0}, {0, 0, 0, 0}, {0, 0, 0, 0}};
    v8bf a0 = *(const v8bf*)&HtU[(wave * 16 + lr) * 36 + lg * 4];
    v8bf a1 = *(const v8bf*)&HtU[(wave * 16 + lr) * 36 + 16 + lg * 4];
#pragma unroll
    for (int c = 0; c < 4; c++) {
      v8bf b0 = *(const v8bf*)&WlU[(c * 16 + lr) * 36 + lg * 4];
      v8bf b1 = *(const v8bf*)&WlU[(c * 16 + lr) * 36 + 16 + lg * 4];
      acc4[c] = __builtin_amdgcn_mfma_f32_16x16x32_bf16(a0, b0, acc4[c], 0, 0, 0);
      acc4[c] = __builtin_amdgcn_mfma_f32_16x16x32_bf16(a1, b1, acc4[c], 0, 0, 0);
    }
#pragma unroll
    for (int c = 0; c < 4; c++) {
      float mm = fmaxf(fmaxf(acc4[c][0], acc4[c][1]), fmaxf(acc4[c][2], acc4[c][3]));
      mm = fmaxf(mm, __shfl_xor(mm, 16));
      mm = fmaxf(mm, __shfl_xor(mm, 32));
      if (lane < 16) dout[(size_t)(ptb + wave) * 64 + c * 16 + lane] = mm + bb[c * 16 + lane];
    }
  }
}

// ---------------- SF = relu(bn(YS)) @ sw2^T + sb2 (finalize1-sim folded in) -------
__global__ __launch_bounds__(256) void simfeat_gemm(
    const float* __restrict__ YS0, const float* __restrict__ YS1,
    const float* __restrict__ acc, const float* __restrict__ sg,
    const float* __restrict__ sbe, const float* __restrict__ sw2,
    const float* __restrict__ sb2, float* __restrict__ SF0, float* __restrict__ SF1) {
  int dir = blockIdx.y;
  const float* ysim = dir ? YS1 : YS0;
  const float* aS = acc + 256 + dir * 128;
  float* sf = dir ? SF1 : SF0;
  __shared__ float Wl[64][65];
  __shared__ float Hl[64][65];
  __shared__ float sc[64], sh[64], bb[64];
  int t = threadIdx.x;
  if (t < 64) {
    float mu = aS[t] / (float)NPTS;
    float var = aS[64 + t] / (float)NPTS - mu * mu;
    float scale = sg[t] * rsqrtf(var + EPSf);
    sc[t] = scale;
    sh[t] = sbe[t] - mu * scale;
    bb[t] = sb2[t];
  }
#pragma unroll
  for (int i = 0; i < 16; i++) {
    int ix = t + i * 256;
    Wl[ix >> 6][ix & 63] = sw2[ix];
  }
  __syncthreads();
  int ptb = blockIdx.x * 64;
#pragma unroll
  for (int i = 0; i < 16; i++) {
    int ix = t + i * 256;
    int row = ix >> 6, col = ix & 63;
    float v = ysim[(size_t)ptb * 64 + ix];
    Hl[row][col] = fmaxf(sc[col] * v + sh[col], 0.f);
  }
  __syncthreads();
  int ty = t >> 4, tx = t & 15, r0 = ty * 4, c0 = tx * 4;
  float acc4[4][4] = {};
#pragma unroll 4
  for (int j = 0; j < 64; ++j) {
    float a[4], w[4];
#pragma unroll
    for (int i = 0; i < 4; i++) a[i] = Hl[r0 + i][j];
#pragma unroll
    for (int m = 0; m < 4; m++) w[m] = Wl[c0 + m][j];
#pragma unroll
    for (int i = 0; i < 4; i++)
#pragma unroll
      for (int m = 0; m < 4; m++) acc4[i][m] += a[i] * w[m];
  }
#pragma unroll
  for (int i = 0; i < 4; i++) {
    float4 v = make_float4(acc4[i][0] + bb[c0], acc4[i][1] + bb[c0 + 1],
                           acc4[i][2] + bb[c0 + 2], acc4[i][3] + bb[c0 + 3]);
    *reinterpret_cast<float4*>(sf + (size_t)(ptb + r0 + i) * 64 + c0) = v;
  }
}

// ---------------- YF = [DF|SF] @ fw1^T + fin BN stats (MFMA, bf16 tiles) ----------
__global__ __launch_bounds__(256) void yfin_gemm(
    const float* __restrict__ DF0, const float* __restrict__ DF1,
    const float* __restrict__ SF0, const float* __restrict__ SF1,
    const float* __restrict__ fw1, float* __restrict__ YF0, float* __restrict__ YF1,
    float* __restrict__ acc) {
  int dir = blockIdx.z;
  const float* df = dir ? DF1 : DF0;
  const float* sf = dir ? SF1 : SF0;
  float* yf = dir ? YF1 : YF0;
  float* accF = acc + 512 + dir * 256;
  __shared__ __align__(16) unsigned Au[64 * 68];  // A: points x 128K bf16, XOR-swz
  __shared__ __align__(16) unsigned Bu[64 * 68];  // B: fw1 rows x 128K bf16
  __shared__ float redS[4][64], redQ[4][64];
  int t = threadIdx.x;
  int y = blockIdx.y;
  int ptb = blockIdx.x * 64;
#pragma unroll
  for (int i = 0; i < 16; i++) {
    int ix = t + i * 256;
    int row = ix >> 6, uc = ix & 63;
    int sw = uc ^ ((row & 7) << 2);
    float2 v = (uc < 32)
                   ? *(const float2*)(df + (size_t)(ptb + row) * 64 + uc * 2)
                   : *(const float2*)(sf + (size_t)(ptb + row) * 64 + (uc - 32) * 2);
    Au[row * 68 + sw] = pack_bf16x2(v.x, v.y);
    float2 w = *(const float2*)(fw1 + (size_t)(y * 64 + row) * 128 + uc * 2);
    Bu[row * 68 + sw] = pack_bf16x2(w.x, w.y);
  }
  __syncthreads();
  int wave = t >> 6, lane = t & 63, lr = lane & 15, lg = lane >> 4;
  v8bf a[4];
  {
    int arow = wave * 16 + lr;
    int base = arow * 68, sx = (arow & 7) << 2;
#pragma unroll
    for (int kk = 0; kk < 4; kk++)
      a[kk] = *(const v8bf*)&Au[base + ((kk * 16 + lg * 4) ^ sx)];
  }
  v4f acc4[4] = {{0, 0, 0, 0}, {0, 0, 0, 0}, {0, 0, 0, 0}, {0, 0, 0, 0}};
#pragma unroll
  for (int c = 0; c < 4; c++) {
    int brow = c * 16 + lr;
    int base = brow * 68, sx = (brow & 7) << 2;
#pragma unroll
    for (int kk = 0; kk < 4; kk++) {
      v8bf b = *(const v8bf*)&Bu[base + ((kk * 16 + lg * 4) ^ sx)];
      acc4[c] = __builtin_amdgcn_mfma_f32_16x16x32_bf16(a[kk], b, acc4[c], 0, 0, 0);
    }
  }
  // D layout: col = lane&15, row = (lane>>4)*4 + i (within wave's 16-row block)
#pragma unroll
  for (int c = 0; c < 4; c++) {
    float s = 0.f, q = 0.f;
#pragma unroll
    for (int i = 0; i < 4; i++) {
      float v = acc4[c][i];
      yf[(size_t)(ptb + wave * 16 + lg * 4 + i) * 128 + y * 64 + c * 16 + lr] = v;
      s += v;
      q += v * v;
    }
    s += __shfl_xor(s, 16);
    s += __shfl_xor(s, 32);
    q += __shfl_xor(q, 16);
    q += __shfl_xor(q, 32);
    if (lane < 16) {
      redS[wave][c * 16 + lr] = s;
      redQ[wave][c * 16 + lr] = q;
    }
  }
  __syncthreads();
  if (t < 64) {
    atomicAdd(accF + y * 64 + t, redS[0][t] + redS[1][t] + redS[2][t] + redS[3][t]);
    atomicAdd(accF + 128 + y * 64 + t,
              redQ[0][t] + redQ[1][t] + redQ[2][t] + redQ[3][t]);
  }
}

// ---------------- out = relu(bn(YF)) @ fw2^T + fb2 (MFMA, bf16 tiles) -------------
__global__ __launch_bounds__(256) void finout_gemm(
    const float* __restrict__ YF0, const float* __restrict__ YF1,
    const float* __restrict__ acc, const float* __restrict__ fg,
    const float* __restrict__ fbe, const float* __restrict__ fw2,
    const float* __restrict__ fb2, float* __restrict__ out) {
  int dir = blockIdx.y;
  const float* yf = dir ? YF1 : YF0;
  const float* aF = acc + 512 + dir * 256;
  float* outp = out + (size_t)dir * NPTS * 64;
  __shared__ __align__(16) unsigned Au[64 * 68];  // h bf16, XOR-swz
  __shared__ __align__(16) unsigned Bu[64 * 68];  // fw2 bf16
  __shared__ float scl[128], shf[128], bb[64];
  int t = threadIdx.x;
  if (t < 128) {
    float mu = aF[t] / (float)NPTS;
    float var = aF[128 + t] / (float)NPTS - mu * mu;
    float scale = fg[t] * rsqrtf(var + EPSf);
    scl[t] = scale;
    shf[t] = fbe[t] - mu * scale;
  }
  if (t < 64) bb[t] = fb2[t];
  int ptb = blockIdx.x * 64;
#pragma unroll
  for (int i = 0; i < 16; i++) {
    int ix = t + i * 256;
    int row = ix >> 6, uc = ix & 63;
    int sw = uc ^ ((row & 7) << 2);
    float2 w = *(const float2*)(fw2 + (size_t)row * 128 + uc * 2);
    Bu[row * 68 + sw] = pack_bf16x2(w.x, w.y);
  }
  __syncthreads();  // scl/shf ready
#pragma unroll
  for (int i = 0; i < 16; i++) {
    int ix = t + i * 256;
    int row = ix >> 6, uc = ix & 63;
    int sw = uc ^ ((row & 7) << 2);
    float2 v = *(const float2*)(yf + (size_t)(ptb + row) * 128 + uc * 2);
    float h0 = fmaxf(scl[uc * 2] * v.x + shf[uc * 2], 0.f);
    float h1 = fmaxf(scl[uc * 2 + 1] * v.y + shf[uc * 2 + 1], 0.f);
    Au[row * 68 + sw] = pack_bf16x2(h0, h1);
  }
  __syncthreads();
  int wave = t >> 6, lane = t & 63, lr = lane & 15, lg = lane >> 4;
  v8bf a[4];
  {
    int arow = wave * 16 + lr;
    int base = arow * 68, sx = (arow & 7) << 2;
#pragma unroll
    for (int kk = 0; kk < 4; kk++)
      a[kk] = *(const v8bf*)&Au[base + ((kk * 16 + lg * 4) ^ sx)];
  }
  v4f acc4[4] = {{0, 0, 0, 0}, {0, 0, 0, 0}, {0, 0, 0, 0}, {0, 0, 0, 0}};
#pragma unroll
  for (int c = 0; c < 4; c++) {
    int brow = c * 16 + lr;
    int base = brow * 68, sx = (brow & 7) << 2;
#pragma unroll
    for (int kk = 0; kk < 4; kk++) {
      v8bf b = *(const v8bf*)&Bu[base + ((kk * 16 + lg * 4) ^ sx)];
      acc4[c] = __builtin_amdgcn_mfma_f32_16x16x32_bf16(a[kk], b, acc4[c], 0, 0, 0);
    }
  }
#pragma unroll
  for (int c = 0; c < 4; c++) {
    float bbv = bb[c * 16 + lr];
#pragma unroll
    for (int i = 0; i < 4; i++)
      outp[(size_t)(ptb + wave * 16 + lg * 4 + i) * 64 + c * 16 + lr] =
          acc4[c][i] + bbv;
  }
}

extern "C" void kernel_launch(void* const* d_in, const int* in_sizes, int n_in,
                              void* d_out, int out_size, void* d_ws, size_t ws_size,
                              hipStream_t stream) {
  const float* f0 = (const float*)d_in[0];
  const float* f1 = (const float*)d_in[1];
  const int* i01 = (const int*)d_in[2];
  const int* i10 = (const int*)d_in[3];
  const float* dw1 = (const float*)d_in[4];
  const float* dg = (const float*)d_in[6];
  const float* dbe = (const float*)d_in[7];
  const float* dw2 = (const float*)d_in[8];
  const float* db2 = (const float*)d_in[9];
  const float* sw1 = (const float*)d_in[10];
  const float* sg = (const float*)d_in[12];
  const float* sbe = (const float*)d_in[13];
  const float* sw2 = (const float*)d_in[14];
  const float* sb2 = (const float*)d_in[15];
  const float* fw1 = (const float*)d_in[16];
  const float* fg = (const float*)d_in[18];
  const float* fbe = (const float*)d_in[19];
  const float* fw2 = (const float*)d_in[20];
  const float* fb2 = (const float*)d_in[21];

  char* wsb = (char*)d_ws;
  float* out = (float*)d_out;

  char* FT0 = wsb;                 // 12 MB + pad
  char* FT1 = wsb + FTSZ;          // 12 MB + pad
  float* acc = (float*)(wsb + 2 * FTSZ);
  float* YS0 = (float*)(wsb + 2 * FTSZ + 65536);
  float* YS1 = YS0 + GSZ;
  float* DF0 = YS1 + GSZ;
  float* DF1 = DF0 + GSZ;
  float* SF0 = DF1 + GSZ;
  float* SF1 = SF0 + GSZ;
  float* YF0 = YS0;          // 16MB over YS0+YS1 (dead after simfeat_gemm)
  float* YF1 = (float*)wsb;  // 16MB over FT0+FT1 (dead after diff_out_k)

  hipMemsetAsync(acc, 0, 1024 * sizeof(float), stream);
  gemmG<<<dim3(512, 1, 2), 256, 0, stream>>>(f0, f1, dw1, sw1, FT0, FT1);

  stats_sim<<<4096, 256, 0, stream>>>(FT0, FT1, i01, i10, YS0, YS1, acc);

  diff_out_k<<<4096, 256, 0, stream>>>(FT0, FT1, i01, i10, dw2, db2, acc, dg, dbe, DF0, DF1);

  simfeat_gemm<<<dim3(512, 2), 256, 0, stream>>>(YS0, YS1, acc, sg, sbe, sw2, sb2, SF0, SF1);

  yfin_gemm<<<dim3(512, 2, 2), 256, 0, stream>>>(DF0, DF1, SF0, SF1, fw1, YF0, YF1, acc);

  finout_gemm<<<dim3(512, 2), 256, 0, stream>>>(YF0, YF1, acc, fg, fbe, fw2, fb2, out);
}

// Round 20
// 170.914 us; speedup vs baseline: 1.7689x; 1.1278x over previous
//
#include <hip/hip_runtime.h>
#include <hip/hip_fp16.h>

// PointSetDifferenceModule: B=4, N=8192, C=64, K=16
// Round 20: (1) stats_sim 8-lane groups / 8 pts per wave, uint4 gathers
// (halves per-point instruction count; latency-bound fix). (2) simfeat_gemm
// eliminated: YF_sim = relu_bn(YS) @ W'^T with W' = fw1[:,64:]@sw2 (sb2 bias
// cancels exactly under fin-BN). Rest = round 18/19.
// FT row (384B): [ f fp16 x64 | G_d bf16 x64 | G_s bf16 x64 ]

#define Bn 4
#define Nn 8192
#define NPTS (Bn * Nn)        // 32768
#define NSAMP (NPTS * 16)     // 524288
#define EPSf 1e-5f
#define FT_STRIDE 384
#define FTSZ ((size_t)NPTS * FT_STRIDE + 1024)
#define GSZ (NPTS * 64)

typedef __attribute__((ext_vector_type(8))) short v8bf;
typedef __attribute__((ext_vector_type(4))) float v4f;
typedef __attribute__((ext_vector_type(2))) _Float16 v2h;

union U2H {
  unsigned u;
  v2h h;
};

__device__ inline unsigned pack_bf16x2(float a, float b) {
  unsigned ua = __float_as_uint(a), ub = __float_as_uint(b);
  ua = (ua + 0x7FFFu + ((ua >> 16) & 1u)) >> 16;
  ub = (ub + 0x7FFFu + ((ub >> 16) & 1u)) >> 16;
  return (ub << 16) | ua;
}
__device__ inline float bf16_lo(unsigned u) { return __uint_as_float(u << 16); }
__device__ inline float bf16_hi(unsigned u) { return __uint_as_float(u & 0xFFFF0000u); }

__device__ inline float dot2acc(unsigned a, unsigned b, float c) {
  U2H ua, ub;
  ua.u = a;
  ub.u = b;
#if __has_builtin(__builtin_amdgcn_fdot2)
  return __builtin_amdgcn_fdot2(ua.h, ub.h, c, false);
#else
  return c + (float)ua.h.x * (float)ub.h.x + (float)ua.h.y * (float)ub.h.y;
#endif
}

// ---------------- W' = fw1[:,64:128] @ sw2  (128x64) ----------------
__global__ void wprep(const float* __restrict__ fw1, const float* __restrict__ sw2,
                      float* __restrict__ Wp) {
  int gid = blockIdx.x * 256 + threadIdx.x;  // 8192
  int j = gid >> 6, k = gid & 63;
  float s = 0.f;
#pragma unroll 8
  for (int c = 0; c < 64; c++) s += fw1[j * 128 + 64 + c] * sw2[c * 64 + k];
  Wp[gid] = s;
}

// ---------------- build fused tables: f fp16 + G_d, G_s bf16 ----------------
__global__ __launch_bounds__(256) void gemmG(const float* __restrict__ f0,
                                             const float* __restrict__ f1,
                                             const float* __restrict__ wd,
                                             const float* __restrict__ wsim,
                                             char* __restrict__ FT0,
                                             char* __restrict__ FT1) {
  int z = blockIdx.z;
  const float* F = z ? f1 : f0;
  char* FT = z ? FT1 : FT0;
  __shared__ float Fl[64][65];
  __shared__ float Wd[64][65];
  __shared__ float Ws[64][65];
  int t = threadIdx.x;
#pragma unroll
  for (int i = 0; i < 16; i++) {
    int ix = t + i * 256;
    Wd[ix >> 6][ix & 63] = wd[ix];
    Ws[ix >> 6][ix & 63] = wsim[ix];
  }
  int ptb = blockIdx.x * 64;
#pragma unroll
  for (int i = 0; i < 8; i++) {
    int pr = t + i * 256;  // pair index 0..2047
    int row = pr >> 5, c2 = pr & 31;
    float2 v = *(const float2*)(F + (size_t)(ptb + row) * 64 + c2 * 2);
    Fl[row][c2 * 2] = v.x;
    Fl[row][c2 * 2 + 1] = v.y;
    __half2 h2 = __floats2half2_rn(v.x, v.y);
    *(unsigned*)(FT + (size_t)(ptb + row) * FT_STRIDE + c2 * 4) =
        *reinterpret_cast<unsigned*>(&h2);
  }
  __syncthreads();
  int ty = t >> 4, tx = t & 15, r0 = ty * 4, c0 = tx * 4;
  float ad[4][4] = {}, as_[4][4] = {};
#pragma unroll 4
  for (int j = 0; j < 64; ++j) {
    float a[4], w1[4], w2[4];
#pragma unroll
    for (int i = 0; i < 4; i++) a[i] = Fl[r0 + i][j];
#pragma unroll
    for (int m = 0; m < 4; m++) {
      w1[m] = Wd[c0 + m][j];
      w2[m] = Ws[c0 + m][j];
    }
#pragma unroll
    for (int i = 0; i < 4; i++)
#pragma unroll
      for (int m = 0; m < 4; m++) {
        ad[i][m] += a[i] * w1[m];
        as_[i][m] += a[i] * w2[m];
      }
  }
#pragma unroll
  for (int i = 0; i < 4; i++) {
    char* row = FT + (size_t)(ptb + r0 + i) * FT_STRIDE;
    uint2 gd2 = make_uint2(pack_bf16x2(ad[i][0], ad[i][1]),
                           pack_bf16x2(ad[i][2], ad[i][3]));
    *(uint2*)(row + 128 + c0 * 2) = gd2;
    uint2 gs2 = make_uint2(pack_bf16x2(as_[i][0], as_[i][1]),
                           pack_bf16x2(as_[i][2], as_[i][3]));
    *(uint2*)(row + 256 + c0 * 2) = gs2;
  }
}

// ---------------- diff stats + sim softmax + y_sim (8 points per wave) ----------
// group g = lane>>3 owns point ptbase+g; seg s = lane&7 owns channels 8s..8s+7
__global__ __launch_bounds__(256) void stats_sim(
    const char* __restrict__ FT0, const char* __restrict__ FT1,
    const int* __restrict__ i01, const int* __restrict__ i10,
    float* __restrict__ YS0, float* __restrict__ YS1, float* __restrict__ acc) {
  int u = blockIdx.x & 7;
  int dir = u & 1, batch = u >> 1;
  const char* FS = dir ? FT1 : FT0;
  const char* FO = dir ? FT0 : FT1;
  const int* idx = dir ? i10 : i01;
  float* ys = dir ? YS1 : YS0;
  float* accDiff = acc + dir * 128;
  float* accSim = acc + 256 + dir * 128;
  int lane = threadIdx.x & 63, wave = threadIdx.x >> 6;
  int s = lane & 7, g = lane >> 3;
  int ptbase = batch * Nn + (blockIdx.x >> 3) * 32 + wave * 8;
  int bbase = batch * Nn;
  int myidx0 = idx[ptbase * 16 + lane];
  int myidx1 = idx[ptbase * 16 + 64 + lane];
  const char* srow = FS + (size_t)(ptbase + g) * FT_STRIDE;
  uint4 fs4 = *(const uint4*)(srow + s * 16);
  uint4 gds4 = *(const uint4*)(srow + 128 + s * 16);
  float gds[8] = {bf16_lo(gds4.x), bf16_hi(gds4.x), bf16_lo(gds4.y), bf16_hi(gds4.y),
                  bf16_lo(gds4.z), bf16_hi(gds4.z), bf16_lo(gds4.w), bf16_hi(gds4.w)};
  const char* ob = FO + (size_t)bbase * FT_STRIDE;
  int gq = (g & 3) * 16;
  bool hi = g >= 4;
  float S1[8] = {0, 0, 0, 0, 0, 0, 0, 0};
  float S2[8] = {0, 0, 0, 0, 0, 0, 0, 0};
  float ya[8] = {0, 0, 0, 0, 0, 0, 0, 0};
  float den = 0.f;
#pragma unroll 1
  for (int kc = 0; kc < 16; kc += 4) {
    uint4 fo[4], gdo[4], gso[4];
#pragma unroll
    for (int k = 0; k < 4; k++) {
      int jA = __shfl(myidx0, gq + kc + k);
      int jB = __shfl(myidx1, gq + kc + k);
      int j = hi ? jB : jA;
      const char* orow = ob + (size_t)j * FT_STRIDE;
      fo[k] = *(const uint4*)(orow + s * 16);
      gdo[k] = *(const uint4*)(orow + 128 + s * 16);
      gso[k] = *(const uint4*)(orow + 256 + s * 16);
    }
    float sims[4];
#pragma unroll
    for (int k = 0; k < 4; k++) {
      float p = dot2acc(fs4.x, fo[k].x, 0.f);
      p = dot2acc(fs4.y, fo[k].y, p);
      p = dot2acc(fs4.z, fo[k].z, p);
      p = dot2acc(fs4.w, fo[k].w, p);
      p += __shfl_xor(p, 4);
      p += __shfl_xor(p, 2);
      p += __shfl_xor(p, 1);
      sims[k] = p;
      float t0 = bf16_lo(gdo[k].x), t1 = bf16_hi(gdo[k].x);
      float t2 = bf16_lo(gdo[k].y), t3 = bf16_hi(gdo[k].y);
      float t4 = bf16_lo(gdo[k].z), t5 = bf16_hi(gdo[k].z);
      float t6 = bf16_lo(gdo[k].w), t7 = bf16_hi(gdo[k].w);
      S1[0] += t0; S2[0] += t0 * t0;
      S1[1] += t1; S2[1] += t1 * t1;
      S1[2] += t2; S2[2] += t2 * t2;
      S1[3] += t3; S2[3] += t3 * t3;
      S1[4] += t4; S2[4] += t4 * t4;
      S1[5] += t5; S2[5] += t5 * t5;
      S1[6] += t6; S2[6] += t6 * t6;
      S1[7] += t7; S2[7] += t7 * t7;
    }
#pragma unroll
    for (int k = 0; k < 4; k++) {
      float e = __expf(sims[k]);
      den += e;
      ya[0] += e * bf16_lo(gso[k].x);
      ya[1] += e * bf16_hi(gso[k].x);
      ya[2] += e * bf16_lo(gso[k].y);
      ya[3] += e * bf16_hi(gso[k].y);
      ya[4] += e * bf16_lo(gso[k].z);
      ya[5] += e * bf16_hi(gso[k].z);
      ya[6] += e * bf16_lo(gso[k].w);
      ya[7] += e * bf16_hi(gso[k].w);
    }
  }
  float inv = 1.f / den;
#pragma unroll
  for (int i = 0; i < 8; i++) ya[i] *= inv;
  float* yrow = ys + (size_t)(ptbase + g) * 64 + s * 8;
  *(float4*)(yrow) = make_float4(ya[0], ya[1], ya[2], ya[3]);
  *(float4*)(yrow + 4) = make_float4(ya[4], ya[5], ya[6], ya[7]);
  float sd[8], qd[8], qs[8];
#pragma unroll
  for (int i = 0; i < 8; i++) {
    sd[i] = 16.f * gds[i] - S1[i];
    qd[i] = 16.f * gds[i] * gds[i] - 2.f * gds[i] * S1[i] + S2[i];
    qs[i] = ya[i] * ya[i];
  }
  // sum the 8 groups (xor 8,16,32 keep seg s fixed, vary g)
#define GRED(x)           \
  x += __shfl_xor(x, 8);  \
  x += __shfl_xor(x, 16); \
  x += __shfl_xor(x, 32);
#pragma unroll
  for (int i = 0; i < 8; i++) {
    GRED(sd[i]) GRED(qd[i]) GRED(ya[i]) GRED(qs[i])
  }
#undef GRED
  __shared__ float red[4][4][64];  // [wave][which][channel]
  if (lane < 8) {
#pragma unroll
    for (int i = 0; i < 8; i++) {
      red[wave][0][s * 8 + i] = sd[i];
      red[wave][1][s * 8 + i] = qd[i];
      red[wave][2][s * 8 + i] = ya[i];
      red[wave][3][s * 8 + i] = qs[i];
    }
  }
  __syncthreads();
  if (wave == 0) {
    float v = red[0][0][lane] + red[1][0][lane] + red[2][0][lane] + red[3][0][lane];
    atomicAdd(accDiff + lane, v);
    v = red[0][1][lane] + red[1][1][lane] + red[2][1][lane] + red[3][1][lane];
    atomicAdd(accDiff + 64 + lane, v);
    v = red[0][2][lane] + red[1][2][lane] + red[2][2][lane] + red[3][2][lane];
    atomicAdd(accSim + lane, v);
    v = red[0][3][lane] + red[1][3][lane] + red[2][3][lane] + red[3][3][lane];
    atomicAdd(accSim + 64 + lane, v);
  }
}

// ---------------- diff output: gather bf16 + BN/relu + MFMA GEMM + max over K --------
__global__ __launch_bounds__(256) void diff_out_k(
    const char* __restrict__ FT0, const char* __restrict__ FT1,
    const int* __restrict__ i01, const int* __restrict__ i10,
    const float* __restrict__ w2d, const float* __restrict__ b2d,
    const float* __restrict__ acc, const float* __restrict__ dg,
    const float* __restrict__ dbe, float* __restrict__ DF0, float* __restrict__ DF1) {
  int u = blockIdx.x & 7;
  int dir = u & 1, batch = u >> 1;
  const char* FS = dir ? FT1 : FT0;
  const char* FO = dir ? FT0 : FT1;
  const int* idx = dir ? i10 : i01;
  const float* aD = acc + dir * 128;
  float* dout = dir ? DF1 : DF0;
  __shared__ __align__(16) unsigned WlU[64 * 36];
  __shared__ __align__(16) unsigned HtU[64 * 36];
  __shared__ unsigned Gs[4][32];
  __shared__ int idxt[64];
  __shared__ float sc[64], sh[64], bb[64];
  int t = threadIdx.x;
  int r = t >> 2, q = t & 3;
  {
    const float4* w4 = (const float4*)(w2d + r * 64 + q * 16);
#pragma unroll
    for (int uu = 0; uu < 4; uu++) {
      float4 v = w4[uu];
      WlU[r * 36 + q * 8 + uu * 2] = pack_bf16x2(v.x, v.y);
      WlU[r * 36 + q * 8 + uu * 2 + 1] = pack_bf16x2(v.z, v.w);
    }
  }
  if (t < 64) {
    float mu = aD[t] / (float)NSAMP;
    float var = aD[64 + t] / (float)NSAMP - mu * mu;
    float scale = dg[t] * rsqrtf(var + EPSf);
    sc[t] = scale;
    sh[t] = dbe[t] - mu * scale;
    bb[t] = b2d[t];
  }
  int wave = t >> 6, lane = t & 63;
  int lr = lane & 15, lg = lane >> 4;
  int p = r >> 4;
  int wblk = blockIdx.x >> 3;  // 0..511
  int bbase = batch * Nn;
#pragma unroll 1
  for (int tt = 0; tt < 4; tt++) {
    int tile = wblk * 4 + tt;
    int ptb = batch * Nn + tile * 4;
    __syncthreads();
    if (t < 64) idxt[t] = idx[ptb * 16 + t];
    if (t < 128)
      Gs[t >> 5][t & 31] =
          *(const unsigned*)(FS + (size_t)(ptb + (t >> 5)) * FT_STRIDE + 128 + (t & 31) * 4);
    __syncthreads();
    const char* orow = FO + (size_t)(bbase + idxt[r]) * FT_STRIDE + 128;
    uint4 g0 = *(const uint4*)(orow + q * 32);
    uint4 g1 = *(const uint4*)(orow + q * 32 + 16);
#pragma unroll
    for (int uu = 0; uu < 8; uu++) {
      unsigned gdo2 = (uu < 4) ? ((const unsigned*)&g0)[uu] : ((const unsigned*)&g1)[uu - 4];
      unsigned gds2 = Gs[p][q * 8 + uu];
      int c = q * 16 + uu * 2;
      float h0 = fmaxf(sc[c] * (bf16_lo(gds2) - bf16_lo(gdo2)) + sh[c], 0.f);
      float h1 = fmaxf(sc[c + 1] * (bf16_hi(gds2) - bf16_hi(gdo2)) + sh[c + 1], 0.f);
      HtU[r * 36 + q * 8 + uu] = pack_bf16x2(h0, h1);
    }
    __syncthreads();
    v4f acc4[4] = {{0, 0, 0, 0}, {0, 0, 0, 0}, {0, 0, 0, 0}, {0, 0, 0, 0}};
    v8bf a0 = *(const v8bf*)&HtU[(wave * 16 + lr) * 36 + lg * 4];
    v8bf a1 = *(const v8bf*)&HtU[(wave * 16 + lr) * 36 + 16 + lg * 4];
#pragma unroll
    for (int c = 0; c < 4; c++) {
      v8bf b0 = *(const v8bf*)&WlU[(c * 16 + lr) * 36 + lg * 4];
      v8bf b1 = *(const v8bf*)&WlU[(c * 16 + lr) * 36 + 16 + lg * 4];
      acc4[c] = __builtin_amdgcn_mfma_f32_16x16x32_bf16(a0, b0, acc4[c], 0, 0, 0);
      acc4[c] = __builtin_amdgcn_mfma_f32_16x16x32_bf16(a1, b1, acc4[c], 0, 0, 0);
    }
#pragma unroll
    for (int c = 0; c < 4; c++) {
      float mm = fmaxf(fmaxf(acc4[c][0], acc4[c][1]), fmaxf(acc4[c][2], acc4[c][3]));
      mm = fmaxf(mm, __shfl_xor(mm, 16));
      mm = fmaxf(mm, __shfl_xor(mm, 32));
      if (lane < 16) dout[(size_t)(ptb + wave) * 64 + c * 16 + lane] = mm + bb[c * 16 + lane];
    }
  }
}

// ---------------- YF = [DF | relu_bn(YS)] @ [fw1L | W']^T + fin BN stats ----------
__global__ __launch_bounds__(256) void yfin_gemm(
    const float* __restrict__ DF0, const float* __restrict__ DF1,
    const float* __restrict__ YS0, const float* __restrict__ YS1,
    const float* __restrict__ fw1, const float* __restrict__ Wp,
    const float* __restrict__ sg, const float* __restrict__ sbe,
    float* __restrict__ YF0, float* __restrict__ YF1, float* __restrict__ acc) {
  int dir = blockIdx.z;
  const float* df = dir ? DF1 : DF0;
  const float* ysim = dir ? YS1 : YS0;
  float* yf = dir ? YF1 : YF0;
  const float* aS = acc + 256 + dir * 128;
  float* accF = acc + 512 + dir * 256;
  __shared__ __align__(16) unsigned Au[64 * 68];
  __shared__ __align__(16) unsigned Bu[64 * 68];
  __shared__ float redS[4][64], redQ[4][64];
  __shared__ float scs[64], shs[64];
  int t = threadIdx.x;
  int y = blockIdx.y;
  int ptb = blockIdx.x * 64;
  if (t < 64) {
    float mu = aS[t] / (float)NPTS;
    float var = aS[64 + t] / (float)NPTS - mu * mu;
    float scale = sg[t] * rsqrtf(var + EPSf);
    scs[t] = scale;
    shs[t] = sbe[t] - mu * scale;
  }
  __syncthreads();
#pragma unroll
  for (int i = 0; i < 16; i++) {
    int ix = t + i * 256;
    int row = ix >> 6, uc = ix & 63;
    int sw = uc ^ ((row & 7) << 2);
    float2 v;
    if (uc < 32) {
      v = *(const float2*)(df + (size_t)(ptb + row) * 64 + uc * 2);
    } else {
      int c2 = (uc - 32) * 2;
      float2 yv = *(const float2*)(ysim + (size_t)(ptb + row) * 64 + c2);
      v.x = fmaxf(scs[c2] * yv.x + shs[c2], 0.f);
      v.y = fmaxf(scs[c2 + 1] * yv.y + shs[c2 + 1], 0.f);
    }
    Au[row * 68 + sw] = pack_bf16x2(v.x, v.y);
    float2 w = (uc < 32)
                   ? *(const float2*)(fw1 + (size_t)(y * 64 + row) * 128 + uc * 2)
                   : *(const float2*)(Wp + (size_t)(y * 64 + row) * 64 + (uc - 32) * 2);
    Bu[row * 68 + sw] = pack_bf16x2(w.x, w.y);
  }
  __syncthreads();
  int wave = t >> 6, lane = t & 63, lr = lane & 15, lg = lane >> 4;
  v8bf a[4];
  {
    int arow = wave * 16 + lr;
    int base = arow * 68, sx = (arow & 7) << 2;
#pragma unroll
    for (int kk = 0; kk < 4; kk++)
      a[kk] = *(const v8bf*)&Au[base + ((kk * 16 + lg * 4) ^ sx)];
  }
  v4f acc4[4] = {{0, 0, 0, 0}, {0, 0, 0, 0}, {0, 0, 0, 0}, {0, 0, 0, 0}};
#pragma unroll
  for (int c = 0; c < 4; c++) {
    int brow = c * 16 + lr;
    int base = brow * 68, sx = (brow & 7) << 2;
#pragma unroll
    for (int kk = 0; kk < 4; kk++) {
      v8bf b = *(const v8bf*)&Bu[base + ((kk * 16 + lg * 4) ^ sx)];
      acc4[c] = __builtin_amdgcn_mfma_f32_16x16x32_bf16(a[kk], b, acc4[c], 0, 0, 0);
    }
  }
#pragma unroll
  for (int c = 0; c < 4; c++) {
    float s = 0.f, q = 0.f;
#pragma unroll
    for (int i = 0; i < 4; i++) {
      float v = acc4[c][i];
      yf[(size_t)(ptb + wave * 16 + lg * 4 + i) * 128 + y * 64 + c * 16 + lr] = v;
      s += v;
      q += v * v;
    }
    s += __shfl_xor(s, 16);
    s += __shfl_xor(s, 32);
    q += __shfl_xor(q, 16);
    q += __shfl_xor(q, 32);
    if (lane < 16) {
      redS[wave][c * 16 + lr] = s;
      redQ[wave][c * 16 + lr] = q;
    }
  }
  __syncthreads();
  if (t < 64) {
    atomicAdd(accF + y * 64 + t, redS[0][t] + redS[1][t] + redS[2][t] + redS[3][t]);
    atomicAdd(accF + 128 + y * 64 + t,
              redQ[0][t] + redQ[1][t] + redQ[2][t] + redQ[3][t]);
  }
}

// ---------------- out = relu(bn(YF)) @ fw2^T + fb2 (MFMA, bf16 tiles) -------------
__global__ __launch_bounds__(256) void finout_gemm(
    const float* __restrict__ YF0, const float* __restrict__ YF1,
    const float* __restrict__ acc, const float* __restrict__ fg,
    const float* __restrict__ fbe, const float* __restrict__ fw2,
    const float* __restrict__ fb2, float* __restrict__ out) {
  int dir = blockIdx.y;
  const float* yf = dir ? YF1 : YF0;
  const float* aF = acc + 512 + dir * 256;
  float* outp = out + (size_t)dir * NPTS * 64;
  __shared__ __align__(16) unsigned Au[64 * 68];
  __shared__ __align__(16) unsigned Bu[64 * 68];
  __shared__ float scl[128], shf[128], bb[64];
  int t = threadIdx.x;
  if (t < 128) {
    float mu = aF[t] / (float)NPTS;
    float var = aF[128 + t] / (float)NPTS - mu * mu;
    float scale = fg[t] * rsqrtf(var + EPSf);
    scl[t] = scale;
    shf[t] = fbe[t] - mu * scale;
  }
  if (t < 64) bb[t] = fb2[t];
  int ptb = blockIdx.x * 64;
#pragma unroll
  for (int i = 0; i < 16; i++) {
    int ix = t + i * 256;
    int row = ix >> 6, uc = ix & 63;
    int sw = uc ^ ((row & 7) << 2);
    float2 w = *(const float2*)(fw2 + (size_t)row * 128 + uc * 2);
    Bu[row * 68 + sw] = pack_bf16x2(w.x, w.y);
  }
  __syncthreads();
#pragma unroll
  for (int i = 0; i < 16; i++) {
    int ix = t + i * 256;
    int row = ix >> 6, uc = ix & 63;
    int sw = uc ^ ((row & 7) << 2);
    float2 v = *(const float2*)(yf + (size_t)(ptb + row) * 128 + uc * 2);
    float h0 = fmaxf(scl[uc * 2] * v.x + shf[uc * 2], 0.f);
    float h1 = fmaxf(scl[uc * 2 + 1] * v.y + shf[uc * 2 + 1], 0.f);
    Au[row * 68 + sw] = pack_bf16x2(h0, h1);
  }
  __syncthreads();
  int wave = t >> 6, lane = t & 63, lr = lane & 15, lg = lane >> 4;
  v8bf a[4];
  {
    int arow = wave * 16 + lr;
    int base = arow * 68, sx = (arow & 7) << 2;
#pragma unroll
    for (int kk = 0; kk < 4; kk++)
      a[kk] = *(const v8bf*)&Au[base + ((kk * 16 + lg * 4) ^ sx)];
  }
  v4f acc4[4] = {{0, 0, 0, 0}, {0, 0, 0, 0}, {0, 0, 0, 0}, {0, 0, 0, 0}};
#pragma unroll
  for (int c = 0; c < 4; c++) {
    int brow = c * 16 + lr;
    int base = brow * 68, sx = (brow & 7) << 2;
#pragma unroll
    for (int kk = 0; kk < 4; kk++) {
      v8bf b = *(const v8bf*)&Bu[base + ((kk * 16 + lg * 4) ^ sx)];
      acc4[c] = __builtin_amdgcn_mfma_f32_16x16x32_bf16(a[kk], b, acc4[c], 0, 0, 0);
    }
  }
#pragma unroll
  for (int c = 0; c < 4; c++) {
    float bbv = bb[c * 16 + lr];
#pragma unroll
    for (int i = 0; i < 4; i++)
      outp[(size_t)(ptb + wave * 16 + lg * 4 + i) * 64 + c * 16 + lr] =
          acc4[c][i] + bbv;
  }
}

extern "C" void kernel_launch(void* const* d_in, const int* in_sizes, int n_in,
                              void* d_out, int out_size, void* d_ws, size_t ws_size,
                              hipStream_t stream) {
  const float* f0 = (const float*)d_in[0];
  const float* f1 = (const float*)d_in[1];
  const int* i01 = (const int*)d_in[2];
  const int* i10 = (const int*)d_in[3];
  const float* dw1 = (const float*)d_in[4];
  const float* dg = (const float*)d_in[6];
  const float* dbe = (const float*)d_in[7];
  const float* dw2 = (const float*)d_in[8];
  const float* db2 = (const float*)d_in[9];
  const float* sw1 = (const float*)d_in[10];
  const float* sg = (const float*)d_in[12];
  const float* sbe = (const float*)d_in[13];
  const float* sw2 = (const float*)d_in[14];
  const float* sb2 = (const float*)d_in[15];
  const float* fw1 = (const float*)d_in[16];
  const float* fg = (const float*)d_in[18];
  const float* fbe = (const float*)d_in[19];
  const float* fw2 = (const float*)d_in[20];
  const float* fb2 = (const float*)d_in[21];
  (void)sb2;  // cancels exactly under fin-BN after the W' fold

  char* wsb = (char*)d_ws;
  float* out = (float*)d_out;

  char* FT0 = wsb;                 // 12 MB + pad
  char* FT1 = wsb + FTSZ;          // 12 MB + pad
  float* acc = (float*)(wsb + 2 * FTSZ);          // 1024 floats
  float* Wp = (float*)(wsb + 2 * FTSZ + 16384);   // 128x64 = 32KB
  float* YS0 = (float*)(wsb + 2 * FTSZ + 65536);
  float* YS1 = YS0 + GSZ;
  float* DF0 = YS1 + GSZ;
  float* DF1 = DF0 + GSZ;
  float* YF0 = DF1 + GSZ;    // 16MB (old SF region; YS stays live for yfin)
  float* YF1 = (float*)wsb;  // 16MB over FT0+FT1 (dead after diff_out_k)

  hipMemsetAsync(acc, 0, 1024 * sizeof(float), stream);
  wprep<<<32, 256, 0, stream>>>(fw1, sw2, Wp);
  gemmG<<<dim3(512, 1, 2), 256, 0, stream>>>(f0, f1, dw1, sw1, FT0, FT1);

  stats_sim<<<2048, 256, 0, stream>>>(FT0, FT1, i01, i10, YS0, YS1, acc);

  diff_out_k<<<4096, 256, 0, stream>>>(FT0, FT1, i01, i10, dw2, db2, acc, dg, dbe, DF0, DF1);

  yfin_gemm<<<dim3(512, 2, 2), 256, 0, stream>>>(DF0, DF1, YS0, YS1, fw1, Wp, sg, sbe,
                                                 YF0, YF1, acc);

  finout_gemm<<<dim3(512, 2), 256, 0, stream>>>(YF0, YF1, acc, fg, fbe, fw2, fb2, out);
}